// Round 12
// baseline (419.539 us; speedup 1.0000x reference)
//
#include <hip/hip_runtime.h>
#include <hip/hip_fp16.h>
#include <math.h>

#define NG 100000
#define ND 50000
#define EGG 1600000
#define EDG 800000
#define EALL (EGG + EDG)
#define NALL (NG + NG)
#define HID 128
#define NH 8

// bucket sort params
#define SHIFT 11
#define BDSTS (1 << SHIFT)
#define NBUK  ((NALL + BDSTS - 1) / BDSTS)   // 98
#define BUKCAP 36864                          // mean 32768 + ~23 sigma
#define S1_CH 6144
#define KM_HALF ((NG + 127) / 128)            // 782 blocks per metapath

// ---------------- workspace layout (4-byte element offsets) ----------------
#define OFF_OUT_GG 0UL          // f16 out_gg: 6,400,000 (colPacked overlay: 3,612,672 u32)
#define OFF_OUT_DG 6400000UL    // f16 out_dg: 6,400,000
#define OFF_XG     12800000UL   // f16 xg: 6,400,000 -> ends 19,200,000
#define OFF_XD     19200000UL   // f16 xd: 3,200,000 -> ends 22,400,000
#define OFF_ASG    22400000UL   //   800,000
#define OFF_ADG    23200000UL   //   800,000
#define OFF_ADD    24000000UL   //   800,000
#define OFF_ASD    24800000UL   //   400,000 -> ends 25,200,000
#define OFF_KPART  25200000UL   //       256  (zero-init)
#define OFF_BCNT   25200256UL   //       128  (zero-init)
#define ZERO_BASE  OFF_KPART
#define ZERO_CNT   384
#define OFF_ATTN   25200384UL   //         2 (+pad)
#define OFF_RP     25200640UL   //   200,001 (+pad)
#define OFF_COL    25400704UL   // 2,400,000 -> ends 27,800,704
#define OFF_WTIL   27800704UL   //     3,072
#define OFF_BTIL   27803776UL   //        24
#define OFF_WTILD  27803904UL   //     1,024
#define OFF_BTILD  27804928UL   //         8
// end ~27,804,936 floats = 111 MB

typedef float  f32x4  __attribute__((ext_vector_type(4)));
typedef short  bf16x8 __attribute__((ext_vector_type(8)));
typedef _Float16 f16x8 __attribute__((ext_vector_type(8)));
#define MFMA(a, b, c)  __builtin_amdgcn_mfma_f32_16x16x32_bf16(a, b, c, 0, 0, 0)
#define MFMAH(a, b, c) __builtin_amdgcn_mfma_f32_16x16x32_f16(a, b, c, 0, 0, 0)

// acc += f16(lo/hi half of SRC u32) * AL   (single v_fma_mix_f32)
#define FMAMIX_LO(ACC, SRC, AL) \
    asm("v_fma_mix_f32 %0, %1, %2, %0 op_sel:[0,0,0] op_sel_hi:[1,0,0]" \
        : "+v"(ACC) : "v"(SRC), "v"(AL))
#define FMAMIX_HI(ACC, SRC, AL) \
    asm("v_fma_mix_f32 %0, %1, %2, %0 op_sel:[1,0,0] op_sel_hi:[1,0,0]" \
        : "+v"(ACC) : "v"(SRC), "v"(AL))

__device__ __forceinline__ unsigned short bf16_rne(float f) {
    unsigned u = __float_as_uint(f);
    u += 0x7FFFu + ((u >> 16) & 1u);
    return (unsigned short)(u >> 16);
}
__device__ __forceinline__ float bf16f(unsigned short h) {
    return __uint_as_float(((unsigned)h) << 16);
}
__device__ __forceinline__ unsigned short f16_bits(float f) {
    __half h = __float2half(f);
    return *(unsigned short*)&h;
}
__device__ __forceinline__ float fast_tanh(float x) {
    x = fminf(fmaxf(x, -15.f), 15.f);
    float t = __expf(2.f * x);
    return (t - 1.f) / (t + 1.f);
}
__device__ __forceinline__ bf16x8 cvt_hi8(f32x4 v0, f32x4 v1) {
    bf16x8 f;
    f[0] = (short)bf16_rne(v0.x); f[1] = (short)bf16_rne(v0.y);
    f[2] = (short)bf16_rne(v0.z); f[3] = (short)bf16_rne(v0.w);
    f[4] = (short)bf16_rne(v1.x); f[5] = (short)bf16_rne(v1.y);
    f[6] = (short)bf16_rne(v1.z); f[7] = (short)bf16_rne(v1.w);
    return f;
}
__device__ __forceinline__ bf16x8 cvt_lo8(f32x4 v0, f32x4 v1, bf16x8 h) {
    bf16x8 f;
    f[0] = (short)bf16_rne(v0.x - bf16f((unsigned short)h[0]));
    f[1] = (short)bf16_rne(v0.y - bf16f((unsigned short)h[1]));
    f[2] = (short)bf16_rne(v0.z - bf16f((unsigned short)h[2]));
    f[3] = (short)bf16_rne(v0.w - bf16f((unsigned short)h[3]));
    f[4] = (short)bf16_rne(v1.x - bf16f((unsigned short)h[4]));
    f[5] = (short)bf16_rne(v1.y - bf16f((unsigned short)h[5]));
    f[6] = (short)bf16_rne(v1.z - bf16f((unsigned short)h[6]));
    f[7] = (short)bf16_rne(v1.w - bf16f((unsigned short)h[7]));
    return f;
}
// packed relu on 2x f16 in a u32: zero any half with sign bit set
__device__ __forceinline__ unsigned relu_pk(unsigned u) {
    return u & ~(((u & 0x80008000u) >> 15) * 0xFFFFu);
}
union U4F16 { uint4 u; f16x8 f; };

// ---------------- init ----------------
__global__ void init_zero_k(float* __restrict__ p, int n) {
    int i = blockIdx.x * 256 + threadIdx.x;
    if (i < n) p[i] = 0.f;
}

// ---------------- wtilde (both node types in one launch) ----------------
__device__ __forceinline__ void wtil_body(const float* __restrict__ W,
                                          const float* __restrict__ bias,
                                          const float* __restrict__ a0,
                                          const float* __restrict__ a1,
                                          const float* __restrict__ a2, int natt,
                                          float* __restrict__ wtil, float* __restrict__ btil,
                                          int bid, int nblk) {
    int tot = natt * 8 * 128;
    for (int i = bid * 256 + threadIdx.x; i < tot; i += nblk * 256) {
        int k = i & 127, cc = i >> 7;
        int v = cc >> 3, h = cc & 7;
        const float* av = (v == 0) ? a0 : (v == 1) ? a1 : a2;
        float s = 0.f;
        #pragma unroll
        for (int c = 0; c < 16; c++) s += av[h * 16 + c] * W[(h * 16 + c) * 128 + k];
        wtil[i] = s;
    }
    if (bid == 0 && threadIdx.x < natt * 8) {
        int v = threadIdx.x >> 3, h = threadIdx.x & 7;
        const float* av = (v == 0) ? a0 : (v == 1) ? a1 : a2;
        float s = 0.f;
        #pragma unroll
        for (int c = 0; c < 16; c++) s += av[h * 16 + c] * bias[h * 16 + c];
        btil[threadIdx.x] = s;
    }
}

__global__ void make_wtil_both(const float* __restrict__ Wg, const float* __restrict__ bg,
                               const float* __restrict__ ag0, const float* __restrict__ ag1,
                               const float* __restrict__ ag2,
                               const float* __restrict__ Wd, const float* __restrict__ bd,
                               const float* __restrict__ ad0,
                               float* __restrict__ wtilG, float* __restrict__ btilG,
                               float* __restrict__ wtilD, float* __restrict__ btilD) {
    if (blockIdx.x < 8)
        wtil_body(Wg, bg, ag0, ag1, ag2, 3, wtilG, btilG, blockIdx.x, 8);
    else
        wtil_body(Wd, bd, ad0, ad0, ad0, 1, wtilD, btilD, blockIdx.x - 8, 4);
}

// ---------------- proj via split-bf16 MFMA (straight-line, scratch-free) ----------------
template<int NATT>
__launch_bounds__(256)
__global__ void proj_mfma(const float* __restrict__ x, const float* __restrict__ W,
                          const float* __restrict__ bias,
                          const float* __restrict__ wtil, const float* __restrict__ btil,
                          unsigned short* __restrict__ xbf,   // f16 [N][128]
                          float* __restrict__ o0, float* __restrict__ o1,
                          float* __restrict__ o2, int N) {
    constexpr int NTE = (NATT * 8 + 15) / 16;
    constexpr int NT = 8 + NTE;
    __shared__ bf16x8 Bhi[NT * 4 * 64];
    __shared__ bf16x8 Blo[8 * 4 * 64];
    for (int idx = threadIdx.x; idx < 128 * 32; idx += 256) {
        int row = idx >> 5, kq = idx & 31;
        f32x4 v = *(const f32x4*)&W[row * 128 + kq * 4];
        int ct = row >> 4, c = row & 15;
        int k0 = kq * 4;
        int kc = k0 >> 5, q16 = (k0 & 31) >> 3, j2 = (k0 & 7) >> 1;
        int slot = (ct * 4 + kc) * 64 + q16 * 16 + c;
        unsigned short hx = bf16_rne(v.x), hy = bf16_rne(v.y);
        unsigned short hz = bf16_rne(v.z), hw = bf16_rne(v.w);
        unsigned* dh = (unsigned*)&Bhi[slot];
        dh[j2]     = ((unsigned)hy << 16) | hx;
        dh[j2 + 1] = ((unsigned)hw << 16) | hz;
        unsigned* dl = (unsigned*)&Blo[slot];
        dl[j2]     = ((unsigned)bf16_rne(v.y - bf16f(hy)) << 16) | bf16_rne(v.x - bf16f(hx));
        dl[j2 + 1] = ((unsigned)bf16_rne(v.w - bf16f(hw)) << 16) | bf16_rne(v.z - bf16f(hz));
    }
    for (int idx = threadIdx.x; idx < NTE * 16 * 32; idx += 256) {
        int cc = idx >> 5, kq = idx & 31;
        f32x4 v = {0.f, 0.f, 0.f, 0.f};
        if (cc < NATT * 8) v = *(const f32x4*)&wtil[cc * 128 + kq * 4];
        int ct = 8 + (cc >> 4), c = cc & 15;
        int k0 = kq * 4;
        int kc = k0 >> 5, q16 = (k0 & 31) >> 3, j2 = (k0 & 7) >> 1;
        unsigned* dh = (unsigned*)&Bhi[(ct * 4 + kc) * 64 + q16 * 16 + c];
        dh[j2]     = ((unsigned)bf16_rne(v.y) << 16) | bf16_rne(v.x);
        dh[j2 + 1] = ((unsigned)bf16_rne(v.w) << 16) | bf16_rne(v.z);
    }
    __syncthreads();
    int wv = threadIdx.x >> 6, l = threadIdx.x & 63;
    int q = l >> 4, c16 = l & 15;
    int rw = blockIdx.x * 128 + wv * 32;
    int n0 = min(rw + c16, N - 1);
    int n1 = min(rw + 16 + c16, N - 1);
    const float* xr0 = &x[(size_t)n0 * 128 + q * 8];
    const float* xr1 = &x[(size_t)n1 * 128 + q * 8];
    #define LOADX(FH, FL, PTR, OFF) \
        bf16x8 FH, FL; \
        { f32x4 v0_ = *(const f32x4*)((PTR) + (OFF)); \
          f32x4 v1_ = *(const f32x4*)((PTR) + (OFF) + 4); \
          FH = cvt_hi8(v0_, v1_); FL = cvt_lo8(v0_, v1_, FH); }
    LOADX(xh00, xl00, xr0, 0)  LOADX(xh01, xl01, xr0, 32)
    LOADX(xh02, xl02, xr0, 64) LOADX(xh03, xl03, xr0, 96)
    LOADX(xh10, xl10, xr1, 0)  LOADX(xh11, xl11, xr1, 32)
    LOADX(xh12, xl12, xr1, 64) LOADX(xh13, xl13, xr1, 96)
    #undef LOADX
    int r0 = rw + q * 4;
    int r1 = r0 + 16;
    #define CT_MAIN(CT) { \
        bf16x8 bh0 = Bhi[((CT) * 4 + 0) * 64 + l]; \
        bf16x8 bh1 = Bhi[((CT) * 4 + 1) * 64 + l]; \
        bf16x8 bh2 = Bhi[((CT) * 4 + 2) * 64 + l]; \
        bf16x8 bh3 = Bhi[((CT) * 4 + 3) * 64 + l]; \
        bf16x8 bl0 = Blo[((CT) * 4 + 0) * 64 + l]; \
        bf16x8 bl1 = Blo[((CT) * 4 + 1) * 64 + l]; \
        bf16x8 bl2 = Blo[((CT) * 4 + 2) * 64 + l]; \
        bf16x8 bl3 = Blo[((CT) * 4 + 3) * 64 + l]; \
        f32x4 aA = {0,0,0,0}, aB = {0,0,0,0}, aC = {0,0,0,0}, aD = {0,0,0,0}; \
        aA = MFMA(xh00, bh0, aA); aB = MFMA(xh01, bh1, aB); \
        aC = MFMA(xh10, bh0, aC); aD = MFMA(xh11, bh1, aD); \
        aA = MFMA(xl00, bh0, aA); aB = MFMA(xl01, bh1, aB); \
        aC = MFMA(xl10, bh0, aC); aD = MFMA(xl11, bh1, aD); \
        aA = MFMA(xh00, bl0, aA); aB = MFMA(xh01, bl1, aB); \
        aC = MFMA(xh10, bl0, aC); aD = MFMA(xh11, bl1, aD); \
        aA = MFMA(xh02, bh2, aA); aB = MFMA(xh03, bh3, aB); \
        aC = MFMA(xh12, bh2, aC); aD = MFMA(xh13, bh3, aD); \
        aA = MFMA(xl02, bh2, aA); aB = MFMA(xl03, bh3, aB); \
        aC = MFMA(xl12, bh2, aC); aD = MFMA(xl13, bh3, aD); \
        aA = MFMA(xh02, bl2, aA); aB = MFMA(xh03, bl3, aB); \
        aC = MFMA(xh12, bl2, aC); aD = MFMA(xh13, bl3, aD); \
        f32x4 d0 = aA + aB, d1 = aC + aD; \
        float bv = bias[(CT) * 16 + c16]; \
        int col = (CT) * 16 + c16; \
        if (r0 + 0 < N) xbf[(size_t)(r0 + 0) * 128 + col] = f16_bits(d0[0] + bv); \
        if (r0 + 1 < N) xbf[(size_t)(r0 + 1) * 128 + col] = f16_bits(d0[1] + bv); \
        if (r0 + 2 < N) xbf[(size_t)(r0 + 2) * 128 + col] = f16_bits(d0[2] + bv); \
        if (r0 + 3 < N) xbf[(size_t)(r0 + 3) * 128 + col] = f16_bits(d0[3] + bv); \
        if (r1 + 0 < N) xbf[(size_t)(r1 + 0) * 128 + col] = f16_bits(d1[0] + bv); \
        if (r1 + 1 < N) xbf[(size_t)(r1 + 1) * 128 + col] = f16_bits(d1[1] + bv); \
        if (r1 + 2 < N) xbf[(size_t)(r1 + 2) * 128 + col] = f16_bits(d1[2] + bv); \
        if (r1 + 3 < N) xbf[(size_t)(r1 + 3) * 128 + col] = f16_bits(d1[3] + bv); }
    CT_MAIN(0) CT_MAIN(1) CT_MAIN(2) CT_MAIN(3)
    CT_MAIN(4) CT_MAIN(5) CT_MAIN(6) CT_MAIN(7)
    #undef CT_MAIN
    #define CT_ATT(TE) { \
        bf16x8 bh0 = Bhi[((8 + (TE)) * 4 + 0) * 64 + l]; \
        bf16x8 bh1 = Bhi[((8 + (TE)) * 4 + 1) * 64 + l]; \
        bf16x8 bh2 = Bhi[((8 + (TE)) * 4 + 2) * 64 + l]; \
        bf16x8 bh3 = Bhi[((8 + (TE)) * 4 + 3) * 64 + l]; \
        f32x4 aA = {0,0,0,0}, aB = {0,0,0,0}, aC = {0,0,0,0}, aD = {0,0,0,0}; \
        aA = MFMA(xh00, bh0, aA); aB = MFMA(xh01, bh1, aB); \
        aC = MFMA(xh10, bh0, aC); aD = MFMA(xh11, bh1, aD); \
        aA = MFMA(xh02, bh2, aA); aB = MFMA(xh03, bh3, aB); \
        aC = MFMA(xh12, bh2, aC); aD = MFMA(xh13, bh3, aD); \
        f32x4 d0 = aA + aB, d1 = aC + aD; \
        int cc = (TE) * 16 + c16; \
        if (cc < NATT * 8) { \
            float bt = btil[cc]; \
            int v = cc >> 3, h = cc & 7; \
            float* op = (v == 0) ? o0 : ((v == 1) ? o1 : o2); \
            if (r0 + 0 < N) op[(r0 + 0) * 8 + h] = d0[0] + bt; \
            if (r0 + 1 < N) op[(r0 + 1) * 8 + h] = d0[1] + bt; \
            if (r0 + 2 < N) op[(r0 + 2) * 8 + h] = d0[2] + bt; \
            if (r0 + 3 < N) op[(r0 + 3) * 8 + h] = d0[3] + bt; \
            if (r1 + 0 < N) op[(r1 + 0) * 8 + h] = d1[0] + bt; \
            if (r1 + 1 < N) op[(r1 + 1) * 8 + h] = d1[1] + bt; \
            if (r1 + 2 < N) op[(r1 + 2) * 8 + h] = d1[2] + bt; \
            if (r1 + 3 < N) op[(r1 + 3) * 8 + h] = d1[3] + bt; } }
    CT_ATT(0)
    if constexpr (NTE > 1) { CT_ATT(1) }
    #undef CT_ATT
}

// ---------------- K1: fused bucket scatter ----------------
__launch_bounds__(256)
__global__ void fused_scatter(const int* __restrict__ gg_src, const int* __restrict__ gg_dst,
                              const int* __restrict__ dg_src, const int* __restrict__ dg_dst,
                              int* __restrict__ bcnt, unsigned int* __restrict__ colPacked) {
    __shared__ int cnt[256], scanE[256], gbase[256], cursor[256];
    __shared__ int ss[256];
    __shared__ unsigned int sorted[S1_CH];
    __shared__ unsigned char bof[S1_CH];
    int t = threadIdx.x;
    cnt[t] = 0;
    __syncthreads();
    int base = blockIdx.x * S1_CH;
    for (int k = 0; k < S1_CH; k += 256) {
        int e = base + k + t;
        if (e < EALL) {
            int dn = (e < EGG) ? gg_dst[e] : (NG + dg_dst[e - EGG]);
            atomicAdd(&cnt[dn >> SHIFT], 1);
        }
    }
    __syncthreads();
    int v = cnt[t];
    ss[t] = v;
    __syncthreads();
    for (int off = 1; off < 256; off <<= 1) {
        int y = (t >= off) ? ss[t - off] : 0;
        __syncthreads();
        ss[t] += y;
        __syncthreads();
    }
    scanE[t] = ss[t] - v;
    cursor[t] = ss[t] - v;
    if (t < NBUK && v > 0) gbase[t] = atomicAdd(&bcnt[t], v);
    __syncthreads();
    for (int k = 0; k < S1_CH; k += 256) {
        int e = base + k + t;
        if (e < EALL) {
            int s, dn;
            if (e < EGG) { s = gg_src[e]; dn = gg_dst[e]; }
            else         { s = dg_src[e - EGG]; dn = NG + dg_dst[e - EGG]; }
            int b = dn >> SHIFT;
            int slot = atomicAdd(&cursor[b], 1);
            sorted[slot] = ((unsigned int)s << SHIFT) | (unsigned int)(dn & (BDSTS - 1));
            bof[slot] = (unsigned char)b;
        }
    }
    __syncthreads();
    int total = ss[255];
    for (int f = t; f < total; f += 256) {
        int b = bof[f];
        colPacked[(size_t)b * BUKCAP + gbase[b] + (f - scanE[b])] = sorted[f];
    }
}

// ---------------- K2: per-bucket build (absorbs the 98-bucket scan) ----------------
__launch_bounds__(256)
__global__ void bucket_build(const unsigned int* __restrict__ colPacked,
                             const int* __restrict__ bcnt,
                             int* __restrict__ rp, int* __restrict__ col) {
    __shared__ int lcur[BDSTS];
    __shared__ int tsum[256];
    __shared__ int bscan[128];
    int b = blockIdx.x;
    int t = threadIdx.x;
    // inclusive scan of bcnt[0..127] (NBUK=98 padded with zeros)
    if (t < 128) bscan[t] = (t < NBUK) ? bcnt[t] : 0;
    __syncthreads();
    for (int off = 1; off < 128; off <<= 1) {
        int y = 0;
        if (t < 128 && t >= off) y = bscan[t - off];
        __syncthreads();
        if (t < 128) bscan[t] += y;
        __syncthreads();
    }
    int gb = (b > 0) ? bscan[b - 1] : 0;
    int d0 = b << SHIFT;
    int nd = min(BDSTS, NALL - d0);
    int cnt = bcnt[b];
    const unsigned int* pk = colPacked + (size_t)b * BUKCAP;
    for (int i = t; i < BDSTS; i += 256) lcur[i] = 0;
    __syncthreads();
    for (int i = t; i < cnt; i += 256)
        atomicAdd(&lcur[pk[i] & (BDSTS - 1)], 1);
    __syncthreads();
    int h0 = lcur[t * 8 + 0], h1 = lcur[t * 8 + 1], h2 = lcur[t * 8 + 2], h3 = lcur[t * 8 + 3];
    int h4 = lcur[t * 8 + 4], h5 = lcur[t * 8 + 5], h6 = lcur[t * 8 + 6], h7 = lcur[t * 8 + 7];
    int tot = h0 + h1 + h2 + h3 + h4 + h5 + h6 + h7;
    tsum[t] = tot;
    __syncthreads();
    for (int off = 1; off < 256; off <<= 1) {
        int y = (t >= off) ? tsum[t - off] : 0;
        __syncthreads();
        tsum[t] += y;
        __syncthreads();
    }
    int pp = tsum[t] - tot + gb;
    __syncthreads();
    #define EMIT(J, HJ) { int idx = t * 8 + (J); \
        if (idx < nd) rp[d0 + idx] = pp; \
        lcur[idx] = pp; pp += (HJ); }
    EMIT(0, h0) EMIT(1, h1) EMIT(2, h2) EMIT(3, h3)
    EMIT(4, h4) EMIT(5, h5) EMIT(6, h6) EMIT(7, h7)
    #undef EMIT
    if (b == NBUK - 1 && t == 0) rp[NALL] = EALL;
    __syncthreads();
    for (int i = t; i < cnt; i += 256) {
        unsigned int p = pk[i];
        int pos = atomicAdd(&lcur[p & (BDSTS - 1)], 1);
        col[pos] = (int)(p >> SHIFT);
    }
}

// ---------------- gather v7: shuffle-free, direct col/a_s loads, deferred rsc ----------------
__launch_bounds__(256)
__global__ void gat_gather_all(const int* __restrict__ rp, const int* __restrict__ col,
                               const float* __restrict__ as_gg, const float* __restrict__ ad_gg,
                               const unsigned short* __restrict__ xg_h,
                               const float* __restrict__ as_dg, const float* __restrict__ ad_dg,
                               const unsigned short* __restrict__ xd_h,
                               unsigned short* __restrict__ out_gg,
                               unsigned short* __restrict__ out_dg) {
    int wid = (blockIdx.x * 256 + threadIdx.x) >> 6;
    int l = threadIdx.x & 63;
    if (wid >= NALL) return;
    int isdg = wid >= NG;
    int d = isdg ? wid - NG : wid;
    const float* a_s = isdg ? as_dg : as_gg;
    const float* a_d = isdg ? ad_dg : ad_gg;
    const unsigned short* xbf = isdg ? xd_h : xg_h;
    unsigned short* outh = (isdg ? out_dg : out_gg);

    int base = rp[wid];
    int deg = rp[wid + 1] - base;

    int hl = l & 7;
    int g  = l >> 3;
    float adl = a_d[d * 8 + hl];
    // phase 1: ssum = sum exp(a) per head (logits bounded |a|<~1.5: no max needed)
    float ssum = 0.f;
    for (int t = g; t < deg; t += 8) {
        int s = col[base + t];
        float a = a_s[s * 8 + hl] + adl;
        a = a > 0.f ? a : 0.2f * a;
        ssum += __expf(a);
    }
    ssum += __shfl_xor(ssum, 8);
    ssum += __shfl_xor(ssum, 16);
    ssum += __shfl_xor(ssum, 32);
    float rsc = 1.f / (ssum + 1e-16f);   // lane l holds total for head l&7 (uniform over g)

    // phase 2: quarter q = edge slot (4 edges/group), cq = 8-col block (head hq)
    int q = l >> 4;
    int cq = l & 15;
    int hq = cq >> 1;
    float rscq = __shfl(rsc, hq);        // one shuffle total
    float adq = a_d[d * 8 + hq];
    uint32_t colbyte = (uint32_t)cq << 4;
    float a0 = 0.f, a1 = 0.f, a2 = 0.f, a3 = 0.f, a4 = 0.f, a5 = 0.f, a6 = 0.f, a7 = 0.f;
    for (int j = 0; j < deg; j += 8) {
        #pragma unroll
        for (int sub = 0; sub < 8; sub += 4) {
            int jrel = j + sub + q;
            bool ok = jrel < deg;
            int s = ok ? col[base + jrel] : 0;     // L1-broadcast (16 lanes share line)
            float a = a_s[s * 8 + hq] + adq;       // 32B line shared by 16 lanes
            a = a > 0.f ? a : 0.2f * a;
            float al = ok ? __expf(a) : 0.f;       // alpha*ssum; rsc applied at end
            const uint4 rv = *(const uint4*)((const char*)xbf +
                                (((size_t)(uint32_t)s << 8) + colbyte));
            FMAMIX_LO(a0, rv.x, al); FMAMIX_HI(a1, rv.x, al);
            FMAMIX_LO(a2, rv.y, al); FMAMIX_HI(a3, rv.y, al);
            FMAMIX_LO(a4, rv.z, al); FMAMIX_HI(a5, rv.z, al);
            FMAMIX_LO(a6, rv.w, al); FMAMIX_HI(a7, rv.w, al);
        }
    }
    a0 *= rscq; a1 *= rscq; a2 *= rscq; a3 *= rscq;
    a4 *= rscq; a5 *= rscq; a6 *= rscq; a7 *= rscq;
    a0 += __shfl_xor(a0, 16); a0 += __shfl_xor(a0, 32);
    a1 += __shfl_xor(a1, 16); a1 += __shfl_xor(a1, 32);
    a2 += __shfl_xor(a2, 16); a2 += __shfl_xor(a2, 32);
    a3 += __shfl_xor(a3, 16); a3 += __shfl_xor(a3, 32);
    a4 += __shfl_xor(a4, 16); a4 += __shfl_xor(a4, 32);
    a5 += __shfl_xor(a5, 16); a5 += __shfl_xor(a5, 32);
    a6 += __shfl_xor(a6, 16); a6 += __shfl_xor(a6, 32);
    a7 += __shfl_xor(a7, 16); a7 += __shfl_xor(a7, 32);
    if (q == 0) {
        __half2 h01 = __floats2half2_rn(a0, a1);
        __half2 h23 = __floats2half2_rn(a2, a3);
        __half2 h45 = __floats2half2_rn(a4, a5);
        __half2 h67 = __floats2half2_rn(a6, a7);
        uint4 o;
        o.x = *(unsigned*)&h01; o.y = *(unsigned*)&h23;
        o.z = *(unsigned*)&h45; o.w = *(unsigned*)&h67;
        *(uint4*)((char*)outh + (size_t)d * 256 + cq * 16) = o;
    }
}

// ---------------- kmean via f16 MFMA (raw f16 rows, packed relu) ----------------
__launch_bounds__(256)
__global__ void kmean_mfma(const unsigned short* __restrict__ srcA,
                           const unsigned short* __restrict__ srcB,
                           const float* __restrict__ W, const float* __restrict__ bias,
                           float* __restrict__ kp) {
    __shared__ f16x8 Bs[8 * 4 * 64];
    for (int idx = threadIdx.x; idx < 128 * 32; idx += 256) {
        int row = idx >> 5, kq = idx & 31;
        f32x4 v = *(const f32x4*)&W[row * 128 + kq * 4];
        int ct = row >> 4, c = row & 15;
        int k0 = kq * 4;
        int kc = k0 >> 5, q16 = (k0 & 31) >> 3, j2 = (k0 & 7) >> 1;
        unsigned* dst = (unsigned*)&Bs[(ct * 4 + kc) * 64 + q16 * 16 + c];
        dst[j2]     = ((unsigned)f16_bits(v.y) << 16) | f16_bits(v.x);
        dst[j2 + 1] = ((unsigned)f16_bits(v.w) << 16) | f16_bits(v.z);
    }
    __syncthreads();
    int half = blockIdx.x >= KM_HALF;
    const unsigned short* src = half ? srcB : srcA;
    float* kpp = half ? (kp + 128) : kp;
    int rb = (half ? blockIdx.x - KM_HALF : blockIdx.x) * 128;
    int wv = threadIdx.x >> 6, l = threadIdx.x & 63;
    int q = l >> 4, c16 = l & 15;
    int rw = rb + wv * 32;
    const char* xr0 = (const char*)src + (size_t)(rw + c16) * 256 + q * 16;
    const char* xr1 = xr0 + 16 * 256;
    #define LOADA(F, PTR, OFF) f16x8 F; { \
        U4F16 u_; u_.u = *(const uint4*)((PTR) + (OFF)); \
        u_.u.x = relu_pk(u_.u.x); u_.u.y = relu_pk(u_.u.y); \
        u_.u.z = relu_pk(u_.u.z); u_.u.w = relu_pk(u_.u.w); \
        F = u_.f; }
    LOADA(f00, xr0, 0) LOADA(f01, xr0, 64) LOADA(f02, xr0, 128) LOADA(f03, xr0, 192)
    LOADA(f10, xr1, 0) LOADA(f11, xr1, 64) LOADA(f12, xr1, 128) LOADA(f13, xr1, 192)
    #undef LOADA
    float bv0 = bias[c16],      bv1 = bias[16 + c16], bv2 = bias[32 + c16], bv3 = bias[48 + c16];
    float bv4 = bias[64 + c16], bv5 = bias[80 + c16], bv6 = bias[96 + c16], bv7 = bias[112 + c16];
    int row0 = rw + q * 4;
    int row1 = row0 + 16;
    float cs0 = 0.f, cs1 = 0.f, cs2 = 0.f, cs3 = 0.f, cs4 = 0.f, cs5 = 0.f, cs6 = 0.f, cs7 = 0.f;
    #define CT_STEP(CT, CS, BV) { \
        f16x8 b0 = Bs[((CT) * 4 + 0) * 64 + l]; \
        f16x8 b1 = Bs[((CT) * 4 + 1) * 64 + l]; \
        f16x8 b2 = Bs[((CT) * 4 + 2) * 64 + l]; \
        f16x8 b3 = Bs[((CT) * 4 + 3) * 64 + l]; \
        f32x4 aA = {0,0,0,0}, aB = {0,0,0,0}, aC = {0,0,0,0}, aD = {0,0,0,0}; \
        aA = MFMAH(f00, b0, aA); aB = MFMAH(f01, b1, aB); \
        aA = MFMAH(f02, b2, aA); aB = MFMAH(f03, b3, aB); \
        aC = MFMAH(f10, b0, aC); aD = MFMAH(f11, b1, aD); \
        aC = MFMAH(f12, b2, aC); aD = MFMAH(f13, b3, aD); \
        f32x4 d0 = aA + aB, d1 = aC + aD; \
        float s = 0.f; \
        if (row0 + 0 < NG) s += fast_tanh(d0[0] + (BV)); \
        if (row0 + 1 < NG) s += fast_tanh(d0[1] + (BV)); \
        if (row0 + 2 < NG) s += fast_tanh(d0[2] + (BV)); \
        if (row0 + 3 < NG) s += fast_tanh(d0[3] + (BV)); \
        if (row1 + 0 < NG) s += fast_tanh(d1[0] + (BV)); \
        if (row1 + 1 < NG) s += fast_tanh(d1[1] + (BV)); \
        if (row1 + 2 < NG) s += fast_tanh(d1[2] + (BV)); \
        if (row1 + 3 < NG) s += fast_tanh(d1[3] + (BV)); \
        CS += s; }
    CT_STEP(0, cs0, bv0) CT_STEP(1, cs1, bv1) CT_STEP(2, cs2, bv2) CT_STEP(3, cs3, bv3)
    CT_STEP(4, cs4, bv4) CT_STEP(5, cs5, bv5) CT_STEP(6, cs6, bv6) CT_STEP(7, cs7, bv7)
    #undef CT_STEP
    __syncthreads();
    float* red = (float*)Bs;
    #define REDUCE_CT(CT, CS) { \
        float v = (CS); \
        v += __shfl_xor(v, 16); v += __shfl_xor(v, 32); \
        if (l < 16) red[wv * 128 + (CT) * 16 + l] = v; }
    REDUCE_CT(0, cs0) REDUCE_CT(1, cs1) REDUCE_CT(2, cs2) REDUCE_CT(3, cs3)
    REDUCE_CT(4, cs4) REDUCE_CT(5, cs5) REDUCE_CT(6, cs6) REDUCE_CT(7, cs7)
    #undef REDUCE_CT
    __syncthreads();
    if (threadIdx.x < 128) {
        float s = red[threadIdx.x] + red[128 + threadIdx.x]
                + red[256 + threadIdx.x] + red[384 + threadIdx.x];
        atomicAdd(&kpp[threadIdx.x], s);
    }
}

// ---------------- semantic softmax (2 scores) ----------------
__global__ void score_attn(const float* __restrict__ kpart, const float* __restrict__ q,
                           float* __restrict__ attn) {
    __shared__ float r0[128], r1[128];
    int t = threadIdx.x;
    r0[t] = q[t] * kpart[t];
    r1[t] = q[t] * kpart[128 + t];
    __syncthreads();
    for (int s = 64; s > 0; s >>= 1) {
        if (t < s) { r0[t] += r0[t + s]; r1[t] += r1[t + s]; }
        __syncthreads();
    }
    if (t == 0) {
        float s0 = r0[0] / (float)NG, s1 = r1[0] / (float)NG;
        float mx = fmaxf(s0, s1);
        float e0 = expf(s0 - mx), e1 = expf(s1 - mx);
        attn[0] = e0 / (e0 + e1);
        attn[1] = e1 / (e0 + e1);
    }
}

// ---------------- fused combine + final linear (f16 inputs) ----------------
__launch_bounds__(256)
__global__ void final_lin(const unsigned short* __restrict__ gg,
                          const unsigned short* __restrict__ dgb,
                          const float* __restrict__ attn, const float* __restrict__ lin_w,
                          const float* __restrict__ lin_b, float* __restrict__ outp) {
    int wid = (blockIdx.x * 256 + threadIdx.x) >> 6;
    int l = threadIdx.x & 63;
    if (wid >= NG) return;
    float a0 = attn[0], a1 = attn[1];
    unsigned gu = *(const unsigned*)((const char*)gg + (size_t)wid * 256 + l * 4);
    unsigned du = *(const unsigned*)((const char*)dgb + (size_t)wid * 256 + l * 4);
    float2 gv = __half22float2(*(const __half2*)&gu);
    float2 dv = __half22float2(*(const __half2*)&du);
    float fx = a0 * fmaxf(gv.x, 0.f) + a1 * fmaxf(dv.x, 0.f);
    float fy = a0 * fmaxf(gv.y, 0.f) + a1 * fmaxf(dv.y, 0.f);
    float2 w0 = *(const float2*)&lin_w[l * 2];
    float2 w1 = *(const float2*)&lin_w[128 + l * 2];
    float p0 = fx * w0.x + fy * w0.y;
    float p1 = fx * w1.x + fy * w1.y;
    for (int off = 32; off > 0; off >>= 1) {
        p0 += __shfl_down(p0, off);
        p1 += __shfl_down(p1, off);
    }
    if (l == 0) {
        float2 o;
        o.x = p0 + lin_b[0];
        o.y = p1 + lin_b[1];
        *(float2*)&outp[wid * 2] = o;
    }
}

extern "C" void kernel_launch(void* const* d_in, const int* in_sizes, int n_in,
                              void* d_out, int out_size, void* d_ws, size_t ws_size,
                              hipStream_t stream) {
    const float* x_gene    = (const float*)d_in[0];
    const float* x_disease = (const float*)d_in[1];
    const int*   edge_gg   = (const int*)d_in[2];
    const int*   edge_dg   = (const int*)d_in[3];
    const float* pg_w      = (const float*)d_in[4];
    const float* pg_b      = (const float*)d_in[5];
    const float* pd_w      = (const float*)d_in[6];
    const float* pd_b      = (const float*)d_in[7];
    const float* att_src_gg= (const float*)d_in[8];
    const float* att_dst_gg= (const float*)d_in[9];
    const float* att_src_dg= (const float*)d_in[10];
    const float* att_dst_dg= (const float*)d_in[11];
    const float* k_lin_w   = (const float*)d_in[12];
    const float* k_lin_b   = (const float*)d_in[13];
    const float* q         = (const float*)d_in[14];
    const float* lin_w     = (const float*)d_in[15];
    const float* lin_b     = (const float*)d_in[16];
    float* out = (float*)d_out;
    float* ws  = (float*)d_ws;

    unsigned short* out_gg = (unsigned short*)(ws + OFF_OUT_GG);
    unsigned short* out_dg = (unsigned short*)(ws + OFF_OUT_DG);
    unsigned int* colPacked = (unsigned int*)(ws + OFF_OUT_GG);  // overlay (dead before gather)
    unsigned short* xg_h = (unsigned short*)(ws + OFF_XG);
    unsigned short* xd_h = (unsigned short*)(ws + OFF_XD);
    float* a_src_gg = ws + OFF_ASG;
    float* a_dst_gg = ws + OFF_ADG;
    float* a_dst_dg = ws + OFF_ADD;
    float* a_src_dg = ws + OFF_ASD;
    float* kpart  = ws + OFF_KPART;
    float* attn   = ws + OFF_ATTN;
    float* wtilG  = ws + OFF_WTIL;
    float* btilG  = ws + OFF_BTIL;
    float* wtilD  = ws + OFF_WTILD;
    float* btilD  = ws + OFF_BTILD;
    int* bcnt  = (int*)(ws + OFF_BCNT);
    int* rp    = (int*)(ws + OFF_RP);
    int* col   = (int*)(ws + OFF_COL);

    const int* gg_src = edge_gg;
    const int* gg_dst = edge_gg + EGG;
    const int* dg_src = edge_dg;
    const int* dg_dst = edge_dg + EDG;

    // 1. zero kpart + bucket counters; wtilde precompute (single launch)
    hipLaunchKernelGGL(init_zero_k, dim3(2), dim3(256), 0, stream, ws + ZERO_BASE, ZERO_CNT);
    hipLaunchKernelGGL(make_wtil_both, dim3(12), dim3(256), 0, stream,
                       pg_w, pg_b, att_src_gg, att_dst_gg, att_dst_dg,
                       pd_w, pd_b, att_src_dg, wtilG, btilG, wtilD, btilD);
    // 2. split-bf16 MFMA projections (f16 table + fused logits)
    hipLaunchKernelGGL((proj_mfma<3>), dim3((NG + 127) / 128), dim3(256), 0, stream,
                       x_gene, pg_w, pg_b, wtilG, btilG, xg_h,
                       a_src_gg, a_dst_gg, a_dst_dg, NG);
    hipLaunchKernelGGL((proj_mfma<1>), dim3((ND + 127) / 128), dim3(256), 0, stream,
                       x_disease, pd_w, pd_b, wtilD, btilD, xd_h,
                       a_src_dg, (float*)nullptr, (float*)nullptr, ND);
    // 3. CSR build: fused scatter -> per-bucket build (scan folded in)
    hipLaunchKernelGGL(fused_scatter, dim3((EALL + S1_CH - 1) / S1_CH), dim3(256), 0, stream,
                       gg_src, gg_dst, dg_src, dg_dst, bcnt, colPacked);
    hipLaunchKernelGGL(bucket_build, dim3(NBUK), dim3(256), 0, stream,
                       colPacked, bcnt, rp, col);
    // 4. merged fused gather (out_gg overwrites colPacked overlay — dead by now)
    hipLaunchKernelGGL(gat_gather_all, dim3((NALL + 3) / 4), dim3(256), 0, stream,
                       rp, col, a_src_gg, a_dst_gg, xg_h, a_src_dg, a_dst_dg, xd_h,
                       out_gg, out_dg);
    // 5. semantic attention (f16 MFMA kmean)
    hipLaunchKernelGGL(kmean_mfma, dim3(KM_HALF * 2), dim3(256), 0, stream,
                       out_gg, out_dg, k_lin_w, k_lin_b, kpart);
    hipLaunchKernelGGL(score_attn, dim3(1), dim3(128), 0, stream, kpart, q, attn);
    // 6. fused combine + final linear (f16 reads)
    hipLaunchKernelGGL(final_lin, dim3((NG + 3) / 4), dim3(256), 0, stream,
                       out_gg, out_dg, attn, lin_w, lin_b, out);
}

// Round 13
// 371.885 us; speedup vs baseline: 1.1281x; 1.1281x over previous
//
#include <hip/hip_runtime.h>
#include <hip/hip_fp16.h>
#include <math.h>

#define NG 100000
#define ND 50000
#define EGG 1600000
#define EDG 800000
#define EALL (EGG + EDG)
#define NALL (NG + NG)
#define HID 128
#define NH 8

// bucket sort params
#define SHIFT 11
#define BDSTS (1 << SHIFT)
#define NBUK  ((NALL + BDSTS - 1) / BDSTS)   // 98
#define BUKCAP 36864                          // mean 32768 + ~23 sigma
#define S1_CH 6144
#define KM_HALF ((NG + 127) / 128)            // 782 blocks per metapath

// ---------------- workspace layout (4-byte element offsets) ----------------
#define OFF_OUT_GG 0UL          // f16 out_gg: 6,400,000 (colPacked overlay: 3,612,672 u32)
#define OFF_OUT_DG 6400000UL    // f16 out_dg: 6,400,000
#define OFF_XG     12800000UL   // f16 xg: 6,400,000 -> ends 19,200,000
#define OFF_XD     19200000UL   // f16 xd: 3,200,000 -> ends 22,400,000
#define OFF_ASG    22400000UL   //   800,000
#define OFF_ADG    23200000UL   //   800,000
#define OFF_ADD    24000000UL   //   800,000
#define OFF_ASD    24800000UL   //   400,000 -> ends 25,200,000
#define OFF_KPART  25200000UL   //       256  (zero-init)
#define OFF_BCNT   25200256UL   //       128  (zero-init)
#define ZERO_BASE  OFF_KPART
#define ZERO_CNT   384
#define OFF_ATTN   25200384UL   //         2 (+pad)
#define OFF_RP     25200640UL   //   200,001 (+pad)
#define OFF_COL    25400704UL   // 2,400,000 -> ends 27,800,704
#define OFF_WTIL   27800704UL   //     3,072
#define OFF_BTIL   27803776UL   //        24
#define OFF_WTILD  27803904UL   //     1,024
#define OFF_BTILD  27804928UL   //         8
// end ~27,804,936 floats = 111 MB

typedef float  f32x4  __attribute__((ext_vector_type(4)));
typedef short  bf16x8 __attribute__((ext_vector_type(8)));
typedef _Float16 f16x8 __attribute__((ext_vector_type(8)));
#define MFMA(a, b, c)  __builtin_amdgcn_mfma_f32_16x16x32_bf16(a, b, c, 0, 0, 0)
#define MFMAH(a, b, c) __builtin_amdgcn_mfma_f32_16x16x32_f16(a, b, c, 0, 0, 0)

// acc += f16(lo/hi half of SRC u32) * AL   (single v_fma_mix_f32)
#define FMAMIX_LO(ACC, SRC, AL) \
    asm("v_fma_mix_f32 %0, %1, %2, %0 op_sel:[0,0,0] op_sel_hi:[1,0,0]" \
        : "+v"(ACC) : "v"(SRC), "v"(AL))
#define FMAMIX_HI(ACC, SRC, AL) \
    asm("v_fma_mix_f32 %0, %1, %2, %0 op_sel:[1,0,0] op_sel_hi:[1,0,0]" \
        : "+v"(ACC) : "v"(SRC), "v"(AL))

__device__ __forceinline__ unsigned short bf16_rne(float f) {
    unsigned u = __float_as_uint(f);
    u += 0x7FFFu + ((u >> 16) & 1u);
    return (unsigned short)(u >> 16);
}
__device__ __forceinline__ float bf16f(unsigned short h) {
    return __uint_as_float(((unsigned)h) << 16);
}
__device__ __forceinline__ unsigned short f16_bits(float f) {
    __half h = __float2half(f);
    return *(unsigned short*)&h;
}
__device__ __forceinline__ float fast_tanh(float x) {
    x = fminf(fmaxf(x, -15.f), 15.f);
    float t = __expf(2.f * x);
    return (t - 1.f) / (t + 1.f);
}
__device__ __forceinline__ bf16x8 cvt_hi8(f32x4 v0, f32x4 v1) {
    bf16x8 f;
    f[0] = (short)bf16_rne(v0.x); f[1] = (short)bf16_rne(v0.y);
    f[2] = (short)bf16_rne(v0.z); f[3] = (short)bf16_rne(v0.w);
    f[4] = (short)bf16_rne(v1.x); f[5] = (short)bf16_rne(v1.y);
    f[6] = (short)bf16_rne(v1.z); f[7] = (short)bf16_rne(v1.w);
    return f;
}
__device__ __forceinline__ bf16x8 cvt_lo8(f32x4 v0, f32x4 v1, bf16x8 h) {
    bf16x8 f;
    f[0] = (short)bf16_rne(v0.x - bf16f((unsigned short)h[0]));
    f[1] = (short)bf16_rne(v0.y - bf16f((unsigned short)h[1]));
    f[2] = (short)bf16_rne(v0.z - bf16f((unsigned short)h[2]));
    f[3] = (short)bf16_rne(v0.w - bf16f((unsigned short)h[3]));
    f[4] = (short)bf16_rne(v1.x - bf16f((unsigned short)h[4]));
    f[5] = (short)bf16_rne(v1.y - bf16f((unsigned short)h[5]));
    f[6] = (short)bf16_rne(v1.z - bf16f((unsigned short)h[6]));
    f[7] = (short)bf16_rne(v1.w - bf16f((unsigned short)h[7]));
    return f;
}
// packed relu on 2x f16 in a u32: zero any half with sign bit set
__device__ __forceinline__ unsigned relu_pk(unsigned u) {
    return u & ~(((u & 0x80008000u) >> 15) * 0xFFFFu);
}
union U4F16 { uint4 u; f16x8 f; };

// ---------------- init ----------------
__global__ void init_zero_k(float* __restrict__ p, int n) {
    int i = blockIdx.x * 256 + threadIdx.x;
    if (i < n) p[i] = 0.f;
}

// ---------------- wtilde (both node types in one launch) ----------------
__device__ __forceinline__ void wtil_body(const float* __restrict__ W,
                                          const float* __restrict__ bias,
                                          const float* __restrict__ a0,
                                          const float* __restrict__ a1,
                                          const float* __restrict__ a2, int natt,
                                          float* __restrict__ wtil, float* __restrict__ btil,
                                          int bid, int nblk) {
    int tot = natt * 8 * 128;
    for (int i = bid * 256 + threadIdx.x; i < tot; i += nblk * 256) {
        int k = i & 127, cc = i >> 7;
        int v = cc >> 3, h = cc & 7;
        const float* av = (v == 0) ? a0 : (v == 1) ? a1 : a2;
        float s = 0.f;
        #pragma unroll
        for (int c = 0; c < 16; c++) s += av[h * 16 + c] * W[(h * 16 + c) * 128 + k];
        wtil[i] = s;
    }
    if (bid == 0 && threadIdx.x < natt * 8) {
        int v = threadIdx.x >> 3, h = threadIdx.x & 7;
        const float* av = (v == 0) ? a0 : (v == 1) ? a1 : a2;
        float s = 0.f;
        #pragma unroll
        for (int c = 0; c < 16; c++) s += av[h * 16 + c] * bias[h * 16 + c];
        btil[threadIdx.x] = s;
    }
}

__global__ void make_wtil_both(const float* __restrict__ Wg, const float* __restrict__ bg,
                               const float* __restrict__ ag0, const float* __restrict__ ag1,
                               const float* __restrict__ ag2,
                               const float* __restrict__ Wd, const float* __restrict__ bd,
                               const float* __restrict__ ad0,
                               float* __restrict__ wtilG, float* __restrict__ btilG,
                               float* __restrict__ wtilD, float* __restrict__ btilD) {
    if (blockIdx.x < 8)
        wtil_body(Wg, bg, ag0, ag1, ag2, 3, wtilG, btilG, blockIdx.x, 8);
    else
        wtil_body(Wd, bd, ad0, ad0, ad0, 1, wtilD, btilD, blockIdx.x - 8, 4);
}

// ---------------- proj via split-bf16 MFMA (straight-line, scratch-free) ----------------
template<int NATT>
__launch_bounds__(256)
__global__ void proj_mfma(const float* __restrict__ x, const float* __restrict__ W,
                          const float* __restrict__ bias,
                          const float* __restrict__ wtil, const float* __restrict__ btil,
                          unsigned short* __restrict__ xbf,   // f16 [N][128]
                          float* __restrict__ o0, float* __restrict__ o1,
                          float* __restrict__ o2, int N) {
    constexpr int NTE = (NATT * 8 + 15) / 16;
    constexpr int NT = 8 + NTE;
    __shared__ bf16x8 Bhi[NT * 4 * 64];
    __shared__ bf16x8 Blo[8 * 4 * 64];
    for (int idx = threadIdx.x; idx < 128 * 32; idx += 256) {
        int row = idx >> 5, kq = idx & 31;
        f32x4 v = *(const f32x4*)&W[row * 128 + kq * 4];
        int ct = row >> 4, c = row & 15;
        int k0 = kq * 4;
        int kc = k0 >> 5, q16 = (k0 & 31) >> 3, j2 = (k0 & 7) >> 1;
        int slot = (ct * 4 + kc) * 64 + q16 * 16 + c;
        unsigned short hx = bf16_rne(v.x), hy = bf16_rne(v.y);
        unsigned short hz = bf16_rne(v.z), hw = bf16_rne(v.w);
        unsigned* dh = (unsigned*)&Bhi[slot];
        dh[j2]     = ((unsigned)hy << 16) | hx;
        dh[j2 + 1] = ((unsigned)hw << 16) | hz;
        unsigned* dl = (unsigned*)&Blo[slot];
        dl[j2]     = ((unsigned)bf16_rne(v.y - bf16f(hy)) << 16) | bf16_rne(v.x - bf16f(hx));
        dl[j2 + 1] = ((unsigned)bf16_rne(v.w - bf16f(hw)) << 16) | bf16_rne(v.z - bf16f(hz));
    }
    for (int idx = threadIdx.x; idx < NTE * 16 * 32; idx += 256) {
        int cc = idx >> 5, kq = idx & 31;
        f32x4 v = {0.f, 0.f, 0.f, 0.f};
        if (cc < NATT * 8) v = *(const f32x4*)&wtil[cc * 128 + kq * 4];
        int ct = 8 + (cc >> 4), c = cc & 15;
        int k0 = kq * 4;
        int kc = k0 >> 5, q16 = (k0 & 31) >> 3, j2 = (k0 & 7) >> 1;
        unsigned* dh = (unsigned*)&Bhi[(ct * 4 + kc) * 64 + q16 * 16 + c];
        dh[j2]     = ((unsigned)bf16_rne(v.y) << 16) | bf16_rne(v.x);
        dh[j2 + 1] = ((unsigned)bf16_rne(v.w) << 16) | bf16_rne(v.z);
    }
    __syncthreads();
    int wv = threadIdx.x >> 6, l = threadIdx.x & 63;
    int q = l >> 4, c16 = l & 15;
    int rw = blockIdx.x * 128 + wv * 32;
    int n0 = min(rw + c16, N - 1);
    int n1 = min(rw + 16 + c16, N - 1);
    const float* xr0 = &x[(size_t)n0 * 128 + q * 8];
    const float* xr1 = &x[(size_t)n1 * 128 + q * 8];
    #define LOADX(FH, FL, PTR, OFF) \
        bf16x8 FH, FL; \
        { f32x4 v0_ = *(const f32x4*)((PTR) + (OFF)); \
          f32x4 v1_ = *(const f32x4*)((PTR) + (OFF) + 4); \
          FH = cvt_hi8(v0_, v1_); FL = cvt_lo8(v0_, v1_, FH); }
    LOADX(xh00, xl00, xr0, 0)  LOADX(xh01, xl01, xr0, 32)
    LOADX(xh02, xl02, xr0, 64) LOADX(xh03, xl03, xr0, 96)
    LOADX(xh10, xl10, xr1, 0)  LOADX(xh11, xl11, xr1, 32)
    LOADX(xh12, xl12, xr1, 64) LOADX(xh13, xl13, xr1, 96)
    #undef LOADX
    int r0 = rw + q * 4;
    int r1 = r0 + 16;
    #define CT_MAIN(CT) { \
        bf16x8 bh0 = Bhi[((CT) * 4 + 0) * 64 + l]; \
        bf16x8 bh1 = Bhi[((CT) * 4 + 1) * 64 + l]; \
        bf16x8 bh2 = Bhi[((CT) * 4 + 2) * 64 + l]; \
        bf16x8 bh3 = Bhi[((CT) * 4 + 3) * 64 + l]; \
        bf16x8 bl0 = Blo[((CT) * 4 + 0) * 64 + l]; \
        bf16x8 bl1 = Blo[((CT) * 4 + 1) * 64 + l]; \
        bf16x8 bl2 = Blo[((CT) * 4 + 2) * 64 + l]; \
        bf16x8 bl3 = Blo[((CT) * 4 + 3) * 64 + l]; \
        f32x4 aA = {0,0,0,0}, aB = {0,0,0,0}, aC = {0,0,0,0}, aD = {0,0,0,0}; \
        aA = MFMA(xh00, bh0, aA); aB = MFMA(xh01, bh1, aB); \
        aC = MFMA(xh10, bh0, aC); aD = MFMA(xh11, bh1, aD); \
        aA = MFMA(xl00, bh0, aA); aB = MFMA(xl01, bh1, aB); \
        aC = MFMA(xl10, bh0, aC); aD = MFMA(xl11, bh1, aD); \
        aA = MFMA(xh00, bl0, aA); aB = MFMA(xh01, bl1, aB); \
        aC = MFMA(xh10, bl0, aC); aD = MFMA(xh11, bl1, aD); \
        aA = MFMA(xh02, bh2, aA); aB = MFMA(xh03, bh3, aB); \
        aC = MFMA(xh12, bh2, aC); aD = MFMA(xh13, bh3, aD); \
        aA = MFMA(xl02, bh2, aA); aB = MFMA(xl03, bh3, aB); \
        aC = MFMA(xl12, bh2, aC); aD = MFMA(xl13, bh3, aD); \
        aA = MFMA(xh02, bl2, aA); aB = MFMA(xh03, bl3, aB); \
        aC = MFMA(xh12, bl2, aC); aD = MFMA(xh13, bl3, aD); \
        f32x4 d0 = aA + aB, d1 = aC + aD; \
        float bv = bias[(CT) * 16 + c16]; \
        int col = (CT) * 16 + c16; \
        if (r0 + 0 < N) xbf[(size_t)(r0 + 0) * 128 + col] = f16_bits(d0[0] + bv); \
        if (r0 + 1 < N) xbf[(size_t)(r0 + 1) * 128 + col] = f16_bits(d0[1] + bv); \
        if (r0 + 2 < N) xbf[(size_t)(r0 + 2) * 128 + col] = f16_bits(d0[2] + bv); \
        if (r0 + 3 < N) xbf[(size_t)(r0 + 3) * 128 + col] = f16_bits(d0[3] + bv); \
        if (r1 + 0 < N) xbf[(size_t)(r1 + 0) * 128 + col] = f16_bits(d1[0] + bv); \
        if (r1 + 1 < N) xbf[(size_t)(r1 + 1) * 128 + col] = f16_bits(d1[1] + bv); \
        if (r1 + 2 < N) xbf[(size_t)(r1 + 2) * 128 + col] = f16_bits(d1[2] + bv); \
        if (r1 + 3 < N) xbf[(size_t)(r1 + 3) * 128 + col] = f16_bits(d1[3] + bv); }
    CT_MAIN(0) CT_MAIN(1) CT_MAIN(2) CT_MAIN(3)
    CT_MAIN(4) CT_MAIN(5) CT_MAIN(6) CT_MAIN(7)
    #undef CT_MAIN
    #define CT_ATT(TE) { \
        bf16x8 bh0 = Bhi[((8 + (TE)) * 4 + 0) * 64 + l]; \
        bf16x8 bh1 = Bhi[((8 + (TE)) * 4 + 1) * 64 + l]; \
        bf16x8 bh2 = Bhi[((8 + (TE)) * 4 + 2) * 64 + l]; \
        bf16x8 bh3 = Bhi[((8 + (TE)) * 4 + 3) * 64 + l]; \
        f32x4 aA = {0,0,0,0}, aB = {0,0,0,0}, aC = {0,0,0,0}, aD = {0,0,0,0}; \
        aA = MFMA(xh00, bh0, aA); aB = MFMA(xh01, bh1, aB); \
        aC = MFMA(xh10, bh0, aC); aD = MFMA(xh11, bh1, aD); \
        aA = MFMA(xh02, bh2, aA); aB = MFMA(xh03, bh3, aB); \
        aC = MFMA(xh12, bh2, aC); aD = MFMA(xh13, bh3, aD); \
        f32x4 d0 = aA + aB, d1 = aC + aD; \
        int cc = (TE) * 16 + c16; \
        if (cc < NATT * 8) { \
            float bt = btil[cc]; \
            int v = cc >> 3, h = cc & 7; \
            float* op = (v == 0) ? o0 : ((v == 1) ? o1 : o2); \
            if (r0 + 0 < N) op[(r0 + 0) * 8 + h] = d0[0] + bt; \
            if (r0 + 1 < N) op[(r0 + 1) * 8 + h] = d0[1] + bt; \
            if (r0 + 2 < N) op[(r0 + 2) * 8 + h] = d0[2] + bt; \
            if (r0 + 3 < N) op[(r0 + 3) * 8 + h] = d0[3] + bt; \
            if (r1 + 0 < N) op[(r1 + 0) * 8 + h] = d1[0] + bt; \
            if (r1 + 1 < N) op[(r1 + 1) * 8 + h] = d1[1] + bt; \
            if (r1 + 2 < N) op[(r1 + 2) * 8 + h] = d1[2] + bt; \
            if (r1 + 3 < N) op[(r1 + 3) * 8 + h] = d1[3] + bt; } }
    CT_ATT(0)
    if constexpr (NTE > 1) { CT_ATT(1) }
    #undef CT_ATT
}

// ---------------- K1: fused bucket scatter ----------------
__launch_bounds__(256)
__global__ void fused_scatter(const int* __restrict__ gg_src, const int* __restrict__ gg_dst,
                              const int* __restrict__ dg_src, const int* __restrict__ dg_dst,
                              int* __restrict__ bcnt, unsigned int* __restrict__ colPacked) {
    __shared__ int cnt[256], scanE[256], gbase[256], cursor[256];
    __shared__ int ss[256];
    __shared__ unsigned int sorted[S1_CH];
    __shared__ unsigned char bof[S1_CH];
    int t = threadIdx.x;
    cnt[t] = 0;
    __syncthreads();
    int base = blockIdx.x * S1_CH;
    for (int k = 0; k < S1_CH; k += 256) {
        int e = base + k + t;
        if (e < EALL) {
            int dn = (e < EGG) ? gg_dst[e] : (NG + dg_dst[e - EGG]);
            atomicAdd(&cnt[dn >> SHIFT], 1);
        }
    }
    __syncthreads();
    int v = cnt[t];
    ss[t] = v;
    __syncthreads();
    for (int off = 1; off < 256; off <<= 1) {
        int y = (t >= off) ? ss[t - off] : 0;
        __syncthreads();
        ss[t] += y;
        __syncthreads();
    }
    scanE[t] = ss[t] - v;
    cursor[t] = ss[t] - v;
    if (t < NBUK && v > 0) gbase[t] = atomicAdd(&bcnt[t], v);
    __syncthreads();
    for (int k = 0; k < S1_CH; k += 256) {
        int e = base + k + t;
        if (e < EALL) {
            int s, dn;
            if (e < EGG) { s = gg_src[e]; dn = gg_dst[e]; }
            else         { s = dg_src[e - EGG]; dn = NG + dg_dst[e - EGG]; }
            int b = dn >> SHIFT;
            int slot = atomicAdd(&cursor[b], 1);
            sorted[slot] = ((unsigned int)s << SHIFT) | (unsigned int)(dn & (BDSTS - 1));
            bof[slot] = (unsigned char)b;
        }
    }
    __syncthreads();
    int total = ss[255];
    for (int f = t; f < total; f += 256) {
        int b = bof[f];
        colPacked[(size_t)b * BUKCAP + gbase[b] + (f - scanE[b])] = sorted[f];
    }
}

// ---------------- K2: per-bucket build (absorbs the 98-bucket scan) ----------------
__launch_bounds__(256)
__global__ void bucket_build(const unsigned int* __restrict__ colPacked,
                             const int* __restrict__ bcnt,
                             int* __restrict__ rp, int* __restrict__ col) {
    __shared__ int lcur[BDSTS];
    __shared__ int tsum[256];
    __shared__ int bscan[128];
    int b = blockIdx.x;
    int t = threadIdx.x;
    if (t < 128) bscan[t] = (t < NBUK) ? bcnt[t] : 0;
    __syncthreads();
    for (int off = 1; off < 128; off <<= 1) {
        int y = 0;
        if (t < 128 && t >= off) y = bscan[t - off];
        __syncthreads();
        if (t < 128) bscan[t] += y;
        __syncthreads();
    }
    int gb = (b > 0) ? bscan[b - 1] : 0;
    int d0 = b << SHIFT;
    int nd = min(BDSTS, NALL - d0);
    int cnt = bcnt[b];
    const unsigned int* pk = colPacked + (size_t)b * BUKCAP;
    for (int i = t; i < BDSTS; i += 256) lcur[i] = 0;
    __syncthreads();
    for (int i = t; i < cnt; i += 256)
        atomicAdd(&lcur[pk[i] & (BDSTS - 1)], 1);
    __syncthreads();
    int h0 = lcur[t * 8 + 0], h1 = lcur[t * 8 + 1], h2 = lcur[t * 8 + 2], h3 = lcur[t * 8 + 3];
    int h4 = lcur[t * 8 + 4], h5 = lcur[t * 8 + 5], h6 = lcur[t * 8 + 6], h7 = lcur[t * 8 + 7];
    int tot = h0 + h1 + h2 + h3 + h4 + h5 + h6 + h7;
    tsum[t] = tot;
    __syncthreads();
    for (int off = 1; off < 256; off <<= 1) {
        int y = (t >= off) ? tsum[t - off] : 0;
        __syncthreads();
        tsum[t] += y;
        __syncthreads();
    }
    int pp = tsum[t] - tot + gb;
    __syncthreads();
    #define EMIT(J, HJ) { int idx = t * 8 + (J); \
        if (idx < nd) rp[d0 + idx] = pp; \
        lcur[idx] = pp; pp += (HJ); }
    EMIT(0, h0) EMIT(1, h1) EMIT(2, h2) EMIT(3, h3)
    EMIT(4, h4) EMIT(5, h5) EMIT(6, h6) EMIT(7, h7)
    #undef EMIT
    if (b == NBUK - 1 && t == 0) rp[NALL] = EALL;
    __syncthreads();
    for (int i = t; i < cnt; i += 256) {
        unsigned int p = pk[i];
        int pos = atomicAdd(&lcur[p & (BDSTS - 1)], 1);
        col[pos] = (int)(p >> SHIFT);
    }
}

// ---------------- gather v6 (restored from R11): colreg staging + shfl, no-max, fma_mix ----------------
__launch_bounds__(256)
__global__ void gat_gather_all(const int* __restrict__ rp, const int* __restrict__ col,
                               const float* __restrict__ as_gg, const float* __restrict__ ad_gg,
                               const unsigned short* __restrict__ xg_h,
                               const float* __restrict__ as_dg, const float* __restrict__ ad_dg,
                               const unsigned short* __restrict__ xd_h,
                               unsigned short* __restrict__ out_gg,
                               unsigned short* __restrict__ out_dg) {
    int wid = (blockIdx.x * 256 + threadIdx.x) >> 6;
    int l = threadIdx.x & 63;
    if (wid >= NALL) return;
    int isdg = wid >= NG;
    int d = isdg ? wid - NG : wid;
    const float* a_s = isdg ? as_dg : as_gg;
    const float* a_d = isdg ? ad_dg : ad_gg;
    const unsigned short* xbf = isdg ? xd_h : xg_h;
    unsigned short* outh = (isdg ? out_dg : out_gg);

    int base = rp[wid];
    int deg = rp[wid + 1] - base;

    int hl = l & 7;
    int g  = l >> 3;
    float adl = a_d[d * 8 + hl];
    // phase 1: ssum = sum exp(a)  (logits bounded |a|<~1.5 by construction: no max)
    float ssum = 0.f;
    for (int c0 = 0; c0 < deg; c0 += 64) {
        int myi = c0 + l;
        int colreg = (myi < deg) ? col[base + myi] : 0;
        int lim = min(deg - c0, 64);
        for (int t = g; t < lim; t += 8) {
            int s = __shfl(colreg, t);
            float a = a_s[s * 8 + hl] + adl;
            a = a > 0.f ? a : 0.2f * a;
            ssum += __expf(a);
        }
    }
    ssum += __shfl_xor(ssum, 8);
    ssum += __shfl_xor(ssum, 16);
    ssum += __shfl_xor(ssum, 32);
    float rsc = 1.f / (ssum + 1e-16f);

    // phase 2: quarter q = edge slot (4 edges/iter), cq = 8-col block (head hq)
    int q = l >> 4;
    int cq = l & 15;
    int hq = cq >> 1;
    uint32_t colbyte = (uint32_t)cq << 4;
    float a0 = 0.f, a1 = 0.f, a2 = 0.f, a3 = 0.f, a4 = 0.f, a5 = 0.f, a6 = 0.f, a7 = 0.f;
    for (int c0 = 0; c0 < deg; c0 += 64) {
        int myi = c0 + l;
        int colreg = (myi < deg) ? col[base + myi] : 0;
        int lim = min(deg - c0, 64);
        for (int j8 = 0; j8 < lim; j8 += 8) {
            float alpha;
            {
                int s = __shfl(colreg, j8 + g);
                float a = a_s[s * 8 + hl] + adl;
                a = a > 0.f ? a : 0.2f * a;
                alpha = __expf(a) * rsc;
            }
            int jlim = min(lim - j8, 8);
            #pragma unroll
            for (int sub = 0; sub < 8; sub += 4) {
                int jrel = sub + q;
                int s = __shfl(colreg, j8 + jrel);
                float al = __shfl(alpha, (jrel << 3) + hq);
                al = (jrel < jlim) ? al : 0.f;
                const uint4 rv = *(const uint4*)((const char*)xbf +
                                    (((size_t)(uint32_t)s << 8) + colbyte));
                FMAMIX_LO(a0, rv.x, al); FMAMIX_HI(a1, rv.x, al);
                FMAMIX_LO(a2, rv.y, al); FMAMIX_HI(a3, rv.y, al);
                FMAMIX_LO(a4, rv.z, al); FMAMIX_HI(a5, rv.z, al);
                FMAMIX_LO(a6, rv.w, al); FMAMIX_HI(a7, rv.w, al);
            }
        }
    }
    a0 += __shfl_xor(a0, 16); a0 += __shfl_xor(a0, 32);
    a1 += __shfl_xor(a1, 16); a1 += __shfl_xor(a1, 32);
    a2 += __shfl_xor(a2, 16); a2 += __shfl_xor(a2, 32);
    a3 += __shfl_xor(a3, 16); a3 += __shfl_xor(a3, 32);
    a4 += __shfl_xor(a4, 16); a4 += __shfl_xor(a4, 32);
    a5 += __shfl_xor(a5, 16); a5 += __shfl_xor(a5, 32);
    a6 += __shfl_xor(a6, 16); a6 += __shfl_xor(a6, 32);
    a7 += __shfl_xor(a7, 16); a7 += __shfl_xor(a7, 32);
    if (q == 0) {
        __half2 h01 = __floats2half2_rn(a0, a1);
        __half2 h23 = __floats2half2_rn(a2, a3);
        __half2 h45 = __floats2half2_rn(a4, a5);
        __half2 h67 = __floats2half2_rn(a6, a7);
        uint4 o;
        o.x = *(unsigned*)&h01; o.y = *(unsigned*)&h23;
        o.z = *(unsigned*)&h45; o.w = *(unsigned*)&h67;
        *(uint4*)((char*)outh + (size_t)d * 256 + cq * 16) = o;
    }
}

// ---------------- kmean via f16 MFMA (raw f16 rows, packed relu) ----------------
__launch_bounds__(256)
__global__ void kmean_mfma(const unsigned short* __restrict__ srcA,
                           const unsigned short* __restrict__ srcB,
                           const float* __restrict__ W, const float* __restrict__ bias,
                           float* __restrict__ kp) {
    __shared__ f16x8 Bs[8 * 4 * 64];
    for (int idx = threadIdx.x; idx < 128 * 32; idx += 256) {
        int row = idx >> 5, kq = idx & 31;
        f32x4 v = *(const f32x4*)&W[row * 128 + kq * 4];
        int ct = row >> 4, c = row & 15;
        int k0 = kq * 4;
        int kc = k0 >> 5, q16 = (k0 & 31) >> 3, j2 = (k0 & 7) >> 1;
        unsigned* dst = (unsigned*)&Bs[(ct * 4 + kc) * 64 + q16 * 16 + c];
        dst[j2]     = ((unsigned)f16_bits(v.y) << 16) | f16_bits(v.x);
        dst[j2 + 1] = ((unsigned)f16_bits(v.w) << 16) | f16_bits(v.z);
    }
    __syncthreads();
    int half = blockIdx.x >= KM_HALF;
    const unsigned short* src = half ? srcB : srcA;
    float* kpp = half ? (kp + 128) : kp;
    int rb = (half ? blockIdx.x - KM_HALF : blockIdx.x) * 128;
    int wv = threadIdx.x >> 6, l = threadIdx.x & 63;
    int q = l >> 4, c16 = l & 15;
    int rw = rb + wv * 32;
    const char* xr0 = (const char*)src + (size_t)(rw + c16) * 256 + q * 16;
    const char* xr1 = xr0 + 16 * 256;
    #define LOADA(F, PTR, OFF) f16x8 F; { \
        U4F16 u_; u_.u = *(const uint4*)((PTR) + (OFF)); \
        u_.u.x = relu_pk(u_.u.x); u_.u.y = relu_pk(u_.u.y); \
        u_.u.z = relu_pk(u_.u.z); u_.u.w = relu_pk(u_.u.w); \
        F = u_.f; }
    LOADA(f00, xr0, 0) LOADA(f01, xr0, 64) LOADA(f02, xr0, 128) LOADA(f03, xr0, 192)
    LOADA(f10, xr1, 0) LOADA(f11, xr1, 64) LOADA(f12, xr1, 128) LOADA(f13, xr1, 192)
    #undef LOADA
    float bv0 = bias[c16],      bv1 = bias[16 + c16], bv2 = bias[32 + c16], bv3 = bias[48 + c16];
    float bv4 = bias[64 + c16], bv5 = bias[80 + c16], bv6 = bias[96 + c16], bv7 = bias[112 + c16];
    int row0 = rw + q * 4;
    int row1 = row0 + 16;
    float cs0 = 0.f, cs1 = 0.f, cs2 = 0.f, cs3 = 0.f, cs4 = 0.f, cs5 = 0.f, cs6 = 0.f, cs7 = 0.f;
    #define CT_STEP(CT, CS, BV) { \
        f16x8 b0 = Bs[((CT) * 4 + 0) * 64 + l]; \
        f16x8 b1 = Bs[((CT) * 4 + 1) * 64 + l]; \
        f16x8 b2 = Bs[((CT) * 4 + 2) * 64 + l]; \
        f16x8 b3 = Bs[((CT) * 4 + 3) * 64 + l]; \
        f32x4 aA = {0,0,0,0}, aB = {0,0,0,0}, aC = {0,0,0,0}, aD = {0,0,0,0}; \
        aA = MFMAH(f00, b0, aA); aB = MFMAH(f01, b1, aB); \
        aA = MFMAH(f02, b2, aA); aB = MFMAH(f03, b3, aB); \
        aC = MFMAH(f10, b0, aC); aD = MFMAH(f11, b1, aD); \
        aC = MFMAH(f12, b2, aC); aD = MFMAH(f13, b3, aD); \
        f32x4 d0 = aA + aB, d1 = aC + aD; \
        float s = 0.f; \
        if (row0 + 0 < NG) s += fast_tanh(d0[0] + (BV)); \
        if (row0 + 1 < NG) s += fast_tanh(d0[1] + (BV)); \
        if (row0 + 2 < NG) s += fast_tanh(d0[2] + (BV)); \
        if (row0 + 3 < NG) s += fast_tanh(d0[3] + (BV)); \
        if (row1 + 0 < NG) s += fast_tanh(d1[0] + (BV)); \
        if (row1 + 1 < NG) s += fast_tanh(d1[1] + (BV)); \
        if (row1 + 2 < NG) s += fast_tanh(d1[2] + (BV)); \
        if (row1 + 3 < NG) s += fast_tanh(d1[3] + (BV)); \
        CS += s; }
    CT_STEP(0, cs0, bv0) CT_STEP(1, cs1, bv1) CT_STEP(2, cs2, bv2) CT_STEP(3, cs3, bv3)
    CT_STEP(4, cs4, bv4) CT_STEP(5, cs5, bv5) CT_STEP(6, cs6, bv6) CT_STEP(7, cs7, bv7)
    #undef CT_STEP
    __syncthreads();
    float* red = (float*)Bs;
    #define REDUCE_CT(CT, CS) { \
        float v = (CS); \
        v += __shfl_xor(v, 16); v += __shfl_xor(v, 32); \
        if (l < 16) red[wv * 128 + (CT) * 16 + l] = v; }
    REDUCE_CT(0, cs0) REDUCE_CT(1, cs1) REDUCE_CT(2, cs2) REDUCE_CT(3, cs3)
    REDUCE_CT(4, cs4) REDUCE_CT(5, cs5) REDUCE_CT(6, cs6) REDUCE_CT(7, cs7)
    #undef REDUCE_CT
    __syncthreads();
    if (threadIdx.x < 128) {
        float s = red[threadIdx.x] + red[128 + threadIdx.x]
                + red[256 + threadIdx.x] + red[384 + threadIdx.x];
        atomicAdd(&kpp[threadIdx.x], s);
    }
}

// ---------------- semantic softmax (2 scores) ----------------
__global__ void score_attn(const float* __restrict__ kpart, const float* __restrict__ q,
                           float* __restrict__ attn) {
    __shared__ float r0[128], r1[128];
    int t = threadIdx.x;
    r0[t] = q[t] * kpart[t];
    r1[t] = q[t] * kpart[128 + t];
    __syncthreads();
    for (int s = 64; s > 0; s >>= 1) {
        if (t < s) { r0[t] += r0[t + s]; r1[t] += r1[t + s]; }
        __syncthreads();
    }
    if (t == 0) {
        float s0 = r0[0] / (float)NG, s1 = r1[0] / (float)NG;
        float mx = fmaxf(s0, s1);
        float e0 = expf(s0 - mx), e1 = expf(s1 - mx);
        attn[0] = e0 / (e0 + e1);
        attn[1] = e1 / (e0 + e1);
    }
}

// ---------------- fused combine + final linear (f16 inputs) ----------------
__launch_bounds__(256)
__global__ void final_lin(const unsigned short* __restrict__ gg,
                          const unsigned short* __restrict__ dgb,
                          const float* __restrict__ attn, const float* __restrict__ lin_w,
                          const float* __restrict__ lin_b, float* __restrict__ outp) {
    int wid = (blockIdx.x * 256 + threadIdx.x) >> 6;
    int l = threadIdx.x & 63;
    if (wid >= NG) return;
    float a0 = attn[0], a1 = attn[1];
    unsigned gu = *(const unsigned*)((const char*)gg + (size_t)wid * 256 + l * 4);
    unsigned du = *(const unsigned*)((const char*)dgb + (size_t)wid * 256 + l * 4);
    float2 gv = __half22float2(*(const __half2*)&gu);
    float2 dv = __half22float2(*(const __half2*)&du);
    float fx = a0 * fmaxf(gv.x, 0.f) + a1 * fmaxf(dv.x, 0.f);
    float fy = a0 * fmaxf(gv.y, 0.f) + a1 * fmaxf(dv.y, 0.f);
    float2 w0 = *(const float2*)&lin_w[l * 2];
    float2 w1 = *(const float2*)&lin_w[128 + l * 2];
    float p0 = fx * w0.x + fy * w0.y;
    float p1 = fx * w1.x + fy * w1.y;
    for (int off = 32; off > 0; off >>= 1) {
        p0 += __shfl_down(p0, off);
        p1 += __shfl_down(p1, off);
    }
    if (l == 0) {
        float2 o;
        o.x = p0 + lin_b[0];
        o.y = p1 + lin_b[1];
        *(float2*)&outp[wid * 2] = o;
    }
}

extern "C" void kernel_launch(void* const* d_in, const int* in_sizes, int n_in,
                              void* d_out, int out_size, void* d_ws, size_t ws_size,
                              hipStream_t stream) {
    const float* x_gene    = (const float*)d_in[0];
    const float* x_disease = (const float*)d_in[1];
    const int*   edge_gg   = (const int*)d_in[2];
    const int*   edge_dg   = (const int*)d_in[3];
    const float* pg_w      = (const float*)d_in[4];
    const float* pg_b      = (const float*)d_in[5];
    const float* pd_w      = (const float*)d_in[6];
    const float* pd_b      = (const float*)d_in[7];
    const float* att_src_gg= (const float*)d_in[8];
    const float* att_dst_gg= (const float*)d_in[9];
    const float* att_src_dg= (const float*)d_in[10];
    const float* att_dst_dg= (const float*)d_in[11];
    const float* k_lin_w   = (const float*)d_in[12];
    const float* k_lin_b   = (const float*)d_in[13];
    const float* q         = (const float*)d_in[14];
    const float* lin_w     = (const float*)d_in[15];
    const float* lin_b     = (const float*)d_in[16];
    float* out = (float*)d_out;
    float* ws  = (float*)d_ws;

    unsigned short* out_gg = (unsigned short*)(ws + OFF_OUT_GG);
    unsigned short* out_dg = (unsigned short*)(ws + OFF_OUT_DG);
    unsigned int* colPacked = (unsigned int*)(ws + OFF_OUT_GG);  // overlay (dead before gather)
    unsigned short* xg_h = (unsigned short*)(ws + OFF_XG);
    unsigned short* xd_h = (unsigned short*)(ws + OFF_XD);
    float* a_src_gg = ws + OFF_ASG;
    float* a_dst_gg = ws + OFF_ADG;
    float* a_dst_dg = ws + OFF_ADD;
    float* a_src_dg = ws + OFF_ASD;
    float* kpart  = ws + OFF_KPART;
    float* attn   = ws + OFF_ATTN;
    float* wtilG  = ws + OFF_WTIL;
    float* btilG  = ws + OFF_BTIL;
    float* wtilD  = ws + OFF_WTILD;
    float* btilD  = ws + OFF_BTILD;
    int* bcnt  = (int*)(ws + OFF_BCNT);
    int* rp    = (int*)(ws + OFF_RP);
    int* col   = (int*)(ws + OFF_COL);

    const int* gg_src = edge_gg;
    const int* gg_dst = edge_gg + EGG;
    const int* dg_src = edge_dg;
    const int* dg_dst = edge_dg + EDG;

    // 1. zero kpart + bucket counters; wtilde precompute (single launch)
    hipLaunchKernelGGL(init_zero_k, dim3(2), dim3(256), 0, stream, ws + ZERO_BASE, ZERO_CNT);
    hipLaunchKernelGGL(make_wtil_both, dim3(12), dim3(256), 0, stream,
                       pg_w, pg_b, att_src_gg, att_dst_gg, att_dst_dg,
                       pd_w, pd_b, att_src_dg, wtilG, btilG, wtilD, btilD);
    // 2. split-bf16 MFMA projections (f16 table + fused logits)
    hipLaunchKernelGGL((proj_mfma<3>), dim3((NG + 127) / 128), dim3(256), 0, stream,
                       x_gene, pg_w, pg_b, wtilG, btilG, xg_h,
                       a_src_gg, a_dst_gg, a_dst_dg, NG);
    hipLaunchKernelGGL((proj_mfma<1>), dim3((ND + 127) / 128), dim3(256), 0, stream,
                       x_disease, pd_w, pd_b, wtilD, btilD, xd_h,
                       a_src_dg, (float*)nullptr, (float*)nullptr, ND);
    // 3. CSR build: fused scatter -> per-bucket build (scan folded in)
    hipLaunchKernelGGL(fused_scatter, dim3((EALL + S1_CH - 1) / S1_CH), dim3(256), 0, stream,
                       gg_src, gg_dst, dg_src, dg_dst, bcnt, colPacked);
    hipLaunchKernelGGL(bucket_build, dim3(NBUK), dim3(256), 0, stream,
                       colPacked, bcnt, rp, col);
    // 4. merged fused gather (out_gg overwrites colPacked overlay — dead by now)
    hipLaunchKernelGGL(gat_gather_all, dim3((NALL + 3) / 4), dim3(256), 0, stream,
                       rp, col, a_src_gg, a_dst_gg, xg_h, a_src_dg, a_dst_dg, xd_h,
                       out_gg, out_dg);
    // 5. semantic attention (f16 MFMA kmean)
    hipLaunchKernelGGL(kmean_mfma, dim3(KM_HALF * 2), dim3(256), 0, stream,
                       out_gg, out_dg, k_lin_w, k_lin_b, kpart);
    hipLaunchKernelGGL(score_attn, dim3(1), dim3(128), 0, stream, kpart, q, attn);
    // 6. fused combine + final linear (f16 reads)
    hipLaunchKernelGGL(final_lin, dim3((NG + 3) / 4), dim3(256), 0, stream,
                       out_gg, out_dg, attn, lin_w, lin_b, out);
}

// Round 15
// 332.395 us; speedup vs baseline: 1.2622x; 1.1188x over previous
//
#include <hip/hip_runtime.h>
#include <hip/hip_fp16.h>
#include <math.h>

#define NG 100000
#define ND 50000
#define EGG 1600000
#define EDG 800000
#define EALL (EGG + EDG)
#define NALL (NG + NG)
#define HID 128
#define NH 8

// bucket sort params (R15: SHIFT=10, S1_CH=3072; BUKCAP fixed 16384->18432:
// gg buckets have mean 1.6M*1024/100000 = 16384 exactly -> need slack; 18432 = +16 sigma)
#define SHIFT 10
#define BDSTS (1 << SHIFT)                    // 1024
#define NBUK  ((NALL + BDSTS - 1) / BDSTS)    // 196
#define BUKCAP 18432
#define S1_CH 3072
#define KM_HALF ((NG + 127) / 128)            // 782 blocks per metapath

// ---------------- workspace layout (4-byte element offsets) ----------------
#define OFF_OUT_GG 0UL          // f16 out_gg: 6,400,000 (colPacked overlay: 196*18432 = 3,612,672 u32)
#define OFF_OUT_DG 6400000UL    // f16 out_dg: 6,400,000
#define OFF_XG     12800000UL   // f16 xg: 6,400,000 -> ends 19,200,000
#define OFF_XD     19200000UL   // f16 xd: 3,200,000 -> ends 22,400,000
#define OFF_ASG    22400000UL   //   800,000
#define OFF_ADG    23200000UL   //   800,000
#define OFF_ADD    24000000UL   //   800,000
#define OFF_ASD    24800000UL   //   400,000 -> ends 25,200,000
#define OFF_KPART  25200000UL   //       256  (zero-init)
#define OFF_BCNT   25200256UL   //       256  (zero-init)
#define ZERO_BASE  OFF_KPART
#define ZERO_CNT   512
#define OFF_ATTN   25200768UL   //         2 (+pad)
#define OFF_RP     25200896UL   //   200,001 (+pad)
#define OFF_COL    25400960UL   // 2,400,000 -> ends 27,800,960
#define OFF_WTIL   27800960UL   //     3,072
#define OFF_BTIL   27804032UL   //        24
#define OFF_WTILD  27804160UL   //     1,024
#define OFF_BTILD  27805184UL   //         8
// end ~27,805,192 floats = 111 MB

typedef float  f32x4  __attribute__((ext_vector_type(4)));
typedef short  bf16x8 __attribute__((ext_vector_type(8)));
typedef _Float16 f16x8 __attribute__((ext_vector_type(8)));
#define MFMA(a, b, c)  __builtin_amdgcn_mfma_f32_16x16x32_bf16(a, b, c, 0, 0, 0)
#define MFMAH(a, b, c) __builtin_amdgcn_mfma_f32_16x16x32_f16(a, b, c, 0, 0, 0)

// acc += f16(lo/hi half of SRC u32) * AL   (single v_fma_mix_f32)
#define FMAMIX_LO(ACC, SRC, AL) \
    asm("v_fma_mix_f32 %0, %1, %2, %0 op_sel:[0,0,0] op_sel_hi:[1,0,0]" \
        : "+v"(ACC) : "v"(SRC), "v"(AL))
#define FMAMIX_HI(ACC, SRC, AL) \
    asm("v_fma_mix_f32 %0, %1, %2, %0 op_sel:[1,0,0] op_sel_hi:[1,0,0]" \
        : "+v"(ACC) : "v"(SRC), "v"(AL))

__device__ __forceinline__ unsigned short bf16_rne(float f) {
    unsigned u = __float_as_uint(f);
    u += 0x7FFFu + ((u >> 16) & 1u);
    return (unsigned short)(u >> 16);
}
__device__ __forceinline__ float bf16f(unsigned short h) {
    return __uint_as_float(((unsigned)h) << 16);
}
__device__ __forceinline__ unsigned short f16_bits(float f) {
    __half h = __float2half(f);
    return *(unsigned short*)&h;
}
__device__ __forceinline__ float fast_tanh(float x) {
    x = fminf(fmaxf(x, -15.f), 15.f);
    float t = __expf(2.f * x);
    return (t - 1.f) / (t + 1.f);
}
__device__ __forceinline__ bf16x8 cvt_hi8(f32x4 v0, f32x4 v1) {
    bf16x8 f;
    f[0] = (short)bf16_rne(v0.x); f[1] = (short)bf16_rne(v0.y);
    f[2] = (short)bf16_rne(v0.z); f[3] = (short)bf16_rne(v0.w);
    f[4] = (short)bf16_rne(v1.x); f[5] = (short)bf16_rne(v1.y);
    f[6] = (short)bf16_rne(v1.z); f[7] = (short)bf16_rne(v1.w);
    return f;
}
__device__ __forceinline__ bf16x8 cvt_lo8(f32x4 v0, f32x4 v1, bf16x8 h) {
    bf16x8 f;
    f[0] = (short)bf16_rne(v0.x - bf16f((unsigned short)h[0]));
    f[1] = (short)bf16_rne(v0.y - bf16f((unsigned short)h[1]));
    f[2] = (short)bf16_rne(v0.z - bf16f((unsigned short)h[2]));
    f[3] = (short)bf16_rne(v0.w - bf16f((unsigned short)h[3]));
    f[4] = (short)bf16_rne(v1.x - bf16f((unsigned short)h[4]));
    f[5] = (short)bf16_rne(v1.y - bf16f((unsigned short)h[5]));
    f[6] = (short)bf16_rne(v1.z - bf16f((unsigned short)h[6]));
    f[7] = (short)bf16_rne(v1.w - bf16f((unsigned short)h[7]));
    return f;
}
// packed relu on 2x f16 in a u32: zero any half with sign bit set
__device__ __forceinline__ unsigned relu_pk(unsigned u) {
    return u & ~(((u & 0x80008000u) >> 15) * 0xFFFFu);
}
union U4F16 { uint4 u; f16x8 f; };

// ---------------- init ----------------
__global__ void init_zero_k(float* __restrict__ p, int n) {
    int i = blockIdx.x * 256 + threadIdx.x;
    if (i < n) p[i] = 0.f;
}

// ---------------- wtilde (both node types in one launch) ----------------
__device__ __forceinline__ void wtil_body(const float* __restrict__ W,
                                          const float* __restrict__ bias,
                                          const float* __restrict__ a0,
                                          const float* __restrict__ a1,
                                          const float* __restrict__ a2, int natt,
                                          float* __restrict__ wtil, float* __restrict__ btil,
                                          int bid, int nblk) {
    int tot = natt * 8 * 128;
    for (int i = bid * 256 + threadIdx.x; i < tot; i += nblk * 256) {
        int k = i & 127, cc = i >> 7;
        int v = cc >> 3, h = cc & 7;
        const float* av = (v == 0) ? a0 : (v == 1) ? a1 : a2;
        float s = 0.f;
        #pragma unroll
        for (int c = 0; c < 16; c++) s += av[h * 16 + c] * W[(h * 16 + c) * 128 + k];
        wtil[i] = s;
    }
    if (bid == 0 && threadIdx.x < natt * 8) {
        int v = threadIdx.x >> 3, h = threadIdx.x & 7;
        const float* av = (v == 0) ? a0 : (v == 1) ? a1 : a2;
        float s = 0.f;
        #pragma unroll
        for (int c = 0; c < 16; c++) s += av[h * 16 + c] * bias[h * 16 + c];
        btil[threadIdx.x] = s;
    }
}

__global__ void make_wtil_both(const float* __restrict__ Wg, const float* __restrict__ bg,
                               const float* __restrict__ ag0, const float* __restrict__ ag1,
                               const float* __restrict__ ag2,
                               const float* __restrict__ Wd, const float* __restrict__ bd,
                               const float* __restrict__ ad0,
                               float* __restrict__ wtilG, float* __restrict__ btilG,
                               float* __restrict__ wtilD, float* __restrict__ btilD) {
    if (blockIdx.x < 8)
        wtil_body(Wg, bg, ag0, ag1, ag2, 3, wtilG, btilG, blockIdx.x, 8);
    else
        wtil_body(Wd, bd, ad0, ad0, ad0, 1, wtilD, btilD, blockIdx.x - 8, 4);
}

// ---------------- proj via split-bf16 MFMA (straight-line, scratch-free) ----------------
template<int NATT>
__launch_bounds__(256)
__global__ void proj_mfma(const float* __restrict__ x, const float* __restrict__ W,
                          const float* __restrict__ bias,
                          const float* __restrict__ wtil, const float* __restrict__ btil,
                          unsigned short* __restrict__ xbf,   // f16 [N][128]
                          float* __restrict__ o0, float* __restrict__ o1,
                          float* __restrict__ o2, int N) {
    constexpr int NTE = (NATT * 8 + 15) / 16;
    constexpr int NT = 8 + NTE;
    __shared__ bf16x8 Bhi[NT * 4 * 64];
    __shared__ bf16x8 Blo[8 * 4 * 64];
    for (int idx = threadIdx.x; idx < 128 * 32; idx += 256) {
        int row = idx >> 5, kq = idx & 31;
        f32x4 v = *(const f32x4*)&W[row * 128 + kq * 4];
        int ct = row >> 4, c = row & 15;
        int k0 = kq * 4;
        int kc = k0 >> 5, q16 = (k0 & 31) >> 3, j2 = (k0 & 7) >> 1;
        int slot = (ct * 4 + kc) * 64 + q16 * 16 + c;
        unsigned short hx = bf16_rne(v.x), hy = bf16_rne(v.y);
        unsigned short hz = bf16_rne(v.z), hw = bf16_rne(v.w);
        unsigned* dh = (unsigned*)&Bhi[slot];
        dh[j2]     = ((unsigned)hy << 16) | hx;
        dh[j2 + 1] = ((unsigned)hw << 16) | hz;
        unsigned* dl = (unsigned*)&Blo[slot];
        dl[j2]     = ((unsigned)bf16_rne(v.y - bf16f(hy)) << 16) | bf16_rne(v.x - bf16f(hx));
        dl[j2 + 1] = ((unsigned)bf16_rne(v.w - bf16f(hw)) << 16) | bf16_rne(v.z - bf16f(hz));
    }
    for (int idx = threadIdx.x; idx < NTE * 16 * 32; idx += 256) {
        int cc = idx >> 5, kq = idx & 31;
        f32x4 v = {0.f, 0.f, 0.f, 0.f};
        if (cc < NATT * 8) v = *(const f32x4*)&wtil[cc * 128 + kq * 4];
        int ct = 8 + (cc >> 4), c = cc & 15;
        int k0 = kq * 4;
        int kc = k0 >> 5, q16 = (k0 & 31) >> 3, j2 = (k0 & 7) >> 1;
        unsigned* dh = (unsigned*)&Bhi[(ct * 4 + kc) * 64 + q16 * 16 + c];
        dh[j2]     = ((unsigned)bf16_rne(v.y) << 16) | bf16_rne(v.x);
        dh[j2 + 1] = ((unsigned)bf16_rne(v.w) << 16) | bf16_rne(v.z);
    }
    __syncthreads();
    int wv = threadIdx.x >> 6, l = threadIdx.x & 63;
    int q = l >> 4, c16 = l & 15;
    int rw = blockIdx.x * 128 + wv * 32;
    int n0 = min(rw + c16, N - 1);
    int n1 = min(rw + 16 + c16, N - 1);
    const float* xr0 = &x[(size_t)n0 * 128 + q * 8];
    const float* xr1 = &x[(size_t)n1 * 128 + q * 8];
    #define LOADX(FH, FL, PTR, OFF) \
        bf16x8 FH, FL; \
        { f32x4 v0_ = *(const f32x4*)((PTR) + (OFF)); \
          f32x4 v1_ = *(const f32x4*)((PTR) + (OFF) + 4); \
          FH = cvt_hi8(v0_, v1_); FL = cvt_lo8(v0_, v1_, FH); }
    LOADX(xh00, xl00, xr0, 0)  LOADX(xh01, xl01, xr0, 32)
    LOADX(xh02, xl02, xr0, 64) LOADX(xh03, xl03, xr0, 96)
    LOADX(xh10, xl10, xr1, 0)  LOADX(xh11, xl11, xr1, 32)
    LOADX(xh12, xl12, xr1, 64) LOADX(xh13, xl13, xr1, 96)
    #undef LOADX
    int r0 = rw + q * 4;
    int r1 = r0 + 16;
    #define CT_MAIN(CT) { \
        bf16x8 bh0 = Bhi[((CT) * 4 + 0) * 64 + l]; \
        bf16x8 bh1 = Bhi[((CT) * 4 + 1) * 64 + l]; \
        bf16x8 bh2 = Bhi[((CT) * 4 + 2) * 64 + l]; \
        bf16x8 bh3 = Bhi[((CT) * 4 + 3) * 64 + l]; \
        bf16x8 bl0 = Blo[((CT) * 4 + 0) * 64 + l]; \
        bf16x8 bl1 = Blo[((CT) * 4 + 1) * 64 + l]; \
        bf16x8 bl2 = Blo[((CT) * 4 + 2) * 64 + l]; \
        bf16x8 bl3 = Blo[((CT) * 4 + 3) * 64 + l]; \
        f32x4 aA = {0,0,0,0}, aB = {0,0,0,0}, aC = {0,0,0,0}, aD = {0,0,0,0}; \
        aA = MFMA(xh00, bh0, aA); aB = MFMA(xh01, bh1, aB); \
        aC = MFMA(xh10, bh0, aC); aD = MFMA(xh11, bh1, aD); \
        aA = MFMA(xl00, bh0, aA); aB = MFMA(xl01, bh1, aB); \
        aC = MFMA(xl10, bh0, aC); aD = MFMA(xl11, bh1, aD); \
        aA = MFMA(xh00, bl0, aA); aB = MFMA(xh01, bl1, aB); \
        aC = MFMA(xh10, bl0, aC); aD = MFMA(xh11, bl1, aD); \
        aA = MFMA(xh02, bh2, aA); aB = MFMA(xh03, bh3, aB); \
        aC = MFMA(xh12, bh2, aC); aD = MFMA(xh13, bh3, aD); \
        aA = MFMA(xl02, bh2, aA); aB = MFMA(xl03, bh3, aB); \
        aC = MFMA(xl12, bh2, aC); aD = MFMA(xl13, bh3, aD); \
        aA = MFMA(xh02, bl2, aA); aB = MFMA(xh03, bl3, aB); \
        aC = MFMA(xh12, bl2, aC); aD = MFMA(xh13, bl3, aD); \
        f32x4 d0 = aA + aB, d1 = aC + aD; \
        float bv = bias[(CT) * 16 + c16]; \
        int col = (CT) * 16 + c16; \
        if (r0 + 0 < N) xbf[(size_t)(r0 + 0) * 128 + col] = f16_bits(d0[0] + bv); \
        if (r0 + 1 < N) xbf[(size_t)(r0 + 1) * 128 + col] = f16_bits(d0[1] + bv); \
        if (r0 + 2 < N) xbf[(size_t)(r0 + 2) * 128 + col] = f16_bits(d0[2] + bv); \
        if (r0 + 3 < N) xbf[(size_t)(r0 + 3) * 128 + col] = f16_bits(d0[3] + bv); \
        if (r1 + 0 < N) xbf[(size_t)(r1 + 0) * 128 + col] = f16_bits(d1[0] + bv); \
        if (r1 + 1 < N) xbf[(size_t)(r1 + 1) * 128 + col] = f16_bits(d1[1] + bv); \
        if (r1 + 2 < N) xbf[(size_t)(r1 + 2) * 128 + col] = f16_bits(d1[2] + bv); \
        if (r1 + 3 < N) xbf[(size_t)(r1 + 3) * 128 + col] = f16_bits(d1[3] + bv); }
    CT_MAIN(0) CT_MAIN(1) CT_MAIN(2) CT_MAIN(3)
    CT_MAIN(4) CT_MAIN(5) CT_MAIN(6) CT_MAIN(7)
    #undef CT_MAIN
    #define CT_ATT(TE) { \
        bf16x8 bh0 = Bhi[((8 + (TE)) * 4 + 0) * 64 + l]; \
        bf16x8 bh1 = Bhi[((8 + (TE)) * 4 + 1) * 64 + l]; \
        bf16x8 bh2 = Bhi[((8 + (TE)) * 4 + 2) * 64 + l]; \
        bf16x8 bh3 = Bhi[((8 + (TE)) * 4 + 3) * 64 + l]; \
        f32x4 aA = {0,0,0,0}, aB = {0,0,0,0}, aC = {0,0,0,0}, aD = {0,0,0,0}; \
        aA = MFMA(xh00, bh0, aA); aB = MFMA(xh01, bh1, aB); \
        aC = MFMA(xh10, bh0, aC); aD = MFMA(xh11, bh1, aD); \
        aA = MFMA(xh02, bh2, aA); aB = MFMA(xh03, bh3, aB); \
        aC = MFMA(xh12, bh2, aC); aD = MFMA(xh13, bh3, aD); \
        f32x4 d0 = aA + aB, d1 = aC + aD; \
        int cc = (TE) * 16 + c16; \
        if (cc < NATT * 8) { \
            float bt = btil[cc]; \
            int v = cc >> 3, h = cc & 7; \
            float* op = (v == 0) ? o0 : ((v == 1) ? o1 : o2); \
            if (r0 + 0 < N) op[(r0 + 0) * 8 + h] = d0[0] + bt; \
            if (r0 + 1 < N) op[(r0 + 1) * 8 + h] = d0[1] + bt; \
            if (r0 + 2 < N) op[(r0 + 2) * 8 + h] = d0[2] + bt; \
            if (r0 + 3 < N) op[(r0 + 3) * 8 + h] = d0[3] + bt; \
            if (r1 + 0 < N) op[(r1 + 0) * 8 + h] = d1[0] + bt; \
            if (r1 + 1 < N) op[(r1 + 1) * 8 + h] = d1[1] + bt; \
            if (r1 + 2 < N) op[(r1 + 2) * 8 + h] = d1[2] + bt; \
            if (r1 + 3 < N) op[(r1 + 3) * 8 + h] = d1[3] + bt; } }
    CT_ATT(0)
    if constexpr (NTE > 1) { CT_ATT(1) }
    #undef CT_ATT
}

// ---------------- K1: fused bucket scatter (782 blocks, 18KB LDS) ----------------
__launch_bounds__(256)
__global__ void fused_scatter(const int* __restrict__ gg_src, const int* __restrict__ gg_dst,
                              const int* __restrict__ dg_src, const int* __restrict__ dg_dst,
                              int* __restrict__ bcnt, unsigned int* __restrict__ colPacked) {
    __shared__ int cnt[256], scanE[256], gbase[256], cursor[256];
    __shared__ int ss[256];
    __shared__ unsigned int sorted[S1_CH];
    __shared__ unsigned char bof[S1_CH];
    int t = threadIdx.x;
    cnt[t] = 0;
    __syncthreads();
    int base = blockIdx.x * S1_CH;
    for (int k = 0; k < S1_CH; k += 256) {
        int e = base + k + t;
        if (e < EALL) {
            int dn = (e < EGG) ? gg_dst[e] : (NG + dg_dst[e - EGG]);
            atomicAdd(&cnt[dn >> SHIFT], 1);
        }
    }
    __syncthreads();
    int v = cnt[t];
    ss[t] = v;
    __syncthreads();
    for (int off = 1; off < 256; off <<= 1) {
        int y = (t >= off) ? ss[t - off] : 0;
        __syncthreads();
        ss[t] += y;
        __syncthreads();
    }
    scanE[t] = ss[t] - v;
    cursor[t] = ss[t] - v;
    if (t < NBUK && v > 0) gbase[t] = atomicAdd(&bcnt[t], v);
    __syncthreads();
    for (int k = 0; k < S1_CH; k += 256) {
        int e = base + k + t;
        if (e < EALL) {
            int s, dn;
            if (e < EGG) { s = gg_src[e]; dn = gg_dst[e]; }
            else         { s = dg_src[e - EGG]; dn = NG + dg_dst[e - EGG]; }
            int b = dn >> SHIFT;
            int slot = atomicAdd(&cursor[b], 1);
            sorted[slot] = ((unsigned int)s << SHIFT) | (unsigned int)(dn & (BDSTS - 1));
            bof[slot] = (unsigned char)b;
        }
    }
    __syncthreads();
    int total = ss[255];
    for (int f = t; f < total; f += 256) {
        int b = bof[f];
        colPacked[(size_t)b * BUKCAP + gbase[b] + (f - scanE[b])] = sorted[f];
    }
}

// ---------------- K2: per-bucket build (196 blocks; bucket scan folded in) ----------------
__launch_bounds__(256)
__global__ void bucket_build(const unsigned int* __restrict__ colPacked,
                             const int* __restrict__ bcnt,
                             int* __restrict__ rp, int* __restrict__ col) {
    __shared__ int lcur[BDSTS];
    __shared__ int tsum[256];
    __shared__ int bscan[256];
    int b = blockIdx.x;
    int t = threadIdx.x;
    bscan[t] = (t < NBUK) ? bcnt[t] : 0;
    __syncthreads();
    for (int off = 1; off < 256; off <<= 1) {
        int y = (t >= off) ? bscan[t - off] : 0;
        __syncthreads();
        bscan[t] += y;
        __syncthreads();
    }
    int gb = (b > 0) ? bscan[b - 1] : 0;
    int d0 = b << SHIFT;
    int nd = min(BDSTS, NALL - d0);
    int cnt = bcnt[b];
    const unsigned int* pk = colPacked + (size_t)b * BUKCAP;
    for (int i = t; i < BDSTS; i += 256) lcur[i] = 0;
    __syncthreads();
    for (int i = t; i < cnt; i += 256)
        atomicAdd(&lcur[pk[i] & (BDSTS - 1)], 1);
    __syncthreads();
    int h0 = lcur[t * 4 + 0], h1 = lcur[t * 4 + 1], h2 = lcur[t * 4 + 2], h3 = lcur[t * 4 + 3];
    int tot = h0 + h1 + h2 + h3;
    tsum[t] = tot;
    __syncthreads();
    for (int off = 1; off < 256; off <<= 1) {
        int y = (t >= off) ? tsum[t - off] : 0;
        __syncthreads();
        tsum[t] += y;
        __syncthreads();
    }
    int pp = tsum[t] - tot + gb;
    __syncthreads();
    #define EMIT(J, HJ) { int idx = t * 4 + (J); \
        if (idx < nd) rp[d0 + idx] = pp; \
        lcur[idx] = pp; pp += (HJ); }
    EMIT(0, h0) EMIT(1, h1) EMIT(2, h2) EMIT(3, h3)
    #undef EMIT
    if (b == NBUK - 1 && t == 0) rp[NALL] = EALL;
    __syncthreads();
    for (int i = t; i < cnt; i += 256) {
        unsigned int p = pk[i];
        int pos = atomicAdd(&lcur[p & (BDSTS - 1)], 1);
        col[pos] = (int)(p >> SHIFT);
    }
}

// ---------------- gather v6: colreg staging + shfl, no-max softmax, fma_mix, f16 in/out ----------------
__launch_bounds__(256)
__global__ void gat_gather_all(const int* __restrict__ rp, const int* __restrict__ col,
                               const float* __restrict__ as_gg, const float* __restrict__ ad_gg,
                               const unsigned short* __restrict__ xg_h,
                               const float* __restrict__ as_dg, const float* __restrict__ ad_dg,
                               const unsigned short* __restrict__ xd_h,
                               unsigned short* __restrict__ out_gg,
                               unsigned short* __restrict__ out_dg) {
    int wid = (blockIdx.x * 256 + threadIdx.x) >> 6;
    int l = threadIdx.x & 63;
    if (wid >= NALL) return;
    int isdg = wid >= NG;
    int d = isdg ? wid - NG : wid;
    const float* a_s = isdg ? as_dg : as_gg;
    const float* a_d = isdg ? ad_dg : ad_gg;
    const unsigned short* xbf = isdg ? xd_h : xg_h;
    unsigned short* outh = (isdg ? out_dg : out_gg);

    int base = rp[wid];
    int deg = rp[wid + 1] - base;

    int hl = l & 7;
    int g  = l >> 3;
    float adl = a_d[d * 8 + hl];
    // phase 1: ssum = sum exp(a)  (logits bounded |a|<~1.5 by construction: no max)
    float ssum = 0.f;
    for (int c0 = 0; c0 < deg; c0 += 64) {
        int myi = c0 + l;
        int colreg = (myi < deg) ? col[base + myi] : 0;
        int lim = min(deg - c0, 64);
        for (int t = g; t < lim; t += 8) {
            int s = __shfl(colreg, t);
            float a = a_s[s * 8 + hl] + adl;
            a = a > 0.f ? a : 0.2f * a;
            ssum += __expf(a);
        }
    }
    ssum += __shfl_xor(ssum, 8);
    ssum += __shfl_xor(ssum, 16);
    ssum += __shfl_xor(ssum, 32);
    float rsc = 1.f / (ssum + 1e-16f);

    // phase 2: quarter q = edge slot (4 edges/iter), cq = 8-col block (head hq)
    int q = l >> 4;
    int cq = l & 15;
    int hq = cq >> 1;
    uint32_t colbyte = (uint32_t)cq << 4;
    float a0 = 0.f, a1 = 0.f, a2 = 0.f, a3 = 0.f, a4 = 0.f, a5 = 0.f, a6 = 0.f, a7 = 0.f;
    for (int c0 = 0; c0 < deg; c0 += 64) {
        int myi = c0 + l;
        int colreg = (myi < deg) ? col[base + myi] : 0;
        int lim = min(deg - c0, 64);
        for (int j8 = 0; j8 < lim; j8 += 8) {
            float alpha;
            {
                int s = __shfl(colreg, j8 + g);
                float a = a_s[s * 8 + hl] + adl;
                a = a > 0.f ? a : 0.2f * a;
                alpha = __expf(a) * rsc;
            }
            int jlim = min(lim - j8, 8);
            #pragma unroll
            for (int sub = 0; sub < 8; sub += 4) {
                int jrel = sub + q;
                int s = __shfl(colreg, j8 + jrel);
                float al = __shfl(alpha, (jrel << 3) + hq);
                al = (jrel < jlim) ? al : 0.f;
                const uint4 rv = *(const uint4*)((const char*)xbf +
                                    (((size_t)(uint32_t)s << 8) + colbyte));
                FMAMIX_LO(a0, rv.x, al); FMAMIX_HI(a1, rv.x, al);
                FMAMIX_LO(a2, rv.y, al); FMAMIX_HI(a3, rv.y, al);
                FMAMIX_LO(a4, rv.z, al); FMAMIX_HI(a5, rv.z, al);
                FMAMIX_LO(a6, rv.w, al); FMAMIX_HI(a7, rv.w, al);
            }
        }
    }
    a0 += __shfl_xor(a0, 16); a0 += __shfl_xor(a0, 32);
    a1 += __shfl_xor(a1, 16); a1 += __shfl_xor(a1, 32);
    a2 += __shfl_xor(a2, 16); a2 += __shfl_xor(a2, 32);
    a3 += __shfl_xor(a3, 16); a3 += __shfl_xor(a3, 32);
    a4 += __shfl_xor(a4, 16); a4 += __shfl_xor(a4, 32);
    a5 += __shfl_xor(a5, 16); a5 += __shfl_xor(a5, 32);
    a6 += __shfl_xor(a6, 16); a6 += __shfl_xor(a6, 32);
    a7 += __shfl_xor(a7, 16); a7 += __shfl_xor(a7, 32);
    if (q == 0) {
        __half2 h01 = __floats2half2_rn(a0, a1);
        __half2 h23 = __floats2half2_rn(a2, a3);
        __half2 h45 = __floats2half2_rn(a4, a5);
        __half2 h67 = __floats2half2_rn(a6, a7);
        uint4 o;
        o.x = *(unsigned*)&h01; o.y = *(unsigned*)&h23;
        o.z = *(unsigned*)&h45; o.w = *(unsigned*)&h67;
        *(uint4*)((char*)outh + (size_t)d * 256 + cq * 16) = o;
    }
}

// ---------------- kmean via f16 MFMA (raw f16 rows, packed relu) ----------------
__launch_bounds__(256)
__global__ void kmean_mfma(const unsigned short* __restrict__ srcA,
                           const unsigned short* __restrict__ srcB,
                           const float* __restrict__ W, const float* __restrict__ bias,
                           float* __restrict__ kp) {
    __shared__ f16x8 Bs[8 * 4 * 64];
    for (int idx = threadIdx.x; idx < 128 * 32; idx += 256) {
        int row = idx >> 5, kq = idx & 31;
        f32x4 v = *(const f32x4*)&W[row * 128 + kq * 4];
        int ct = row >> 4, c = row & 15;
        int k0 = kq * 4;
        int kc = k0 >> 5, q16 = (k0 & 31) >> 3, j2 = (k0 & 7) >> 1;
        unsigned* dst = (unsigned*)&Bs[(ct * 4 + kc) * 64 + q16 * 16 + c];
        dst[j2]     = ((unsigned)f16_bits(v.y) << 16) | f16_bits(v.x);
        dst[j2 + 1] = ((unsigned)f16_bits(v.w) << 16) | f16_bits(v.z);
    }
    __syncthreads();
    int half = blockIdx.x >= KM_HALF;
    const unsigned short* src = half ? srcB : srcA;
    float* kpp = half ? (kp + 128) : kp;
    int rb = (half ? blockIdx.x - KM_HALF : blockIdx.x) * 128;
    int wv = threadIdx.x >> 6, l = threadIdx.x & 63;
    int q = l >> 4, c16 = l & 15;
    int rw = rb + wv * 32;
    const char* xr0 = (const char*)src + (size_t)(rw + c16) * 256 + q * 16;
    const char* xr1 = xr0 + 16 * 256;
    #define LOADA(F, PTR, OFF) f16x8 F; { \
        U4F16 u_; u_.u = *(const uint4*)((PTR) + (OFF)); \
        u_.u.x = relu_pk(u_.u.x); u_.u.y = relu_pk(u_.u.y); \
        u_.u.z = relu_pk(u_.u.z); u_.u.w = relu_pk(u_.u.w); \
        F = u_.f; }
    LOADA(f00, xr0, 0) LOADA(f01, xr0, 64) LOADA(f02, xr0, 128) LOADA(f03, xr0, 192)
    LOADA(f10, xr1, 0) LOADA(f11, xr1, 64) LOADA(f12, xr1, 128) LOADA(f13, xr1, 192)
    #undef LOADA
    float bv0 = bias[c16],      bv1 = bias[16 + c16], bv2 = bias[32 + c16], bv3 = bias[48 + c16];
    float bv4 = bias[64 + c16], bv5 = bias[80 + c16], bv6 = bias[96 + c16], bv7 = bias[112 + c16];
    int row0 = rw + q * 4;
    int row1 = row0 + 16;
    float cs0 = 0.f, cs1 = 0.f, cs2 = 0.f, cs3 = 0.f, cs4 = 0.f, cs5 = 0.f, cs6 = 0.f, cs7 = 0.f;
    #define CT_STEP(CT, CS, BV) { \
        f16x8 b0 = Bs[((CT) * 4 + 0) * 64 + l]; \
        f16x8 b1 = Bs[((CT) * 4 + 1) * 64 + l]; \
        f16x8 b2 = Bs[((CT) * 4 + 2) * 64 + l]; \
        f16x8 b3 = Bs[((CT) * 4 + 3) * 64 + l]; \
        f32x4 aA = {0,0,0,0}, aB = {0,0,0,0}, aC = {0,0,0,0}, aD = {0,0,0,0}; \
        aA = MFMAH(f00, b0, aA); aB = MFMAH(f01, b1, aB); \
        aA = MFMAH(f02, b2, aA); aB = MFMAH(f03, b3, aB); \
        aC = MFMAH(f10, b0, aC); aD = MFMAH(f11, b1, aD); \
        aC = MFMAH(f12, b2, aC); aD = MFMAH(f13, b3, aD); \
        f32x4 d0 = aA + aB, d1 = aC + aD; \
        float s = 0.f; \
        if (row0 + 0 < NG) s += fast_tanh(d0[0] + (BV)); \
        if (row0 + 1 < NG) s += fast_tanh(d0[1] + (BV)); \
        if (row0 + 2 < NG) s += fast_tanh(d0[2] + (BV)); \
        if (row0 + 3 < NG) s += fast_tanh(d0[3] + (BV)); \
        if (row1 + 0 < NG) s += fast_tanh(d1[0] + (BV)); \
        if (row1 + 1 < NG) s += fast_tanh(d1[1] + (BV)); \
        if (row1 + 2 < NG) s += fast_tanh(d1[2] + (BV)); \
        if (row1 + 3 < NG) s += fast_tanh(d1[3] + (BV)); \
        CS += s; }
    CT_STEP(0, cs0, bv0) CT_STEP(1, cs1, bv1) CT_STEP(2, cs2, bv2) CT_STEP(3, cs3, bv3)
    CT_STEP(4, cs4, bv4) CT_STEP(5, cs5, bv5) CT_STEP(6, cs6, bv6) CT_STEP(7, cs7, bv7)
    #undef CT_STEP
    __syncthreads();
    float* red = (float*)Bs;
    #define REDUCE_CT(CT, CS) { \
        float v = (CS); \
        v += __shfl_xor(v, 16); v += __shfl_xor(v, 32); \
        if (l < 16) red[wv * 128 + (CT) * 16 + l] = v; }
    REDUCE_CT(0, cs0) REDUCE_CT(1, cs1) REDUCE_CT(2, cs2) REDUCE_CT(3, cs3)
    REDUCE_CT(4, cs4) REDUCE_CT(5, cs5) REDUCE_CT(6, cs6) REDUCE_CT(7, cs7)
    #undef REDUCE_CT
    __syncthreads();
    if (threadIdx.x < 128) {
        float s = red[threadIdx.x] + red[128 + threadIdx.x]
                + red[256 + threadIdx.x] + red[384 + threadIdx.x];
        atomicAdd(&kpp[threadIdx.x], s);
    }
}

// ---------------- semantic softmax (2 scores) ----------------
__global__ void score_attn(const float* __restrict__ kpart, const float* __restrict__ q,
                           float* __restrict__ attn) {
    __shared__ float r0[128], r1[128];
    int t = threadIdx.x;
    r0[t] = q[t] * kpart[t];
    r1[t] = q[t] * kpart[128 + t];
    __syncthreads();
    for (int s = 64; s > 0; s >>= 1) {
        if (t < s) { r0[t] += r0[t + s]; r1[t] += r1[t + s]; }
        __syncthreads();
    }
    if (t == 0) {
        float s0 = r0[0] / (float)NG, s1 = r1[0] / (float)NG;
        float mx = fmaxf(s0, s1);
        float e0 = expf(s0 - mx), e1 = expf(s1 - mx);
        attn[0] = e0 / (e0 + e1);
        attn[1] = e1 / (e0 + e1);
    }
}

// ---------------- fused combine + final linear (f16 inputs) ----------------
__launch_bounds__(256)
__global__ void final_lin(const unsigned short* __restrict__ gg,
                          const unsigned short* __restrict__ dgb,
                          const float* __restrict__ attn, const float* __restrict__ lin_w,
                          const float* __restrict__ lin_b, float* __restrict__ outp) {
    int wid = (blockIdx.x * 256 + threadIdx.x) >> 6;
    int l = threadIdx.x & 63;
    if (wid >= NG) return;
    float a0 = attn[0], a1 = attn[1];
    unsigned gu = *(const unsigned*)((const char*)gg + (size_t)wid * 256 + l * 4);
    unsigned du = *(const unsigned*)((const char*)dgb + (size_t)wid * 256 + l * 4);
    float2 gv = __half22float2(*(const __half2*)&gu);
    float2 dv = __half22float2(*(const __half2*)&du);
    float fx = a0 * fmaxf(gv.x, 0.f) + a1 * fmaxf(dv.x, 0.f);
    float fy = a0 * fmaxf(gv.y, 0.f) + a1 * fmaxf(dv.y, 0.f);
    float2 w0 = *(const float2*)&lin_w[l * 2];
    float2 w1 = *(const float2*)&lin_w[128 + l * 2];
    float p0 = fx * w0.x + fy * w0.y;
    float p1 = fx * w1.x + fy * w1.y;
    for (int off = 32; off > 0; off >>= 1) {
        p0 += __shfl_down(p0, off);
        p1 += __shfl_down(p1, off);
    }
    if (l == 0) {
        float2 o;
        o.x = p0 + lin_b[0];
        o.y = p1 + lin_b[1];
        *(float2*)&outp[wid * 2] = o;
    }
}

extern "C" void kernel_launch(void* const* d_in, const int* in_sizes, int n_in,
                              void* d_out, int out_size, void* d_ws, size_t ws_size,
                              hipStream_t stream) {
    const float* x_gene    = (const float*)d_in[0];
    const float* x_disease = (const float*)d_in[1];
    const int*   edge_gg   = (const int*)d_in[2];
    const int*   edge_dg   = (const int*)d_in[3];
    const float* pg_w      = (const float*)d_in[4];
    const float* pg_b      = (const float*)d_in[5];
    const float* pd_w      = (const float*)d_in[6];
    const float* pd_b      = (const float*)d_in[7];
    const float* att_src_gg= (const float*)d_in[8];
    const float* att_dst_gg= (const float*)d_in[9];
    const float* att_src_dg= (const float*)d_in[10];
    const float* att_dst_dg= (const float*)d_in[11];
    const float* k_lin_w   = (const float*)d_in[12];
    const float* k_lin_b   = (const float*)d_in[13];
    const float* q         = (const float*)d_in[14];
    const float* lin_w     = (const float*)d_in[15];
    const float* lin_b     = (const float*)d_in[16];
    float* out = (float*)d_out;
    float* ws  = (float*)d_ws;

    unsigned short* out_gg = (unsigned short*)(ws + OFF_OUT_GG);
    unsigned short* out_dg = (unsigned short*)(ws + OFF_OUT_DG);
    unsigned int* colPacked = (unsigned int*)(ws + OFF_OUT_GG);  // overlay (dead before gather)
    unsigned short* xg_h = (unsigned short*)(ws + OFF_XG);
    unsigned short* xd_h = (unsigned short*)(ws + OFF_XD);
    float* a_src_gg = ws + OFF_ASG;
    float* a_dst_gg = ws + OFF_ADG;
    float* a_dst_dg = ws + OFF_ADD;
    float* a_src_dg = ws + OFF_ASD;
    float* kpart  = ws + OFF_KPART;
    float* attn   = ws + OFF_ATTN;
    float* wtilG  = ws + OFF_WTIL;
    float* btilG  = ws + OFF_BTIL;
    float* wtilD  = ws + OFF_WTILD;
    float* btilD  = ws + OFF_BTILD;
    int* bcnt  = (int*)(ws + OFF_BCNT);
    int* rp    = (int*)(ws + OFF_RP);
    int* col   = (int*)(ws + OFF_COL);

    const int* gg_src = edge_gg;
    const int* gg_dst = edge_gg + EGG;
    const int* dg_src = edge_dg;
    const int* dg_dst = edge_dg + EDG;

    // 1. zero kpart + bucket counters; wtilde precompute (single launch)
    hipLaunchKernelGGL(init_zero_k, dim3(2), dim3(256), 0, stream, ws + ZERO_BASE, ZERO_CNT);
    hipLaunchKernelGGL(make_wtil_both, dim3(12), dim3(256), 0, stream,
                       pg_w, pg_b, att_src_gg, att_dst_gg, att_dst_dg,
                       pd_w, pd_b, att_src_dg, wtilG, btilG, wtilD, btilD);
    // 2. split-bf16 MFMA projections (f16 table + fused logits)
    hipLaunchKernelGGL((proj_mfma<3>), dim3((NG + 127) / 128), dim3(256), 0, stream,
                       x_gene, pg_w, pg_b, wtilG, btilG, xg_h,
                       a_src_gg, a_dst_gg, a_dst_dg, NG);
    hipLaunchKernelGGL((proj_mfma<1>), dim3((ND + 127) / 128), dim3(256), 0, stream,
                       x_disease, pd_w, pd_b, wtilD, btilD, xd_h,
                       a_src_dg, (float*)nullptr, (float*)nullptr, ND);
    // 3. CSR build: fused scatter (782 blocks) -> per-bucket build (196 blocks)
    hipLaunchKernelGGL(fused_scatter, dim3((EALL + S1_CH - 1) / S1_CH), dim3(256), 0, stream,
                       gg_src, gg_dst, dg_src, dg_dst, bcnt, colPacked);
    hipLaunchKernelGGL(bucket_build, dim3(NBUK), dim3(256), 0, stream,
                       colPacked, bcnt, rp, col);
    // 4. merged fused gather (out_gg overwrites colPacked overlay — dead by now)
    hipLaunchKernelGGL(gat_gather_all, dim3((NALL + 3) / 4), dim3(256), 0, stream,
                       rp, col, a_src_gg, a_dst_gg, xg_h, a_src_dg, a_dst_dg, xd_h,
                       out_gg, out_dg);
    // 5. semantic attention (f16 MFMA kmean)
    hipLaunchKernelGGL(kmean_mfma, dim3(KM_HALF * 2), dim3(256), 0, stream,
                       out_gg, out_dg, k_lin_w, k_lin_b, kpart);
    hipLaunchKernelGGL(score_attn, dim3(1), dim3(128), 0, stream, kpart, q, attn);
    // 6. fused combine + final linear (f16 reads)
    hipLaunchKernelGGL(final_lin, dim3((NG + 3) / 4), dim3(256), 0, stream,
                       out_gg, out_dg, attn, lin_w, lin_b, out);
}

// Round 16
// 327.067 us; speedup vs baseline: 1.2827x; 1.0163x over previous
//
#include <hip/hip_runtime.h>
#include <hip/hip_fp16.h>
#include <math.h>

#define NG 100000
#define ND 50000
#define EGG 1600000
#define EDG 800000
#define EALL (EGG + EDG)
#define NALL (NG + NG)
#define HID 128
#define NH 8

// bucket sort params (validated R15: SHIFT=10, S1_CH=3072, BUKCAP=18432)
#define SHIFT 10
#define BDSTS (1 << SHIFT)                    // 1024
#define NBUK  ((NALL + BDSTS - 1) / BDSTS)    // 196
#define BUKCAP 18432
#define S1_CH 3072
#define KM_HALF ((NG + 127) / 128)            // 782 blocks per metapath

// ---------------- workspace layout (4-byte element offsets) ----------------
#define OFF_OUT_GG 0UL          // f16 out_gg: 6,400,000 (colPacked overlay: 196*18432 = 3,612,672 u32)
#define OFF_OUT_DG 6400000UL    // f16 out_dg: 6,400,000
#define OFF_XG     12800000UL   // f16 xg: 6,400,000 -> ends 19,200,000
#define OFF_XD     19200000UL   // f16 xd: 3,200,000 -> ends 22,400,000
#define OFF_ASG    22400000UL   //   800,000
#define OFF_ADG    23200000UL   //   800,000
#define OFF_ADD    24000000UL   //   800,000
#define OFF_ASD    24800000UL   //   400,000 -> ends 25,200,000
#define OFF_KPART  25200000UL   //       256  (zero-init)
#define OFF_BCNT   25200256UL   //       256  (zero-init)
#define ZERO_BASE  OFF_KPART
#define ZERO_CNT   512
#define OFF_ATTN   25200768UL   //         2 (+pad)
#define OFF_RP     25200896UL   //   200,001 (+pad)
#define OFF_COL    25400960UL   // 2,400,000 -> ends 27,800,960
#define OFF_WTIL   27800960UL   //     3,072
#define OFF_BTIL   27804032UL   //        24
#define OFF_WTILD  27804160UL   //     1,024
#define OFF_BTILD  27805184UL   //         8
// end ~27,805,192 floats = 111 MB

typedef float  f32x4  __attribute__((ext_vector_type(4)));
typedef short  bf16x8 __attribute__((ext_vector_type(8)));
typedef _Float16 f16x8 __attribute__((ext_vector_type(8)));
#define MFMA(a, b, c)  __builtin_amdgcn_mfma_f32_16x16x32_bf16(a, b, c, 0, 0, 0)
#define MFMAH(a, b, c) __builtin_amdgcn_mfma_f32_16x16x32_f16(a, b, c, 0, 0, 0)

// acc += f16(lo/hi half of SRC u32) * AL   (single v_fma_mix_f32)
#define FMAMIX_LO(ACC, SRC, AL) \
    asm("v_fma_mix_f32 %0, %1, %2, %0 op_sel:[0,0,0] op_sel_hi:[1,0,0]" \
        : "+v"(ACC) : "v"(SRC), "v"(AL))
#define FMAMIX_HI(ACC, SRC, AL) \
    asm("v_fma_mix_f32 %0, %1, %2, %0 op_sel:[1,0,0] op_sel_hi:[1,0,0]" \
        : "+v"(ACC) : "v"(SRC), "v"(AL))

__device__ __forceinline__ unsigned short bf16_rne(float f) {
    unsigned u = __float_as_uint(f);
    u += 0x7FFFu + ((u >> 16) & 1u);
    return (unsigned short)(u >> 16);
}
__device__ __forceinline__ float bf16f(unsigned short h) {
    return __uint_as_float(((unsigned)h) << 16);
}
__device__ __forceinline__ unsigned short f16_bits(float f) {
    __half h = __float2half(f);
    return *(unsigned short*)&h;
}
__device__ __forceinline__ float fast_tanh(float x) {
    x = fminf(fmaxf(x, -15.f), 15.f);
    float t = __expf(2.f * x);
    return (t - 1.f) / (t + 1.f);
}
__device__ __forceinline__ bf16x8 cvt_hi8(f32x4 v0, f32x4 v1) {
    bf16x8 f;
    f[0] = (short)bf16_rne(v0.x); f[1] = (short)bf16_rne(v0.y);
    f[2] = (short)bf16_rne(v0.z); f[3] = (short)bf16_rne(v0.w);
    f[4] = (short)bf16_rne(v1.x); f[5] = (short)bf16_rne(v1.y);
    f[6] = (short)bf16_rne(v1.z); f[7] = (short)bf16_rne(v1.w);
    return f;
}
__device__ __forceinline__ bf16x8 cvt_lo8(f32x4 v0, f32x4 v1, bf16x8 h) {
    bf16x8 f;
    f[0] = (short)bf16_rne(v0.x - bf16f((unsigned short)h[0]));
    f[1] = (short)bf16_rne(v0.y - bf16f((unsigned short)h[1]));
    f[2] = (short)bf16_rne(v0.z - bf16f((unsigned short)h[2]));
    f[3] = (short)bf16_rne(v0.w - bf16f((unsigned short)h[3]));
    f[4] = (short)bf16_rne(v1.x - bf16f((unsigned short)h[4]));
    f[5] = (short)bf16_rne(v1.y - bf16f((unsigned short)h[5]));
    f[6] = (short)bf16_rne(v1.z - bf16f((unsigned short)h[6]));
    f[7] = (short)bf16_rne(v1.w - bf16f((unsigned short)h[7]));
    return f;
}
// packed relu on 2x f16 in a u32: zero any half with sign bit set
__device__ __forceinline__ unsigned relu_pk(unsigned u) {
    return u & ~(((u & 0x80008000u) >> 15) * 0xFFFFu);
}
union U4F16 { uint4 u; f16x8 f; };

// ---------------- init ----------------
__global__ void init_zero_k(float* __restrict__ p, int n) {
    int i = blockIdx.x * 256 + threadIdx.x;
    if (i < n) p[i] = 0.f;
}

// ---------------- wtilde (both node types in one launch) ----------------
__device__ __forceinline__ void wtil_body(const float* __restrict__ W,
                                          const float* __restrict__ bias,
                                          const float* __restrict__ a0,
                                          const float* __restrict__ a1,
                                          const float* __restrict__ a2, int natt,
                                          float* __restrict__ wtil, float* __restrict__ btil,
                                          int bid, int nblk) {
    int tot = natt * 8 * 128;
    for (int i = bid * 256 + threadIdx.x; i < tot; i += nblk * 256) {
        int k = i & 127, cc = i >> 7;
        int v = cc >> 3, h = cc & 7;
        const float* av = (v == 0) ? a0 : (v == 1) ? a1 : a2;
        float s = 0.f;
        #pragma unroll
        for (int c = 0; c < 16; c++) s += av[h * 16 + c] * W[(h * 16 + c) * 128 + k];
        wtil[i] = s;
    }
    if (bid == 0 && threadIdx.x < natt * 8) {
        int v = threadIdx.x >> 3, h = threadIdx.x & 7;
        const float* av = (v == 0) ? a0 : (v == 1) ? a1 : a2;
        float s = 0.f;
        #pragma unroll
        for (int c = 0; c < 16; c++) s += av[h * 16 + c] * bias[h * 16 + c];
        btil[threadIdx.x] = s;
    }
}

__global__ void make_wtil_both(const float* __restrict__ Wg, const float* __restrict__ bg,
                               const float* __restrict__ ag0, const float* __restrict__ ag1,
                               const float* __restrict__ ag2,
                               const float* __restrict__ Wd, const float* __restrict__ bd,
                               const float* __restrict__ ad0,
                               float* __restrict__ wtilG, float* __restrict__ btilG,
                               float* __restrict__ wtilD, float* __restrict__ btilD) {
    if (blockIdx.x < 8)
        wtil_body(Wg, bg, ag0, ag1, ag2, 3, wtilG, btilG, blockIdx.x, 8);
    else
        wtil_body(Wd, bd, ad0, ad0, ad0, 1, wtilD, btilD, blockIdx.x - 8, 4);
}

// ---------------- proj via split-bf16 MFMA (straight-line, scratch-free) ----------------
template<int NATT>
__launch_bounds__(256)
__global__ void proj_mfma(const float* __restrict__ x, const float* __restrict__ W,
                          const float* __restrict__ bias,
                          const float* __restrict__ wtil, const float* __restrict__ btil,
                          unsigned short* __restrict__ xbf,   // f16 [N][128]
                          float* __restrict__ o0, float* __restrict__ o1,
                          float* __restrict__ o2, int N) {
    constexpr int NTE = (NATT * 8 + 15) / 16;
    constexpr int NT = 8 + NTE;
    __shared__ bf16x8 Bhi[NT * 4 * 64];
    __shared__ bf16x8 Blo[8 * 4 * 64];
    for (int idx = threadIdx.x; idx < 128 * 32; idx += 256) {
        int row = idx >> 5, kq = idx & 31;
        f32x4 v = *(const f32x4*)&W[row * 128 + kq * 4];
        int ct = row >> 4, c = row & 15;
        int k0 = kq * 4;
        int kc = k0 >> 5, q16 = (k0 & 31) >> 3, j2 = (k0 & 7) >> 1;
        int slot = (ct * 4 + kc) * 64 + q16 * 16 + c;
        unsigned short hx = bf16_rne(v.x), hy = bf16_rne(v.y);
        unsigned short hz = bf16_rne(v.z), hw = bf16_rne(v.w);
        unsigned* dh = (unsigned*)&Bhi[slot];
        dh[j2]     = ((unsigned)hy << 16) | hx;
        dh[j2 + 1] = ((unsigned)hw << 16) | hz;
        unsigned* dl = (unsigned*)&Blo[slot];
        dl[j2]     = ((unsigned)bf16_rne(v.y - bf16f(hy)) << 16) | bf16_rne(v.x - bf16f(hx));
        dl[j2 + 1] = ((unsigned)bf16_rne(v.w - bf16f(hw)) << 16) | bf16_rne(v.z - bf16f(hz));
    }
    for (int idx = threadIdx.x; idx < NTE * 16 * 32; idx += 256) {
        int cc = idx >> 5, kq = idx & 31;
        f32x4 v = {0.f, 0.f, 0.f, 0.f};
        if (cc < NATT * 8) v = *(const f32x4*)&wtil[cc * 128 + kq * 4];
        int ct = 8 + (cc >> 4), c = cc & 15;
        int k0 = kq * 4;
        int kc = k0 >> 5, q16 = (k0 & 31) >> 3, j2 = (k0 & 7) >> 1;
        unsigned* dh = (unsigned*)&Bhi[(ct * 4 + kc) * 64 + q16 * 16 + c];
        dh[j2]     = ((unsigned)bf16_rne(v.y) << 16) | bf16_rne(v.x);
        dh[j2 + 1] = ((unsigned)bf16_rne(v.w) << 16) | bf16_rne(v.z);
    }
    __syncthreads();
    int wv = threadIdx.x >> 6, l = threadIdx.x & 63;
    int q = l >> 4, c16 = l & 15;
    int rw = blockIdx.x * 128 + wv * 32;
    int n0 = min(rw + c16, N - 1);
    int n1 = min(rw + 16 + c16, N - 1);
    const float* xr0 = &x[(size_t)n0 * 128 + q * 8];
    const float* xr1 = &x[(size_t)n1 * 128 + q * 8];
    #define LOADX(FH, FL, PTR, OFF) \
        bf16x8 FH, FL; \
        { f32x4 v0_ = *(const f32x4*)((PTR) + (OFF)); \
          f32x4 v1_ = *(const f32x4*)((PTR) + (OFF) + 4); \
          FH = cvt_hi8(v0_, v1_); FL = cvt_lo8(v0_, v1_, FH); }
    LOADX(xh00, xl00, xr0, 0)  LOADX(xh01, xl01, xr0, 32)
    LOADX(xh02, xl02, xr0, 64) LOADX(xh03, xl03, xr0, 96)
    LOADX(xh10, xl10, xr1, 0)  LOADX(xh11, xl11, xr1, 32)
    LOADX(xh12, xl12, xr1, 64) LOADX(xh13, xl13, xr1, 96)
    #undef LOADX
    int r0 = rw + q * 4;
    int r1 = r0 + 16;
    #define CT_MAIN(CT) { \
        bf16x8 bh0 = Bhi[((CT) * 4 + 0) * 64 + l]; \
        bf16x8 bh1 = Bhi[((CT) * 4 + 1) * 64 + l]; \
        bf16x8 bh2 = Bhi[((CT) * 4 + 2) * 64 + l]; \
        bf16x8 bh3 = Bhi[((CT) * 4 + 3) * 64 + l]; \
        bf16x8 bl0 = Blo[((CT) * 4 + 0) * 64 + l]; \
        bf16x8 bl1 = Blo[((CT) * 4 + 1) * 64 + l]; \
        bf16x8 bl2 = Blo[((CT) * 4 + 2) * 64 + l]; \
        bf16x8 bl3 = Blo[((CT) * 4 + 3) * 64 + l]; \
        f32x4 aA = {0,0,0,0}, aB = {0,0,0,0}, aC = {0,0,0,0}, aD = {0,0,0,0}; \
        aA = MFMA(xh00, bh0, aA); aB = MFMA(xh01, bh1, aB); \
        aC = MFMA(xh10, bh0, aC); aD = MFMA(xh11, bh1, aD); \
        aA = MFMA(xl00, bh0, aA); aB = MFMA(xl01, bh1, aB); \
        aC = MFMA(xl10, bh0, aC); aD = MFMA(xl11, bh1, aD); \
        aA = MFMA(xh00, bl0, aA); aB = MFMA(xh01, bl1, aB); \
        aC = MFMA(xh10, bl0, aC); aD = MFMA(xh11, bl1, aD); \
        aA = MFMA(xh02, bh2, aA); aB = MFMA(xh03, bh3, aB); \
        aC = MFMA(xh12, bh2, aC); aD = MFMA(xh13, bh3, aD); \
        aA = MFMA(xl02, bh2, aA); aB = MFMA(xl03, bh3, aB); \
        aC = MFMA(xl12, bh2, aC); aD = MFMA(xl13, bh3, aD); \
        aA = MFMA(xh02, bl2, aA); aB = MFMA(xh03, bl3, aB); \
        aC = MFMA(xh12, bl2, aC); aD = MFMA(xh13, bl3, aD); \
        f32x4 d0 = aA + aB, d1 = aC + aD; \
        float bv = bias[(CT) * 16 + c16]; \
        int col = (CT) * 16 + c16; \
        if (r0 + 0 < N) xbf[(size_t)(r0 + 0) * 128 + col] = f16_bits(d0[0] + bv); \
        if (r0 + 1 < N) xbf[(size_t)(r0 + 1) * 128 + col] = f16_bits(d0[1] + bv); \
        if (r0 + 2 < N) xbf[(size_t)(r0 + 2) * 128 + col] = f16_bits(d0[2] + bv); \
        if (r0 + 3 < N) xbf[(size_t)(r0 + 3) * 128 + col] = f16_bits(d0[3] + bv); \
        if (r1 + 0 < N) xbf[(size_t)(r1 + 0) * 128 + col] = f16_bits(d1[0] + bv); \
        if (r1 + 1 < N) xbf[(size_t)(r1 + 1) * 128 + col] = f16_bits(d1[1] + bv); \
        if (r1 + 2 < N) xbf[(size_t)(r1 + 2) * 128 + col] = f16_bits(d1[2] + bv); \
        if (r1 + 3 < N) xbf[(size_t)(r1 + 3) * 128 + col] = f16_bits(d1[3] + bv); }
    CT_MAIN(0) CT_MAIN(1) CT_MAIN(2) CT_MAIN(3)
    CT_MAIN(4) CT_MAIN(5) CT_MAIN(6) CT_MAIN(7)
    #undef CT_MAIN
    #define CT_ATT(TE) { \
        bf16x8 bh0 = Bhi[((8 + (TE)) * 4 + 0) * 64 + l]; \
        bf16x8 bh1 = Bhi[((8 + (TE)) * 4 + 1) * 64 + l]; \
        bf16x8 bh2 = Bhi[((8 + (TE)) * 4 + 2) * 64 + l]; \
        bf16x8 bh3 = Bhi[((8 + (TE)) * 4 + 3) * 64 + l]; \
        f32x4 aA = {0,0,0,0}, aB = {0,0,0,0}, aC = {0,0,0,0}, aD = {0,0,0,0}; \
        aA = MFMA(xh00, bh0, aA); aB = MFMA(xh01, bh1, aB); \
        aC = MFMA(xh10, bh0, aC); aD = MFMA(xh11, bh1, aD); \
        aA = MFMA(xh02, bh2, aA); aB = MFMA(xh03, bh3, aB); \
        aC = MFMA(xh12, bh2, aC); aD = MFMA(xh13, bh3, aD); \
        f32x4 d0 = aA + aB, d1 = aC + aD; \
        int cc = (TE) * 16 + c16; \
        if (cc < NATT * 8) { \
            float bt = btil[cc]; \
            int v = cc >> 3, h = cc & 7; \
            float* op = (v == 0) ? o0 : ((v == 1) ? o1 : o2); \
            if (r0 + 0 < N) op[(r0 + 0) * 8 + h] = d0[0] + bt; \
            if (r0 + 1 < N) op[(r0 + 1) * 8 + h] = d0[1] + bt; \
            if (r0 + 2 < N) op[(r0 + 2) * 8 + h] = d0[2] + bt; \
            if (r0 + 3 < N) op[(r0 + 3) * 8 + h] = d0[3] + bt; \
            if (r1 + 0 < N) op[(r1 + 0) * 8 + h] = d1[0] + bt; \
            if (r1 + 1 < N) op[(r1 + 1) * 8 + h] = d1[1] + bt; \
            if (r1 + 2 < N) op[(r1 + 2) * 8 + h] = d1[2] + bt; \
            if (r1 + 3 < N) op[(r1 + 3) * 8 + h] = d1[3] + bt; } }
    CT_ATT(0)
    if constexpr (NTE > 1) { CT_ATT(1) }
    #undef CT_ATT
}

// ---------------- K1: fused bucket scatter (782 blocks, 18KB LDS) ----------------
__launch_bounds__(256)
__global__ void fused_scatter(const int* __restrict__ gg_src, const int* __restrict__ gg_dst,
                              const int* __restrict__ dg_src, const int* __restrict__ dg_dst,
                              int* __restrict__ bcnt, unsigned int* __restrict__ colPacked) {
    __shared__ int cnt[256], scanE[256], gbase[256], cursor[256];
    __shared__ int ss[256];
    __shared__ unsigned int sorted[S1_CH];
    __shared__ unsigned char bof[S1_CH];
    int t = threadIdx.x;
    cnt[t] = 0;
    __syncthreads();
    int base = blockIdx.x * S1_CH;
    for (int k = 0; k < S1_CH; k += 256) {
        int e = base + k + t;
        if (e < EALL) {
            int dn = (e < EGG) ? gg_dst[e] : (NG + dg_dst[e - EGG]);
            atomicAdd(&cnt[dn >> SHIFT], 1);
        }
    }
    __syncthreads();
    int v = cnt[t];
    ss[t] = v;
    __syncthreads();
    for (int off = 1; off < 256; off <<= 1) {
        int y = (t >= off) ? ss[t - off] : 0;
        __syncthreads();
        ss[t] += y;
        __syncthreads();
    }
    scanE[t] = ss[t] - v;
    cursor[t] = ss[t] - v;
    if (t < NBUK && v > 0) gbase[t] = atomicAdd(&bcnt[t], v);
    __syncthreads();
    for (int k = 0; k < S1_CH; k += 256) {
        int e = base + k + t;
        if (e < EALL) {
            int s, dn;
            if (e < EGG) { s = gg_src[e]; dn = gg_dst[e]; }
            else         { s = dg_src[e - EGG]; dn = NG + dg_dst[e - EGG]; }
            int b = dn >> SHIFT;
            int slot = atomicAdd(&cursor[b], 1);
            sorted[slot] = ((unsigned int)s << SHIFT) | (unsigned int)(dn & (BDSTS - 1));
            bof[slot] = (unsigned char)b;
        }
    }
    __syncthreads();
    int total = ss[255];
    for (int f = t; f < total; f += 256) {
        int b = bof[f];
        colPacked[(size_t)b * BUKCAP + gbase[b] + (f - scanE[b])] = sorted[f];
    }
}

// ---------------- K2: per-bucket build (196 blocks; bucket scan folded in) ----------------
__launch_bounds__(256)
__global__ void bucket_build(const unsigned int* __restrict__ colPacked,
                             const int* __restrict__ bcnt,
                             int* __restrict__ rp, int* __restrict__ col) {
    __shared__ int lcur[BDSTS];
    __shared__ int tsum[256];
    __shared__ int bscan[256];
    int b = blockIdx.x;
    int t = threadIdx.x;
    bscan[t] = (t < NBUK) ? bcnt[t] : 0;
    __syncthreads();
    for (int off = 1; off < 256; off <<= 1) {
        int y = (t >= off) ? bscan[t - off] : 0;
        __syncthreads();
        bscan[t] += y;
        __syncthreads();
    }
    int gb = (b > 0) ? bscan[b - 1] : 0;
    int d0 = b << SHIFT;
    int nd = min(BDSTS, NALL - d0);
    int cnt = bcnt[b];
    const unsigned int* pk = colPacked + (size_t)b * BUKCAP;
    for (int i = t; i < BDSTS; i += 256) lcur[i] = 0;
    __syncthreads();
    for (int i = t; i < cnt; i += 256)
        atomicAdd(&lcur[pk[i] & (BDSTS - 1)], 1);
    __syncthreads();
    int h0 = lcur[t * 4 + 0], h1 = lcur[t * 4 + 1], h2 = lcur[t * 4 + 2], h3 = lcur[t * 4 + 3];
    int tot = h0 + h1 + h2 + h3;
    tsum[t] = tot;
    __syncthreads();
    for (int off = 1; off < 256; off <<= 1) {
        int y = (t >= off) ? tsum[t - off] : 0;
        __syncthreads();
        tsum[t] += y;
        __syncthreads();
    }
    int pp = tsum[t] - tot + gb;
    __syncthreads();
    #define EMIT(J, HJ) { int idx = t * 4 + (J); \
        if (idx < nd) rp[d0 + idx] = pp; \
        lcur[idx] = pp; pp += (HJ); }
    EMIT(0, h0) EMIT(1, h1) EMIT(2, h2) EMIT(3, h3)
    #undef EMIT
    if (b == NBUK - 1 && t == 0) rp[NALL] = EALL;
    __syncthreads();
    for (int i = t; i < cnt; i += 256) {
        unsigned int p = pk[i];
        int pos = atomicAdd(&lcur[p & (BDSTS - 1)], 1);
        col[pos] = (int)(p >> SHIFT);
    }
}

// ---------------- gather v8: SINGLE-PASS fused softmax+accumulate (no phase 1) ----------------
__launch_bounds__(256)
__global__ void gat_gather_all(const int* __restrict__ rp, const int* __restrict__ col,
                               const float* __restrict__ as_gg, const float* __restrict__ ad_gg,
                               const unsigned short* __restrict__ xg_h,
                               const float* __restrict__ as_dg, const float* __restrict__ ad_dg,
                               const unsigned short* __restrict__ xd_h,
                               unsigned short* __restrict__ out_gg,
                               unsigned short* __restrict__ out_dg) {
    int wid = (blockIdx.x * 256 + threadIdx.x) >> 6;
    int l = threadIdx.x & 63;
    if (wid >= NALL) return;
    int isdg = wid >= NG;
    int d = isdg ? wid - NG : wid;
    const float* a_s = isdg ? as_dg : as_gg;
    const float* a_d = isdg ? ad_dg : ad_gg;
    const unsigned short* xbf = isdg ? xd_h : xg_h;
    unsigned short* outh = (isdg ? out_dg : out_gg);

    int base = rp[wid];
    int deg = rp[wid + 1] - base;

    int hl = l & 7;          // head for batch-alpha computation
    int g  = l >> 3;         // edge subgroup for batch-alpha
    float adl = a_d[d * 8 + hl];
    int q = l >> 4;          // edge slot (4 edges/group)
    int cq = l & 15;         // 8-col block (head hq)
    int hq = cq >> 1;
    uint32_t colbyte = (uint32_t)cq << 4;
    // single pass: accumulate UNNORMALIZED weighted sum + denominator together.
    // (no-max softmax is linear in exp(a); logits bounded |a|<~1.5 by construction)
    float a0 = 0.f, a1 = 0.f, a2 = 0.f, a3 = 0.f, a4 = 0.f, a5 = 0.f, a6 = 0.f, a7 = 0.f;
    float sacc = 0.f;
    for (int c0 = 0; c0 < deg; c0 += 64) {
        int myi = c0 + l;
        int colreg = (myi < deg) ? col[base + myi] : 0;
        int lim = min(deg - c0, 64);
        for (int j8 = 0; j8 < lim; j8 += 8) {
            float ex;
            {
                int s = __shfl(colreg, j8 + g);
                float a = a_s[s * 8 + hl] + adl;
                a = a > 0.f ? a : 0.2f * a;
                ex = __expf(a);   // unnormalized weight for (edge j8+g, head hl)
            }
            int jlim = min(lim - j8, 8);
            #pragma unroll
            for (int sub = 0; sub < 8; sub += 4) {
                int jrel = sub + q;
                int s = __shfl(colreg, j8 + jrel);
                float al = __shfl(ex, (jrel << 3) + hq);
                al = (jrel < jlim) ? al : 0.f;
                sacc += al;
                const uint4 rv = *(const uint4*)((const char*)xbf +
                                    (((size_t)(uint32_t)s << 8) + colbyte));
                FMAMIX_LO(a0, rv.x, al); FMAMIX_HI(a1, rv.x, al);
                FMAMIX_LO(a2, rv.y, al); FMAMIX_HI(a3, rv.y, al);
                FMAMIX_LO(a4, rv.z, al); FMAMIX_HI(a5, rv.z, al);
                FMAMIX_LO(a6, rv.w, al); FMAMIX_HI(a7, rv.w, al);
            }
        }
    }
    // reduce accumulators and denominator across the 4 edge-slot groups
    sacc += __shfl_xor(sacc, 16); sacc += __shfl_xor(sacc, 32);
    a0 += __shfl_xor(a0, 16); a0 += __shfl_xor(a0, 32);
    a1 += __shfl_xor(a1, 16); a1 += __shfl_xor(a1, 32);
    a2 += __shfl_xor(a2, 16); a2 += __shfl_xor(a2, 32);
    a3 += __shfl_xor(a3, 16); a3 += __shfl_xor(a3, 32);
    a4 += __shfl_xor(a4, 16); a4 += __shfl_xor(a4, 32);
    a5 += __shfl_xor(a5, 16); a5 += __shfl_xor(a5, 32);
    a6 += __shfl_xor(a6, 16); a6 += __shfl_xor(a6, 32);
    a7 += __shfl_xor(a7, 16); a7 += __shfl_xor(a7, 32);
    if (q == 0) {
        float rsc = 1.f / (sacc + 1e-16f);   // deg==0: 0 * 1e16 = 0 (exact zeros)
        a0 *= rsc; a1 *= rsc; a2 *= rsc; a3 *= rsc;
        a4 *= rsc; a5 *= rsc; a6 *= rsc; a7 *= rsc;
        __half2 h01 = __floats2half2_rn(a0, a1);
        __half2 h23 = __floats2half2_rn(a2, a3);
        __half2 h45 = __floats2half2_rn(a4, a5);
        __half2 h67 = __floats2half2_rn(a6, a7);
        uint4 o;
        o.x = *(unsigned*)&h01; o.y = *(unsigned*)&h23;
        o.z = *(unsigned*)&h45; o.w = *(unsigned*)&h67;
        *(uint4*)((char*)outh + (size_t)d * 256 + cq * 16) = o;
    }
}

// ---------------- kmean via f16 MFMA (raw f16 rows, packed relu) ----------------
__launch_bounds__(256)
__global__ void kmean_mfma(const unsigned short* __restrict__ srcA,
                           const unsigned short* __restrict__ srcB,
                           const float* __restrict__ W, const float* __restrict__ bias,
                           float* __restrict__ kp) {
    __shared__ f16x8 Bs[8 * 4 * 64];
    for (int idx = threadIdx.x; idx < 128 * 32; idx += 256) {
        int row = idx >> 5, kq = idx & 31;
        f32x4 v = *(const f32x4*)&W[row * 128 + kq * 4];
        int ct = row >> 4, c = row & 15;
        int k0 = kq * 4;
        int kc = k0 >> 5, q16 = (k0 & 31) >> 3, j2 = (k0 & 7) >> 1;
        unsigned* dst = (unsigned*)&Bs[(ct * 4 + kc) * 64 + q16 * 16 + c];
        dst[j2]     = ((unsigned)f16_bits(v.y) << 16) | f16_bits(v.x);
        dst[j2 + 1] = ((unsigned)f16_bits(v.w) << 16) | f16_bits(v.z);
    }
    __syncthreads();
    int half = blockIdx.x >= KM_HALF;
    const unsigned short* src = half ? srcB : srcA;
    float* kpp = half ? (kp + 128) : kp;
    int rb = (half ? blockIdx.x - KM_HALF : blockIdx.x) * 128;
    int wv = threadIdx.x >> 6, l = threadIdx.x & 63;
    int q = l >> 4, c16 = l & 15;
    int rw = rb + wv * 32;
    const char* xr0 = (const char*)src + (size_t)(rw + c16) * 256 + q * 16;
    const char* xr1 = xr0 + 16 * 256;
    #define LOADA(F, PTR, OFF) f16x8 F; { \
        U4F16 u_; u_.u = *(const uint4*)((PTR) + (OFF)); \
        u_.u.x = relu_pk(u_.u.x); u_.u.y = relu_pk(u_.u.y); \
        u_.u.z = relu_pk(u_.u.z); u_.u.w = relu_pk(u_.u.w); \
        F = u_.f; }
    LOADA(f00, xr0, 0) LOADA(f01, xr0, 64) LOADA(f02, xr0, 128) LOADA(f03, xr0, 192)
    LOADA(f10, xr1, 0) LOADA(f11, xr1, 64) LOADA(f12, xr1, 128) LOADA(f13, xr1, 192)
    #undef LOADA
    float bv0 = bias[c16],      bv1 = bias[16 + c16], bv2 = bias[32 + c16], bv3 = bias[48 + c16];
    float bv4 = bias[64 + c16], bv5 = bias[80 + c16], bv6 = bias[96 + c16], bv7 = bias[112 + c16];
    int row0 = rw + q * 4;
    int row1 = row0 + 16;
    float cs0 = 0.f, cs1 = 0.f, cs2 = 0.f, cs3 = 0.f, cs4 = 0.f, cs5 = 0.f, cs6 = 0.f, cs7 = 0.f;
    #define CT_STEP(CT, CS, BV) { \
        f16x8 b0 = Bs[((CT) * 4 + 0) * 64 + l]; \
        f16x8 b1 = Bs[((CT) * 4 + 1) * 64 + l]; \
        f16x8 b2 = Bs[((CT) * 4 + 2) * 64 + l]; \
        f16x8 b3 = Bs[((CT) * 4 + 3) * 64 + l]; \
        f32x4 aA = {0,0,0,0}, aB = {0,0,0,0}, aC = {0,0,0,0}, aD = {0,0,0,0}; \
        aA = MFMAH(f00, b0, aA); aB = MFMAH(f01, b1, aB); \
        aA = MFMAH(f02, b2, aA); aB = MFMAH(f03, b3, aB); \
        aC = MFMAH(f10, b0, aC); aD = MFMAH(f11, b1, aD); \
        aC = MFMAH(f12, b2, aC); aD = MFMAH(f13, b3, aD); \
        f32x4 d0 = aA + aB, d1 = aC + aD; \
        float s = 0.f; \
        if (row0 + 0 < NG) s += fast_tanh(d0[0] + (BV)); \
        if (row0 + 1 < NG) s += fast_tanh(d0[1] + (BV)); \
        if (row0 + 2 < NG) s += fast_tanh(d0[2] + (BV)); \
        if (row0 + 3 < NG) s += fast_tanh(d0[3] + (BV)); \
        if (row1 + 0 < NG) s += fast_tanh(d1[0] + (BV)); \
        if (row1 + 1 < NG) s += fast_tanh(d1[1] + (BV)); \
        if (row1 + 2 < NG) s += fast_tanh(d1[2] + (BV)); \
        if (row1 + 3 < NG) s += fast_tanh(d1[3] + (BV)); \
        CS += s; }
    CT_STEP(0, cs0, bv0) CT_STEP(1, cs1, bv1) CT_STEP(2, cs2, bv2) CT_STEP(3, cs3, bv3)
    CT_STEP(4, cs4, bv4) CT_STEP(5, cs5, bv5) CT_STEP(6, cs6, bv6) CT_STEP(7, cs7, bv7)
    #undef CT_STEP
    __syncthreads();
    float* red = (float*)Bs;
    #define REDUCE_CT(CT, CS) { \
        float v = (CS); \
        v += __shfl_xor(v, 16); v += __shfl_xor(v, 32); \
        if (l < 16) red[wv * 128 + (CT) * 16 + l] = v; }
    REDUCE_CT(0, cs0) REDUCE_CT(1, cs1) REDUCE_CT(2, cs2) REDUCE_CT(3, cs3)
    REDUCE_CT(4, cs4) REDUCE_CT(5, cs5) REDUCE_CT(6, cs6) REDUCE_CT(7, cs7)
    #undef REDUCE_CT
    __syncthreads();
    if (threadIdx.x < 128) {
        float s = red[threadIdx.x] + red[128 + threadIdx.x]
                + red[256 + threadIdx.x] + red[384 + threadIdx.x];
        atomicAdd(&kpp[threadIdx.x], s);
    }
}

// ---------------- semantic softmax (2 scores) ----------------
__global__ void score_attn(const float* __restrict__ kpart, const float* __restrict__ q,
                           float* __restrict__ attn) {
    __shared__ float r0[128], r1[128];
    int t = threadIdx.x;
    r0[t] = q[t] * kpart[t];
    r1[t] = q[t] * kpart[128 + t];
    __syncthreads();
    for (int s = 64; s > 0; s >>= 1) {
        if (t < s) { r0[t] += r0[t + s]; r1[t] += r1[t + s]; }
        __syncthreads();
    }
    if (t == 0) {
        float s0 = r0[0] / (float)NG, s1 = r1[0] / (float)NG;
        float mx = fmaxf(s0, s1);
        float e0 = expf(s0 - mx), e1 = expf(s1 - mx);
        attn[0] = e0 / (e0 + e1);
        attn[1] = e1 / (e0 + e1);
    }
}

// ---------------- fused combine + final linear (f16 inputs) ----------------
__launch_bounds__(256)
__global__ void final_lin(const unsigned short* __restrict__ gg,
                          const unsigned short* __restrict__ dgb,
                          const float* __restrict__ attn, const float* __restrict__ lin_w,
                          const float* __restrict__ lin_b, float* __restrict__ outp) {
    int wid = (blockIdx.x * 256 + threadIdx.x) >> 6;
    int l = threadIdx.x & 63;
    if (wid >= NG) return;
    float a0 = attn[0], a1 = attn[1];
    unsigned gu = *(const unsigned*)((const char*)gg + (size_t)wid * 256 + l * 4);
    unsigned du = *(const unsigned*)((const char*)dgb + (size_t)wid * 256 + l * 4);
    float2 gv = __half22float2(*(const __half2*)&gu);
    float2 dv = __half22float2(*(const __half2*)&du);
    float fx = a0 * fmaxf(gv.x, 0.f) + a1 * fmaxf(dv.x, 0.f);
    float fy = a0 * fmaxf(gv.y, 0.f) + a1 * fmaxf(dv.y, 0.f);
    float2 w0 = *(const float2*)&lin_w[l * 2];
    float2 w1 = *(const float2*)&lin_w[128 + l * 2];
    float p0 = fx * w0.x + fy * w0.y;
    float p1 = fx * w1.x + fy * w1.y;
    for (int off = 32; off > 0; off >>= 1) {
        p0 += __shfl_down(p0, off);
        p1 += __shfl_down(p1, off);
    }
    if (l == 0) {
        float2 o;
        o.x = p0 + lin_b[0];
        o.y = p1 + lin_b[1];
        *(float2*)&outp[wid * 2] = o;
    }
}

extern "C" void kernel_launch(void* const* d_in, const int* in_sizes, int n_in,
                              void* d_out, int out_size, void* d_ws, size_t ws_size,
                              hipStream_t stream) {
    const float* x_gene    = (const float*)d_in[0];
    const float* x_disease = (const float*)d_in[1];
    const int*   edge_gg   = (const int*)d_in[2];
    const int*   edge_dg   = (const int*)d_in[3];
    const float* pg_w      = (const float*)d_in[4];
    const float* pg_b      = (const float*)d_in[5];
    const float* pd_w      = (const float*)d_in[6];
    const float* pd_b      = (const float*)d_in[7];
    const float* att_src_gg= (const float*)d_in[8];
    const float* att_dst_gg= (const float*)d_in[9];
    const float* att_src_dg= (const float*)d_in[10];
    const float* att_dst_dg= (const float*)d_in[11];
    const float* k_lin_w   = (const float*)d_in[12];
    const float* k_lin_b   = (const float*)d_in[13];
    const float* q         = (const float*)d_in[14];
    const float* lin_w     = (const float*)d_in[15];
    const float* lin_b     = (const float*)d_in[16];
    float* out = (float*)d_out;
    float* ws  = (float*)d_ws;

    unsigned short* out_gg = (unsigned short*)(ws + OFF_OUT_GG);
    unsigned short* out_dg = (unsigned short*)(ws + OFF_OUT_DG);
    unsigned int* colPacked = (unsigned int*)(ws + OFF_OUT_GG);  // overlay (dead before gather)
    unsigned short* xg_h = (unsigned short*)(ws + OFF_XG);
    unsigned short* xd_h = (unsigned short*)(ws + OFF_XD);
    float* a_src_gg = ws + OFF_ASG;
    float* a_dst_gg = ws + OFF_ADG;
    float* a_dst_dg = ws + OFF_ADD;
    float* a_src_dg = ws + OFF_ASD;
    float* kpart  = ws + OFF_KPART;
    float* attn   = ws + OFF_ATTN;
    float* wtilG  = ws + OFF_WTIL;
    float* btilG  = ws + OFF_BTIL;
    float* wtilD  = ws + OFF_WTILD;
    float* btilD  = ws + OFF_BTILD;
    int* bcnt  = (int*)(ws + OFF_BCNT);
    int* rp    = (int*)(ws + OFF_RP);
    int* col   = (int*)(ws + OFF_COL);

    const int* gg_src = edge_gg;
    const int* gg_dst = edge_gg + EGG;
    const int* dg_src = edge_dg;
    const int* dg_dst = edge_dg + EDG;

    // 1. zero kpart + bucket counters; wtilde precompute (single launch)
    hipLaunchKernelGGL(init_zero_k, dim3(2), dim3(256), 0, stream, ws + ZERO_BASE, ZERO_CNT);
    hipLaunchKernelGGL(make_wtil_both, dim3(12), dim3(256), 0, stream,
                       pg_w, pg_b, att_src_gg, att_dst_gg, att_dst_dg,
                       pd_w, pd_b, att_src_dg, wtilG, btilG, wtilD, btilD);
    // 2. split-bf16 MFMA projections (f16 table + fused logits)
    hipLaunchKernelGGL((proj_mfma<3>), dim3((NG + 127) / 128), dim3(256), 0, stream,
                       x_gene, pg_w, pg_b, wtilG, btilG, xg_h,
                       a_src_gg, a_dst_gg, a_dst_dg, NG);
    hipLaunchKernelGGL((proj_mfma<1>), dim3((ND + 127) / 128), dim3(256), 0, stream,
                       x_disease, pd_w, pd_b, wtilD, btilD, xd_h,
                       a_src_dg, (float*)nullptr, (float*)nullptr, ND);
    // 3. CSR build: fused scatter (782 blocks) -> per-bucket build (196 blocks)
    hipLaunchKernelGGL(fused_scatter, dim3((EALL + S1_CH - 1) / S1_CH), dim3(256), 0, stream,
                       gg_src, gg_dst, dg_src, dg_dst, bcnt, colPacked);
    hipLaunchKernelGGL(bucket_build, dim3(NBUK), dim3(256), 0, stream,
                       colPacked, bcnt, rp, col);
    // 4. merged fused gather, single-pass (out_gg overwrites colPacked overlay — dead by now)
    hipLaunchKernelGGL(gat_gather_all, dim3((NALL + 3) / 4), dim3(256), 0, stream,
                       rp, col, a_src_gg, a_dst_gg, xg_h, a_src_dg, a_dst_dg, xd_h,
                       out_gg, out_dg);
    // 5. semantic attention (f16 MFMA kmean)
    hipLaunchKernelGGL(kmean_mfma, dim3(KM_HALF * 2), dim3(256), 0, stream,
                       out_gg, out_dg, k_lin_w, k_lin_b, kpart);
    hipLaunchKernelGGL(score_attn, dim3(1), dim3(128), 0, stream, kpart, q, attn);
    // 6. fused combine + final linear (f16 reads)
    hipLaunchKernelGGL(final_lin, dim3((NG + 3) / 4), dim3(256), 0, stream,
                       out_gg, out_dg, attn, lin_w, lin_b, out);
}

// Round 17
// 312.741 us; speedup vs baseline: 1.3415x; 1.0458x over previous
//
#include <hip/hip_runtime.h>
#include <hip/hip_fp16.h>
#include <math.h>

#define NG 100000
#define ND 50000
#define EGG 1600000
#define EDG 800000
#define EALL (EGG + EDG)
#define NALL (NG + NG)
#define HID 128
#define NH 8

// bucket sort params (validated R15)
#define SHIFT 10
#define BDSTS (1 << SHIFT)                    // 1024
#define NBUK  ((NALL + BDSTS - 1) / BDSTS)    // 196
#define BUKCAP 18432
#define S1_CH 3072
#define KM_HALF ((NG + 127) / 128)            // 782
#define GBLK ((NG + 127) / 128)               // 782 gene proj blocks
#define DBLK ((ND + 127) / 128)               // 391 disease proj blocks

// ---------------- workspace layout (4-byte element offsets) ----------------
#define OFF_OUT_GG 0UL          // f16 out_gg: 6,400,000 (colPacked overlay: 3,612,672 u32)
#define OFF_OUT_DG 6400000UL    // f16 out_dg: 6,400,000
#define OFF_XG     12800000UL   // f16 xg: 6,400,000
#define OFF_XD     19200000UL   // f16 xd: 3,200,000
#define OFF_ASG    22400000UL   //   800,000
#define OFF_ADG    23200000UL   //   800,000
#define OFF_ADD    24000000UL   //   800,000
#define OFF_ASD    24800000UL   //   400,000
#define OFF_KPART  25200000UL   //       256  (zero-init)
#define OFF_BCNT   25200256UL   //       256  (zero-init)
#define ZERO_BASE  OFF_KPART
#define ZERO_CNT   512
#define OFF_ATTN   25200768UL   //         2 (+pad)
#define OFF_RP     25200896UL   //   200,001 (+pad)
#define OFF_COL    25400960UL   // 2,400,000 -> ends 27,800,960
#define OFF_PGG    27801088UL   //   200,000  f32 [NG][2] partial final-lin (gg)
#define OFF_PDG    28001088UL   //   200,000  f32 [NG][2] partial final-lin (dg)
// end 28,201,088 floats = 112.8 MB

typedef float  f32x4  __attribute__((ext_vector_type(4)));
typedef short  bf16x8 __attribute__((ext_vector_type(8)));
typedef _Float16 f16x8 __attribute__((ext_vector_type(8)));
#define MFMA(a, b, c)  __builtin_amdgcn_mfma_f32_16x16x32_bf16(a, b, c, 0, 0, 0)
#define MFMAH(a, b, c) __builtin_amdgcn_mfma_f32_16x16x32_f16(a, b, c, 0, 0, 0)

#define FMAMIX_LO(ACC, SRC, AL) \
    asm("v_fma_mix_f32 %0, %1, %2, %0 op_sel:[0,0,0] op_sel_hi:[1,0,0]" \
        : "+v"(ACC) : "v"(SRC), "v"(AL))
#define FMAMIX_HI(ACC, SRC, AL) \
    asm("v_fma_mix_f32 %0, %1, %2, %0 op_sel:[1,0,0] op_sel_hi:[1,0,0]" \
        : "+v"(ACC) : "v"(SRC), "v"(AL))

__device__ __forceinline__ unsigned short bf16_rne(float f) {
    unsigned u = __float_as_uint(f);
    u += 0x7FFFu + ((u >> 16) & 1u);
    return (unsigned short)(u >> 16);
}
__device__ __forceinline__ float bf16f(unsigned short h) {
    return __uint_as_float(((unsigned)h) << 16);
}
__device__ __forceinline__ unsigned short f16_bits(float f) {
    __half h = __float2half(f);
    return *(unsigned short*)&h;
}
__device__ __forceinline__ float fast_tanh(float x) {
    x = fminf(fmaxf(x, -15.f), 15.f);
    float t = __expf(2.f * x);
    return (t - 1.f) / (t + 1.f);
}
__device__ __forceinline__ bf16x8 cvt_hi8(f32x4 v0, f32x4 v1) {
    bf16x8 f;
    f[0] = (short)bf16_rne(v0.x); f[1] = (short)bf16_rne(v0.y);
    f[2] = (short)bf16_rne(v0.z); f[3] = (short)bf16_rne(v0.w);
    f[4] = (short)bf16_rne(v1.x); f[5] = (short)bf16_rne(v1.y);
    f[6] = (short)bf16_rne(v1.z); f[7] = (short)bf16_rne(v1.w);
    return f;
}
__device__ __forceinline__ bf16x8 cvt_lo8(f32x4 v0, f32x4 v1, bf16x8 h) {
    bf16x8 f;
    f[0] = (short)bf16_rne(v0.x - bf16f((unsigned short)h[0]));
    f[1] = (short)bf16_rne(v0.y - bf16f((unsigned short)h[1]));
    f[2] = (short)bf16_rne(v0.z - bf16f((unsigned short)h[2]));
    f[3] = (short)bf16_rne(v0.w - bf16f((unsigned short)h[3]));
    f[4] = (short)bf16_rne(v1.x - bf16f((unsigned short)h[4]));
    f[5] = (short)bf16_rne(v1.y - bf16f((unsigned short)h[5]));
    f[6] = (short)bf16_rne(v1.z - bf16f((unsigned short)h[6]));
    f[7] = (short)bf16_rne(v1.w - bf16f((unsigned short)h[7]));
    return f;
}
__device__ __forceinline__ unsigned relu_pk(unsigned u) {
    return u & ~(((u & 0x80008000u) >> 15) * 0xFFFFu);
}
union U4F16 { uint4 u; f16x8 f; };

// ---------------- init ----------------
__global__ void init_zero_k(float* __restrict__ p, int n) {
    int i = blockIdx.x * 256 + threadIdx.x;
    if (i < n) p[i] = 0.f;
}

// ---------------- merged projection (gene blocks [0,GBLK), disease [GBLK,GBLK+DBLK)) ----------------
// split-bf16 MFMA; wtilde computed inline during staging; f16 table + fused logits
__launch_bounds__(256)
__global__ void proj_both(const float* __restrict__ xg, const float* __restrict__ Wg,
                          const float* __restrict__ bg,
                          const float* __restrict__ ag0, const float* __restrict__ ag1,
                          const float* __restrict__ ag2,
                          unsigned short* __restrict__ xgh,
                          float* __restrict__ og0, float* __restrict__ og1,
                          float* __restrict__ og2,
                          const float* __restrict__ xd, const float* __restrict__ Wd,
                          const float* __restrict__ bd, const float* __restrict__ ad0,
                          unsigned short* __restrict__ xdh, float* __restrict__ od0) {
    __shared__ bf16x8 Bhi[10 * 4 * 64];
    __shared__ bf16x8 Blo[8 * 4 * 64];
    __shared__ float btilS[32];
    int gene = blockIdx.x < GBLK;
    const float* x    = gene ? xg : xd;
    const float* W    = gene ? Wg : Wd;
    const float* bias = gene ? bg : bd;
    const float* a0v  = gene ? ag0 : ad0;
    const float* a1v  = gene ? ag1 : ad0;
    const float* a2v  = gene ? ag2 : ad0;
    unsigned short* xbf = gene ? xgh : xdh;
    float* o0 = gene ? og0 : od0;
    float* o1 = og1;   // only dereferenced when ccmax>8 (gene)
    float* o2 = og2;
    int ccmax = gene ? 24 : 8;
    int N = gene ? NG : ND;
    int bid = gene ? blockIdx.x : blockIdx.x - GBLK;

    // W staging (hi+lo)
    for (int idx = threadIdx.x; idx < 128 * 32; idx += 256) {
        int row = idx >> 5, kq = idx & 31;
        f32x4 v = *(const f32x4*)&W[row * 128 + kq * 4];
        int ct = row >> 4, c = row & 15;
        int k0 = kq * 4;
        int kc = k0 >> 5, q16 = (k0 & 31) >> 3, j2 = (k0 & 7) >> 1;
        int slot = (ct * 4 + kc) * 64 + q16 * 16 + c;
        unsigned short hx = bf16_rne(v.x), hy = bf16_rne(v.y);
        unsigned short hz = bf16_rne(v.z), hw = bf16_rne(v.w);
        unsigned* dh = (unsigned*)&Bhi[slot];
        dh[j2]     = ((unsigned)hy << 16) | hx;
        dh[j2 + 1] = ((unsigned)hw << 16) | hz;
        unsigned* dl = (unsigned*)&Blo[slot];
        dl[j2]     = ((unsigned)bf16_rne(v.y - bf16f(hy)) << 16) | bf16_rne(v.x - bf16f(hx));
        dl[j2 + 1] = ((unsigned)bf16_rne(v.w - bf16f(hw)) << 16) | bf16_rne(v.z - bf16f(hz));
    }
    // att tile staging: wtilde computed inline (w~[cc][k] = sum_c av[h*16+c]*W[(h*16+c)*128+k])
    for (int idx = threadIdx.x; idx < 2 * 16 * 32; idx += 256) {
        int cc = idx >> 5, kq = idx & 31;
        f32x4 v = {0.f, 0.f, 0.f, 0.f};
        if (cc < ccmax) {
            int vv = cc >> 3, h = cc & 7;
            const float* av = (vv == 0) ? a0v : (vv == 1) ? a1v : a2v;
            #pragma unroll
            for (int c = 0; c < 16; c++) {
                float a = av[h * 16 + c];
                f32x4 w = *(const f32x4*)&W[(h * 16 + c) * 128 + kq * 4];
                v.x += a * w.x; v.y += a * w.y; v.z += a * w.z; v.w += a * w.w;
            }
        }
        int ct = 8 + (cc >> 4), c = cc & 15;
        int k0 = kq * 4;
        int kc = k0 >> 5, q16 = (k0 & 31) >> 3, j2 = (k0 & 7) >> 1;
        unsigned* dh = (unsigned*)&Bhi[(ct * 4 + kc) * 64 + q16 * 16 + c];
        dh[j2]     = ((unsigned)bf16_rne(v.y) << 16) | bf16_rne(v.x);
        dh[j2 + 1] = ((unsigned)bf16_rne(v.w) << 16) | bf16_rne(v.z);
    }
    if (threadIdx.x < 32) {
        float s = 0.f;
        if (threadIdx.x < ccmax) {
            int vv = threadIdx.x >> 3, h = threadIdx.x & 7;
            const float* av = (vv == 0) ? a0v : (vv == 1) ? a1v : a2v;
            #pragma unroll
            for (int c = 0; c < 16; c++) s += av[h * 16 + c] * bias[h * 16 + c];
        }
        btilS[threadIdx.x] = s;
    }
    __syncthreads();
    int wv = threadIdx.x >> 6, l = threadIdx.x & 63;
    int q = l >> 4, c16 = l & 15;
    int rw = bid * 128 + wv * 32;
    int n0 = min(rw + c16, N - 1);
    int n1 = min(rw + 16 + c16, N - 1);
    const float* xr0 = &x[(size_t)n0 * 128 + q * 8];
    const float* xr1 = &x[(size_t)n1 * 128 + q * 8];
    #define LOADX(FH, FL, PTR, OFF) \
        bf16x8 FH, FL; \
        { f32x4 v0_ = *(const f32x4*)((PTR) + (OFF)); \
          f32x4 v1_ = *(const f32x4*)((PTR) + (OFF) + 4); \
          FH = cvt_hi8(v0_, v1_); FL = cvt_lo8(v0_, v1_, FH); }
    LOADX(xh00, xl00, xr0, 0)  LOADX(xh01, xl01, xr0, 32)
    LOADX(xh02, xl02, xr0, 64) LOADX(xh03, xl03, xr0, 96)
    LOADX(xh10, xl10, xr1, 0)  LOADX(xh11, xl11, xr1, 32)
    LOADX(xh12, xl12, xr1, 64) LOADX(xh13, xl13, xr1, 96)
    #undef LOADX
    int r0 = rw + q * 4;
    int r1 = r0 + 16;
    #define CT_MAIN(CT) { \
        bf16x8 bh0 = Bhi[((CT) * 4 + 0) * 64 + l]; \
        bf16x8 bh1 = Bhi[((CT) * 4 + 1) * 64 + l]; \
        bf16x8 bh2 = Bhi[((CT) * 4 + 2) * 64 + l]; \
        bf16x8 bh3 = Bhi[((CT) * 4 + 3) * 64 + l]; \
        bf16x8 bl0 = Blo[((CT) * 4 + 0) * 64 + l]; \
        bf16x8 bl1 = Blo[((CT) * 4 + 1) * 64 + l]; \
        bf16x8 bl2 = Blo[((CT) * 4 + 2) * 64 + l]; \
        bf16x8 bl3 = Blo[((CT) * 4 + 3) * 64 + l]; \
        f32x4 aA = {0,0,0,0}, aB = {0,0,0,0}, aC = {0,0,0,0}, aD = {0,0,0,0}; \
        aA = MFMA(xh00, bh0, aA); aB = MFMA(xh01, bh1, aB); \
        aC = MFMA(xh10, bh0, aC); aD = MFMA(xh11, bh1, aD); \
        aA = MFMA(xl00, bh0, aA); aB = MFMA(xl01, bh1, aB); \
        aC = MFMA(xl10, bh0, aC); aD = MFMA(xl11, bh1, aD); \
        aA = MFMA(xh00, bl0, aA); aB = MFMA(xh01, bl1, aB); \
        aC = MFMA(xh10, bl0, aC); aD = MFMA(xh11, bl1, aD); \
        aA = MFMA(xh02, bh2, aA); aB = MFMA(xh03, bh3, aB); \
        aC = MFMA(xh12, bh2, aC); aD = MFMA(xh13, bh3, aD); \
        aA = MFMA(xl02, bh2, aA); aB = MFMA(xl03, bh3, aB); \
        aC = MFMA(xl12, bh2, aC); aD = MFMA(xl13, bh3, aD); \
        aA = MFMA(xh02, bl2, aA); aB = MFMA(xh03, bl3, aB); \
        aC = MFMA(xh12, bl2, aC); aD = MFMA(xh13, bl3, aD); \
        f32x4 d0 = aA + aB, d1 = aC + aD; \
        float bv = bias[(CT) * 16 + c16]; \
        int col = (CT) * 16 + c16; \
        if (r0 + 0 < N) xbf[(size_t)(r0 + 0) * 128 + col] = f16_bits(d0[0] + bv); \
        if (r0 + 1 < N) xbf[(size_t)(r0 + 1) * 128 + col] = f16_bits(d0[1] + bv); \
        if (r0 + 2 < N) xbf[(size_t)(r0 + 2) * 128 + col] = f16_bits(d0[2] + bv); \
        if (r0 + 3 < N) xbf[(size_t)(r0 + 3) * 128 + col] = f16_bits(d0[3] + bv); \
        if (r1 + 0 < N) xbf[(size_t)(r1 + 0) * 128 + col] = f16_bits(d1[0] + bv); \
        if (r1 + 1 < N) xbf[(size_t)(r1 + 1) * 128 + col] = f16_bits(d1[1] + bv); \
        if (r1 + 2 < N) xbf[(size_t)(r1 + 2) * 128 + col] = f16_bits(d1[2] + bv); \
        if (r1 + 3 < N) xbf[(size_t)(r1 + 3) * 128 + col] = f16_bits(d1[3] + bv); }
    CT_MAIN(0) CT_MAIN(1) CT_MAIN(2) CT_MAIN(3)
    CT_MAIN(4) CT_MAIN(5) CT_MAIN(6) CT_MAIN(7)
    #undef CT_MAIN
    #define CT_ATT(TE) { \
        bf16x8 bh0 = Bhi[((8 + (TE)) * 4 + 0) * 64 + l]; \
        bf16x8 bh1 = Bhi[((8 + (TE)) * 4 + 1) * 64 + l]; \
        bf16x8 bh2 = Bhi[((8 + (TE)) * 4 + 2) * 64 + l]; \
        bf16x8 bh3 = Bhi[((8 + (TE)) * 4 + 3) * 64 + l]; \
        f32x4 aA = {0,0,0,0}, aB = {0,0,0,0}, aC = {0,0,0,0}, aD = {0,0,0,0}; \
        aA = MFMA(xh00, bh0, aA); aB = MFMA(xh01, bh1, aB); \
        aC = MFMA(xh10, bh0, aC); aD = MFMA(xh11, bh1, aD); \
        aA = MFMA(xh02, bh2, aA); aB = MFMA(xh03, bh3, aB); \
        aC = MFMA(xh12, bh2, aC); aD = MFMA(xh13, bh3, aD); \
        f32x4 d0 = aA + aB, d1 = aC + aD; \
        int cc = (TE) * 16 + c16; \
        if (cc < ccmax) { \
            float bt = btilS[cc]; \
            int vv = cc >> 3, h = cc & 7; \
            float* op = (vv == 0) ? o0 : ((vv == 1) ? o1 : o2); \
            if (r0 + 0 < N) op[(r0 + 0) * 8 + h] = d0[0] + bt; \
            if (r0 + 1 < N) op[(r0 + 1) * 8 + h] = d0[1] + bt; \
            if (r0 + 2 < N) op[(r0 + 2) * 8 + h] = d0[2] + bt; \
            if (r0 + 3 < N) op[(r0 + 3) * 8 + h] = d0[3] + bt; \
            if (r1 + 0 < N) op[(r1 + 0) * 8 + h] = d1[0] + bt; \
            if (r1 + 1 < N) op[(r1 + 1) * 8 + h] = d1[1] + bt; \
            if (r1 + 2 < N) op[(r1 + 2) * 8 + h] = d1[2] + bt; \
            if (r1 + 3 < N) op[(r1 + 3) * 8 + h] = d1[3] + bt; } }
    CT_ATT(0)
    if (ccmax > 16) { CT_ATT(1) }
    #undef CT_ATT
}

// ---------------- K1: fused bucket scatter (782 blocks, 18KB LDS) ----------------
__launch_bounds__(256)
__global__ void fused_scatter(const int* __restrict__ gg_src, const int* __restrict__ gg_dst,
                              const int* __restrict__ dg_src, const int* __restrict__ dg_dst,
                              int* __restrict__ bcnt, unsigned int* __restrict__ colPacked) {
    __shared__ int cnt[256], scanE[256], gbase[256], cursor[256];
    __shared__ int ss[256];
    __shared__ unsigned int sorted[S1_CH];
    __shared__ unsigned char bof[S1_CH];
    int t = threadIdx.x;
    cnt[t] = 0;
    __syncthreads();
    int base = blockIdx.x * S1_CH;
    for (int k = 0; k < S1_CH; k += 256) {
        int e = base + k + t;
        if (e < EALL) {
            int dn = (e < EGG) ? gg_dst[e] : (NG + dg_dst[e - EGG]);
            atomicAdd(&cnt[dn >> SHIFT], 1);
        }
    }
    __syncthreads();
    int v = cnt[t];
    ss[t] = v;
    __syncthreads();
    for (int off = 1; off < 256; off <<= 1) {
        int y = (t >= off) ? ss[t - off] : 0;
        __syncthreads();
        ss[t] += y;
        __syncthreads();
    }
    scanE[t] = ss[t] - v;
    cursor[t] = ss[t] - v;
    if (t < NBUK && v > 0) gbase[t] = atomicAdd(&bcnt[t], v);
    __syncthreads();
    for (int k = 0; k < S1_CH; k += 256) {
        int e = base + k + t;
        if (e < EALL) {
            int s, dn;
            if (e < EGG) { s = gg_src[e]; dn = gg_dst[e]; }
            else         { s = dg_src[e - EGG]; dn = NG + dg_dst[e - EGG]; }
            int b = dn >> SHIFT;
            int slot = atomicAdd(&cursor[b], 1);
            sorted[slot] = ((unsigned int)s << SHIFT) | (unsigned int)(dn & (BDSTS - 1));
            bof[slot] = (unsigned char)b;
        }
    }
    __syncthreads();
    int total = ss[255];
    for (int f = t; f < total; f += 256) {
        int b = bof[f];
        colPacked[(size_t)b * BUKCAP + gbase[b] + (f - scanE[b])] = sorted[f];
    }
}

// ---------------- K2: per-bucket build (196 blocks; bucket scan folded in) ----------------
__launch_bounds__(256)
__global__ void bucket_build(const unsigned int* __restrict__ colPacked,
                             const int* __restrict__ bcnt,
                             int* __restrict__ rp, int* __restrict__ col) {
    __shared__ int lcur[BDSTS];
    __shared__ int tsum[256];
    __shared__ int bscan[256];
    int b = blockIdx.x;
    int t = threadIdx.x;
    bscan[t] = (t < NBUK) ? bcnt[t] : 0;
    __syncthreads();
    for (int off = 1; off < 256; off <<= 1) {
        int y = (t >= off) ? bscan[t - off] : 0;
        __syncthreads();
        bscan[t] += y;
        __syncthreads();
    }
    int gb = (b > 0) ? bscan[b - 1] : 0;
    int d0 = b << SHIFT;
    int nd = min(BDSTS, NALL - d0);
    int cnt = bcnt[b];
    const unsigned int* pk = colPacked + (size_t)b * BUKCAP;
    for (int i = t; i < BDSTS; i += 256) lcur[i] = 0;
    __syncthreads();
    for (int i = t; i < cnt; i += 256)
        atomicAdd(&lcur[pk[i] & (BDSTS - 1)], 1);
    __syncthreads();
    int h0 = lcur[t * 4 + 0], h1 = lcur[t * 4 + 1], h2 = lcur[t * 4 + 2], h3 = lcur[t * 4 + 3];
    int tot = h0 + h1 + h2 + h3;
    tsum[t] = tot;
    __syncthreads();
    for (int off = 1; off < 256; off <<= 1) {
        int y = (t >= off) ? tsum[t - off] : 0;
        __syncthreads();
        tsum[t] += y;
        __syncthreads();
    }
    int pp = tsum[t] - tot + gb;
    __syncthreads();
    #define EMIT(J, HJ) { int idx = t * 4 + (J); \
        if (idx < nd) rp[d0 + idx] = pp; \
        lcur[idx] = pp; pp += (HJ); }
    EMIT(0, h0) EMIT(1, h1) EMIT(2, h2) EMIT(3, h3)
    #undef EMIT
    if (b == NBUK - 1 && t == 0) rp[NALL] = EALL;
    __syncthreads();
    for (int i = t; i < cnt; i += 256) {
        unsigned int p = pk[i];
        int pos = atomicAdd(&lcur[p & (BDSTS - 1)], 1);
        col[pos] = (int)(p >> SHIFT);
    }
}

// ---------------- gather v9: single-pass + fused final-linear partials ----------------
__launch_bounds__(256)
__global__ void gat_gather_all(const int* __restrict__ rp, const int* __restrict__ col,
                               const float* __restrict__ as_gg, const float* __restrict__ ad_gg,
                               const unsigned short* __restrict__ xg_h,
                               const float* __restrict__ as_dg, const float* __restrict__ ad_dg,
                               const unsigned short* __restrict__ xd_h,
                               unsigned short* __restrict__ out_gg,
                               unsigned short* __restrict__ out_dg,
                               const float* __restrict__ lin_w,
                               float* __restrict__ pgg, float* __restrict__ pdg) {
    int wid = (blockIdx.x * 256 + threadIdx.x) >> 6;
    int l = threadIdx.x & 63;
    if (wid >= NALL) return;
    int isdg = wid >= NG;
    int d = isdg ? wid - NG : wid;
    const float* a_s = isdg ? as_dg : as_gg;
    const float* a_d = isdg ? ad_dg : ad_gg;
    const unsigned short* xbf = isdg ? xd_h : xg_h;
    unsigned short* outh = (isdg ? out_dg : out_gg);

    int base = rp[wid];
    int deg = rp[wid + 1] - base;

    int hl = l & 7;
    int g  = l >> 3;
    float adl = a_d[d * 8 + hl];
    int q = l >> 4;
    int cq = l & 15;
    int hq = cq >> 1;
    uint32_t colbyte = (uint32_t)cq << 4;
    float a0 = 0.f, a1 = 0.f, a2 = 0.f, a3 = 0.f, a4 = 0.f, a5 = 0.f, a6 = 0.f, a7 = 0.f;
    float sacc = 0.f;
    for (int c0 = 0; c0 < deg; c0 += 64) {
        int myi = c0 + l;
        int colreg = (myi < deg) ? col[base + myi] : 0;
        int lim = min(deg - c0, 64);
        for (int j8 = 0; j8 < lim; j8 += 8) {
            float ex;
            {
                int s = __shfl(colreg, j8 + g);
                float a = a_s[s * 8 + hl] + adl;
                a = a > 0.f ? a : 0.2f * a;
                ex = __expf(a);
            }
            int jlim = min(lim - j8, 8);
            #pragma unroll
            for (int sub = 0; sub < 8; sub += 4) {
                int jrel = sub + q;
                int s = __shfl(colreg, j8 + jrel);
                float al = __shfl(ex, (jrel << 3) + hq);
                al = (jrel < jlim) ? al : 0.f;
                sacc += al;
                const uint4 rv = *(const uint4*)((const char*)xbf +
                                    (((size_t)(uint32_t)s << 8) + colbyte));
                FMAMIX_LO(a0, rv.x, al); FMAMIX_HI(a1, rv.x, al);
                FMAMIX_LO(a2, rv.y, al); FMAMIX_HI(a3, rv.y, al);
                FMAMIX_LO(a4, rv.z, al); FMAMIX_HI(a5, rv.z, al);
                FMAMIX_LO(a6, rv.w, al); FMAMIX_HI(a7, rv.w, al);
            }
        }
    }
    sacc += __shfl_xor(sacc, 16); sacc += __shfl_xor(sacc, 32);
    a0 += __shfl_xor(a0, 16); a0 += __shfl_xor(a0, 32);
    a1 += __shfl_xor(a1, 16); a1 += __shfl_xor(a1, 32);
    a2 += __shfl_xor(a2, 16); a2 += __shfl_xor(a2, 32);
    a3 += __shfl_xor(a3, 16); a3 += __shfl_xor(a3, 32);
    a4 += __shfl_xor(a4, 16); a4 += __shfl_xor(a4, 32);
    a5 += __shfl_xor(a5, 16); a5 += __shfl_xor(a5, 32);
    a6 += __shfl_xor(a6, 16); a6 += __shfl_xor(a6, 32);
    a7 += __shfl_xor(a7, 16); a7 += __shfl_xor(a7, 32);
    if (q == 0) {
        float rsc = 1.f / (sacc + 1e-16f);
        a0 *= rsc; a1 *= rsc; a2 *= rsc; a3 *= rsc;
        a4 *= rsc; a5 *= rsc; a6 *= rsc; a7 *= rsc;
        __half2 h01 = __floats2half2_rn(a0, a1);
        __half2 h23 = __floats2half2_rn(a2, a3);
        __half2 h45 = __floats2half2_rn(a4, a5);
        __half2 h67 = __floats2half2_rn(a6, a7);
        uint4 o;
        o.x = *(unsigned*)&h01; o.y = *(unsigned*)&h23;
        o.z = *(unsigned*)&h45; o.w = *(unsigned*)&h67;
        *(uint4*)((char*)outh + (size_t)d * 256 + cq * 16) = o;
        // fused final-linear partials: p = relu(row) . lin_w[0/1]  (f32 precision)
        float r0 = fmaxf(a0, 0.f), r1 = fmaxf(a1, 0.f), r2 = fmaxf(a2, 0.f), r3 = fmaxf(a3, 0.f);
        float r4 = fmaxf(a4, 0.f), r5 = fmaxf(a5, 0.f), r6 = fmaxf(a6, 0.f), r7 = fmaxf(a7, 0.f);
        f32x4 w0a = *(const f32x4*)&lin_w[cq * 8];
        f32x4 w0b = *(const f32x4*)&lin_w[cq * 8 + 4];
        f32x4 w1a = *(const f32x4*)&lin_w[128 + cq * 8];
        f32x4 w1b = *(const f32x4*)&lin_w[128 + cq * 8 + 4];
        float p0 = r0 * w0a.x + r1 * w0a.y + r2 * w0a.z + r3 * w0a.w
                 + r4 * w0b.x + r5 * w0b.y + r6 * w0b.z + r7 * w0b.w;
        float p1 = r0 * w1a.x + r1 * w1a.y + r2 * w1a.z + r3 * w1a.w
                 + r4 * w1b.x + r5 * w1b.y + r6 * w1b.z + r7 * w1b.w;
        // reduce over the 16 active lanes (l = 0..15)
        p0 += __shfl_xor(p0, 1); p1 += __shfl_xor(p1, 1);
        p0 += __shfl_xor(p0, 2); p1 += __shfl_xor(p1, 2);
        p0 += __shfl_xor(p0, 4); p1 += __shfl_xor(p1, 4);
        p0 += __shfl_xor(p0, 8); p1 += __shfl_xor(p1, 8);
        if (l == 0) {
            float* pp = isdg ? pdg : pgg;
            float2 pv; pv.x = p0; pv.y = p1;
            *(float2*)&pp[d * 2] = pv;
        }
    }
}

// ---------------- kmean via f16 MFMA (raw f16 rows, packed relu) ----------------
__launch_bounds__(256)
__global__ void kmean_mfma(const unsigned short* __restrict__ srcA,
                           const unsigned short* __restrict__ srcB,
                           const float* __restrict__ W, const float* __restrict__ bias,
                           float* __restrict__ kp) {
    __shared__ f16x8 Bs[8 * 4 * 64];
    for (int idx = threadIdx.x; idx < 128 * 32; idx += 256) {
        int row = idx >> 5, kq = idx & 31;
        f32x4 v = *(const f32x4*)&W[row * 128 + kq * 4];
        int ct = row >> 4, c = row & 15;
        int k0 = kq * 4;
        int kc = k0 >> 5, q16 = (k0 & 31) >> 3, j2 = (k0 & 7) >> 1;
        unsigned* dst = (unsigned*)&Bs[(ct * 4 + kc) * 64 + q16 * 16 + c];
        dst[j2]     = ((unsigned)f16_bits(v.y) << 16) | f16_bits(v.x);
        dst[j2 + 1] = ((unsigned)f16_bits(v.w) << 16) | f16_bits(v.z);
    }
    __syncthreads();
    int half = blockIdx.x >= KM_HALF;
    const unsigned short* src = half ? srcB : srcA;
    float* kpp = half ? (kp + 128) : kp;
    int rb = (half ? blockIdx.x - KM_HALF : blockIdx.x) * 128;
    int wv = threadIdx.x >> 6, l = threadIdx.x & 63;
    int q = l >> 4, c16 = l & 15;
    int rw = rb + wv * 32;
    const char* xr0 = (const char*)src + (size_t)(rw + c16) * 256 + q * 16;
    const char* xr1 = xr0 + 16 * 256;
    #define LOADA(F, PTR, OFF) f16x8 F; { \
        U4F16 u_; u_.u = *(const uint4*)((PTR) + (OFF)); \
        u_.u.x = relu_pk(u_.u.x); u_.u.y = relu_pk(u_.u.y); \
        u_.u.z = relu_pk(u_.u.z); u_.u.w = relu_pk(u_.u.w); \
        F = u_.f; }
    LOADA(f00, xr0, 0) LOADA(f01, xr0, 64) LOADA(f02, xr0, 128) LOADA(f03, xr0, 192)
    LOADA(f10, xr1, 0) LOADA(f11, xr1, 64) LOADA(f12, xr1, 128) LOADA(f13, xr1, 192)
    #undef LOADA
    float bv0 = bias[c16],      bv1 = bias[16 + c16], bv2 = bias[32 + c16], bv3 = bias[48 + c16];
    float bv4 = bias[64 + c16], bv5 = bias[80 + c16], bv6 = bias[96 + c16], bv7 = bias[112 + c16];
    int row0 = rw + q * 4;
    int row1 = row0 + 16;
    float cs0 = 0.f, cs1 = 0.f, cs2 = 0.f, cs3 = 0.f, cs4 = 0.f, cs5 = 0.f, cs6 = 0.f, cs7 = 0.f;
    #define CT_STEP(CT, CS, BV) { \
        f16x8 b0 = Bs[((CT) * 4 + 0) * 64 + l]; \
        f16x8 b1 = Bs[((CT) * 4 + 1) * 64 + l]; \
        f16x8 b2 = Bs[((CT) * 4 + 2) * 64 + l]; \
        f16x8 b3 = Bs[((CT) * 4 + 3) * 64 + l]; \
        f32x4 aA = {0,0,0,0}, aB = {0,0,0,0}, aC = {0,0,0,0}, aD = {0,0,0,0}; \
        aA = MFMAH(f00, b0, aA); aB = MFMAH(f01, b1, aB); \
        aA = MFMAH(f02, b2, aA); aB = MFMAH(f03, b3, aB); \
        aC = MFMAH(f10, b0, aC); aD = MFMAH(f11, b1, aD); \
        aC = MFMAH(f12, b2, aC); aD = MFMAH(f13, b3, aD); \
        f32x4 d0 = aA + aB, d1 = aC + aD; \
        float s = 0.f; \
        if (row0 + 0 < NG) s += fast_tanh(d0[0] + (BV)); \
        if (row0 + 1 < NG) s += fast_tanh(d0[1] + (BV)); \
        if (row0 + 2 < NG) s += fast_tanh(d0[2] + (BV)); \
        if (row0 + 3 < NG) s += fast_tanh(d0[3] + (BV)); \
        if (row1 + 0 < NG) s += fast_tanh(d1[0] + (BV)); \
        if (row1 + 1 < NG) s += fast_tanh(d1[1] + (BV)); \
        if (row1 + 2 < NG) s += fast_tanh(d1[2] + (BV)); \
        if (row1 + 3 < NG) s += fast_tanh(d1[3] + (BV)); \
        CS += s; }
    CT_STEP(0, cs0, bv0) CT_STEP(1, cs1, bv1) CT_STEP(2, cs2, bv2) CT_STEP(3, cs3, bv3)
    CT_STEP(4, cs4, bv4) CT_STEP(5, cs5, bv5) CT_STEP(6, cs6, bv6) CT_STEP(7, cs7, bv7)
    #undef CT_STEP
    __syncthreads();
    float* red = (float*)Bs;
    #define REDUCE_CT(CT, CS) { \
        float v = (CS); \
        v += __shfl_xor(v, 16); v += __shfl_xor(v, 32); \
        if (l < 16) red[wv * 128 + (CT) * 16 + l] = v; }
    REDUCE_CT(0, cs0) REDUCE_CT(1, cs1) REDUCE_CT(2, cs2) REDUCE_CT(3, cs3)
    REDUCE_CT(4, cs4) REDUCE_CT(5, cs5) REDUCE_CT(6, cs6) REDUCE_CT(7, cs7)
    #undef REDUCE_CT
    __syncthreads();
    if (threadIdx.x < 128) {
        float s = red[threadIdx.x] + red[128 + threadIdx.x]
                + red[256 + threadIdx.x] + red[384 + threadIdx.x];
        atomicAdd(&kpp[threadIdx.x], s);
    }
}

// ---------------- semantic softmax (2 scores) ----------------
__global__ void score_attn(const float* __restrict__ kpart, const float* __restrict__ q,
                           float* __restrict__ attn) {
    __shared__ float r0[128], r1[128];
    int t = threadIdx.x;
    r0[t] = q[t] * kpart[t];
    r1[t] = q[t] * kpart[128 + t];
    __syncthreads();
    for (int s = 64; s > 0; s >>= 1) {
        if (t < s) { r0[t] += r0[t + s]; r1[t] += r1[t + s]; }
        __syncthreads();
    }
    if (t == 0) {
        float s0 = r0[0] / (float)NG, s1 = r1[0] / (float)NG;
        float mx = fmaxf(s0, s1);
        float e0 = expf(s0 - mx), e1 = expf(s1 - mx);
        attn[0] = e0 / (e0 + e1);
        attn[1] = e1 / (e0 + e1);
    }
}

// ---------------- final combine: out = attn0*pgg + attn1*pdg + lin_b ----------------
__global__ void final_combine(const float* __restrict__ pgg, const float* __restrict__ pdg,
                              const float* __restrict__ attn, const float* __restrict__ lin_b,
                              float* __restrict__ outp) {
    int n = blockIdx.x * 256 + threadIdx.x;
    if (n >= NG) return;
    float a0 = attn[0], a1 = attn[1];
    float2 g = *(const float2*)&pgg[n * 2];
    float2 dd = *(const float2*)&pdg[n * 2];
    float2 o;
    o.x = a0 * g.x + a1 * dd.x + lin_b[0];
    o.y = a0 * g.y + a1 * dd.y + lin_b[1];
    *(float2*)&outp[n * 2] = o;
}

extern "C" void kernel_launch(void* const* d_in, const int* in_sizes, int n_in,
                              void* d_out, int out_size, void* d_ws, size_t ws_size,
                              hipStream_t stream) {
    const float* x_gene    = (const float*)d_in[0];
    const float* x_disease = (const float*)d_in[1];
    const int*   edge_gg   = (const int*)d_in[2];
    const int*   edge_dg   = (const int*)d_in[3];
    const float* pg_w      = (const float*)d_in[4];
    const float* pg_b      = (const float*)d_in[5];
    const float* pd_w      = (const float*)d_in[6];
    const float* pd_b      = (const float*)d_in[7];
    const float* att_src_gg= (const float*)d_in[8];
    const float* att_dst_gg= (const float*)d_in[9];
    const float* att_src_dg= (const float*)d_in[10];
    const float* att_dst_dg= (const float*)d_in[11];
    const float* k_lin_w   = (const float*)d_in[12];
    const float* k_lin_b   = (const float*)d_in[13];
    const float* q         = (const float*)d_in[14];
    const float* lin_w     = (const float*)d_in[15];
    const float* lin_b     = (const float*)d_in[16];
    float* out = (float*)d_out;
    float* ws  = (float*)d_ws;

    unsigned short* out_gg = (unsigned short*)(ws + OFF_OUT_GG);
    unsigned short* out_dg = (unsigned short*)(ws + OFF_OUT_DG);
    unsigned int* colPacked = (unsigned int*)(ws + OFF_OUT_GG);  // overlay (dead before gather)
    unsigned short* xg_h = (unsigned short*)(ws + OFF_XG);
    unsigned short* xd_h = (unsigned short*)(ws + OFF_XD);
    float* a_src_gg = ws + OFF_ASG;
    float* a_dst_gg = ws + OFF_ADG;
    float* a_dst_dg = ws + OFF_ADD;
    float* a_src_dg = ws + OFF_ASD;
    float* kpart  = ws + OFF_KPART;
    float* attn   = ws + OFF_ATTN;
    float* pgg    = ws + OFF_PGG;
    float* pdg    = ws + OFF_PDG;
    int* bcnt  = (int*)(ws + OFF_BCNT);
    int* rp    = (int*)(ws + OFF_RP);
    int* col   = (int*)(ws + OFF_COL);

    const int* gg_src = edge_gg;
    const int* gg_dst = edge_gg + EGG;
    const int* dg_src = edge_dg;
    const int* dg_dst = edge_dg + EDG;

    // 1. zero kpart + bucket counters
    hipLaunchKernelGGL(init_zero_k, dim3(2), dim3(256), 0, stream, ws + ZERO_BASE, ZERO_CNT);
    // 2. merged projection (wtilde inlined; f16 tables + fused logits)
    hipLaunchKernelGGL(proj_both, dim3(GBLK + DBLK), dim3(256), 0, stream,
                       x_gene, pg_w, pg_b, att_src_gg, att_dst_gg, att_dst_dg,
                       xg_h, a_src_gg, a_dst_gg, a_dst_dg,
                       x_disease, pd_w, pd_b, att_src_dg, xd_h, a_src_dg);
    // 3. CSR build
    hipLaunchKernelGGL(fused_scatter, dim3((EALL + S1_CH - 1) / S1_CH), dim3(256), 0, stream,
                       gg_src, gg_dst, dg_src, dg_dst, bcnt, colPacked);
    hipLaunchKernelGGL(bucket_build, dim3(NBUK), dim3(256), 0, stream,
                       colPacked, bcnt, rp, col);
    // 4. merged single-pass gather + fused final-linear partials
    hipLaunchKernelGGL(gat_gather_all, dim3((NALL + 3) / 4), dim3(256), 0, stream,
                       rp, col, a_src_gg, a_dst_gg, xg_h, a_src_dg, a_dst_dg, xd_h,
                       out_gg, out_dg, lin_w, pgg, pdg);
    // 5. semantic attention
    hipLaunchKernelGGL(kmean_mfma, dim3(KM_HALF * 2), dim3(256), 0, stream,
                       out_gg, out_dg, k_lin_w, k_lin_b, kpart);
    hipLaunchKernelGGL(score_attn, dim3(1), dim3(128), 0, stream, kpart, q, attn);
    // 6. trivial final combine (reads 2 floats/metapath/node instead of 512B)
    hipLaunchKernelGGL(final_combine, dim3((NG + 255) / 256), dim3(256), 0, stream,
                       pgg, pdg, attn, lin_b, out);
}

// Round 18
// 309.674 us; speedup vs baseline: 1.3548x; 1.0099x over previous
//
#include <hip/hip_runtime.h>
#include <hip/hip_fp16.h>
#include <math.h>

#define NG 100000
#define ND 50000
#define EGG 1600000
#define EDG 800000
#define EALL (EGG + EDG)
#define NALL (NG + NG)
#define HID 128
#define NH 8

// bucket sort params (validated R15)
#define SHIFT 10
#define BDSTS (1 << SHIFT)                    // 1024
#define NBUK  ((NALL + BDSTS - 1) / BDSTS)    // 196
#define BUKCAP 18432
#define S1_CH 3072
#define KM_HALF ((NG + 127) / 128)            // 782
#define GBLK ((NG + 127) / 128)               // 782 gene proj blocks
#define DBLK ((ND + 127) / 128)               // 391 disease proj blocks

// ---------------- workspace layout (4-byte element offsets) ----------------
#define OFF_OUT_GG 0UL          // f16 out_gg: 6,400,000 (colPacked overlay: 3,612,672 u32)
#define OFF_OUT_DG 6400000UL    // f16 out_dg: 6,400,000
#define OFF_XG     12800000UL   // f16 xg: 6,400,000
#define OFF_XD     19200000UL   // f16 xd: 3,200,000
#define OFF_ASG    22400000UL   //   800,000
#define OFF_ADG    23200000UL   //   800,000
#define OFF_ADD    24000000UL   //   800,000
#define OFF_ASD    24800000UL   //   400,000
#define OFF_KPART  25200000UL   //       256  (zero-init)
#define OFF_BCNT   25200256UL   //       256  (zero-init)
#define ZERO_BASE  OFF_KPART
#define ZERO_CNT   512
#define OFF_ATTN   25200768UL   //         2 (+pad)
#define OFF_RP     25200896UL   //   200,001 (+pad)
#define OFF_COL    25400960UL   // 2,400,000 -> ends 27,800,960
#define OFF_PGG    27801088UL   //   200,000  f32 [NG][2] partial final-lin (gg)
#define OFF_PDG    28001088UL   //   200,000  f32 [NG][2] partial final-lin (dg)
// end 28,201,088 floats = 112.8 MB

typedef float  f32x4  __attribute__((ext_vector_type(4)));
typedef short  bf16x8 __attribute__((ext_vector_type(8)));
typedef _Float16 f16x8 __attribute__((ext_vector_type(8)));
#define MFMA(a, b, c)  __builtin_amdgcn_mfma_f32_16x16x32_bf16(a, b, c, 0, 0, 0)
#define MFMAH(a, b, c) __builtin_amdgcn_mfma_f32_16x16x32_f16(a, b, c, 0, 0, 0)

#define FMAMIX_LO(ACC, SRC, AL) \
    asm("v_fma_mix_f32 %0, %1, %2, %0 op_sel:[0,0,0] op_sel_hi:[1,0,0]" \
        : "+v"(ACC) : "v"(SRC), "v"(AL))
#define FMAMIX_HI(ACC, SRC, AL) \
    asm("v_fma_mix_f32 %0, %1, %2, %0 op_sel:[1,0,0] op_sel_hi:[1,0,0]" \
        : "+v"(ACC) : "v"(SRC), "v"(AL))

__device__ __forceinline__ unsigned short bf16_rne(float f) {
    unsigned u = __float_as_uint(f);
    u += 0x7FFFu + ((u >> 16) & 1u);
    return (unsigned short)(u >> 16);
}
__device__ __forceinline__ float bf16f(unsigned short h) {
    return __uint_as_float(((unsigned)h) << 16);
}
__device__ __forceinline__ unsigned short f16_bits(float f) {
    __half h = __float2half(f);
    return *(unsigned short*)&h;
}
__device__ __forceinline__ float fast_tanh(float x) {
    x = fminf(fmaxf(x, -15.f), 15.f);
    float t = __expf(2.f * x);
    return (t - 1.f) / (t + 1.f);
}
__device__ __forceinline__ bf16x8 cvt_hi8(f32x4 v0, f32x4 v1) {
    bf16x8 f;
    f[0] = (short)bf16_rne(v0.x); f[1] = (short)bf16_rne(v0.y);
    f[2] = (short)bf16_rne(v0.z); f[3] = (short)bf16_rne(v0.w);
    f[4] = (short)bf16_rne(v1.x); f[5] = (short)bf16_rne(v1.y);
    f[6] = (short)bf16_rne(v1.z); f[7] = (short)bf16_rne(v1.w);
    return f;
}
__device__ __forceinline__ bf16x8 cvt_lo8(f32x4 v0, f32x4 v1, bf16x8 h) {
    bf16x8 f;
    f[0] = (short)bf16_rne(v0.x - bf16f((unsigned short)h[0]));
    f[1] = (short)bf16_rne(v0.y - bf16f((unsigned short)h[1]));
    f[2] = (short)bf16_rne(v0.z - bf16f((unsigned short)h[2]));
    f[3] = (short)bf16_rne(v0.w - bf16f((unsigned short)h[3]));
    f[4] = (short)bf16_rne(v1.x - bf16f((unsigned short)h[4]));
    f[5] = (short)bf16_rne(v1.y - bf16f((unsigned short)h[5]));
    f[6] = (short)bf16_rne(v1.z - bf16f((unsigned short)h[6]));
    f[7] = (short)bf16_rne(v1.w - bf16f((unsigned short)h[7]));
    return f;
}
__device__ __forceinline__ unsigned relu_pk(unsigned u) {
    return u & ~(((u & 0x80008000u) >> 15) * 0xFFFFu);
}
union U4F16 { uint4 u; f16x8 f; };

// ---------------- init ----------------
__global__ void init_zero_k(float* __restrict__ p, int n) {
    int i = blockIdx.x * 256 + threadIdx.x;
    if (i < n) p[i] = 0.f;
}

// ---------------- merged projection (gene blocks [0,GBLK), disease [GBLK,GBLK+DBLK)) ----------------
__launch_bounds__(256)
__global__ void proj_both(const float* __restrict__ xg, const float* __restrict__ Wg,
                          const float* __restrict__ bg,
                          const float* __restrict__ ag0, const float* __restrict__ ag1,
                          const float* __restrict__ ag2,
                          unsigned short* __restrict__ xgh,
                          float* __restrict__ og0, float* __restrict__ og1,
                          float* __restrict__ og2,
                          const float* __restrict__ xd, const float* __restrict__ Wd,
                          const float* __restrict__ bd, const float* __restrict__ ad0,
                          unsigned short* __restrict__ xdh, float* __restrict__ od0) {
    __shared__ bf16x8 Bhi[10 * 4 * 64];
    __shared__ bf16x8 Blo[8 * 4 * 64];
    __shared__ float btilS[32];
    int gene = blockIdx.x < GBLK;
    const float* x    = gene ? xg : xd;
    const float* W    = gene ? Wg : Wd;
    const float* bias = gene ? bg : bd;
    const float* a0v  = gene ? ag0 : ad0;
    const float* a1v  = gene ? ag1 : ad0;
    const float* a2v  = gene ? ag2 : ad0;
    unsigned short* xbf = gene ? xgh : xdh;
    float* o0 = gene ? og0 : od0;
    float* o1 = og1;
    float* o2 = og2;
    int ccmax = gene ? 24 : 8;
    int N = gene ? NG : ND;
    int bid = gene ? blockIdx.x : blockIdx.x - GBLK;

    for (int idx = threadIdx.x; idx < 128 * 32; idx += 256) {
        int row = idx >> 5, kq = idx & 31;
        f32x4 v = *(const f32x4*)&W[row * 128 + kq * 4];
        int ct = row >> 4, c = row & 15;
        int k0 = kq * 4;
        int kc = k0 >> 5, q16 = (k0 & 31) >> 3, j2 = (k0 & 7) >> 1;
        int slot = (ct * 4 + kc) * 64 + q16 * 16 + c;
        unsigned short hx = bf16_rne(v.x), hy = bf16_rne(v.y);
        unsigned short hz = bf16_rne(v.z), hw = bf16_rne(v.w);
        unsigned* dh = (unsigned*)&Bhi[slot];
        dh[j2]     = ((unsigned)hy << 16) | hx;
        dh[j2 + 1] = ((unsigned)hw << 16) | hz;
        unsigned* dl = (unsigned*)&Blo[slot];
        dl[j2]     = ((unsigned)bf16_rne(v.y - bf16f(hy)) << 16) | bf16_rne(v.x - bf16f(hx));
        dl[j2 + 1] = ((unsigned)bf16_rne(v.w - bf16f(hw)) << 16) | bf16_rne(v.z - bf16f(hz));
    }
    for (int idx = threadIdx.x; idx < 2 * 16 * 32; idx += 256) {
        int cc = idx >> 5, kq = idx & 31;
        f32x4 v = {0.f, 0.f, 0.f, 0.f};
        if (cc < ccmax) {
            int vv = cc >> 3, h = cc & 7;
            const float* av = (vv == 0) ? a0v : (vv == 1) ? a1v : a2v;
            #pragma unroll
            for (int c = 0; c < 16; c++) {
                float a = av[h * 16 + c];
                f32x4 w = *(const f32x4*)&W[(h * 16 + c) * 128 + kq * 4];
                v.x += a * w.x; v.y += a * w.y; v.z += a * w.z; v.w += a * w.w;
            }
        }
        int ct = 8 + (cc >> 4), c = cc & 15;
        int k0 = kq * 4;
        int kc = k0 >> 5, q16 = (k0 & 31) >> 3, j2 = (k0 & 7) >> 1;
        unsigned* dh = (unsigned*)&Bhi[(ct * 4 + kc) * 64 + q16 * 16 + c];
        dh[j2]     = ((unsigned)bf16_rne(v.y) << 16) | bf16_rne(v.x);
        dh[j2 + 1] = ((unsigned)bf16_rne(v.w) << 16) | bf16_rne(v.z);
    }
    if (threadIdx.x < 32) {
        float s = 0.f;
        if (threadIdx.x < ccmax) {
            int vv = threadIdx.x >> 3, h = threadIdx.x & 7;
            const float* av = (vv == 0) ? a0v : (vv == 1) ? a1v : a2v;
            #pragma unroll
            for (int c = 0; c < 16; c++) s += av[h * 16 + c] * bias[h * 16 + c];
        }
        btilS[threadIdx.x] = s;
    }
    __syncthreads();
    int wv = threadIdx.x >> 6, l = threadIdx.x & 63;
    int q = l >> 4, c16 = l & 15;
    int rw = bid * 128 + wv * 32;
    int n0 = min(rw + c16, N - 1);
    int n1 = min(rw + 16 + c16, N - 1);
    const float* xr0 = &x[(size_t)n0 * 128 + q * 8];
    const float* xr1 = &x[(size_t)n1 * 128 + q * 8];
    #define LOADX(FH, FL, PTR, OFF) \
        bf16x8 FH, FL; \
        { f32x4 v0_ = *(const f32x4*)((PTR) + (OFF)); \
          f32x4 v1_ = *(const f32x4*)((PTR) + (OFF) + 4); \
          FH = cvt_hi8(v0_, v1_); FL = cvt_lo8(v0_, v1_, FH); }
    LOADX(xh00, xl00, xr0, 0)  LOADX(xh01, xl01, xr0, 32)
    LOADX(xh02, xl02, xr0, 64) LOADX(xh03, xl03, xr0, 96)
    LOADX(xh10, xl10, xr1, 0)  LOADX(xh11, xl11, xr1, 32)
    LOADX(xh12, xl12, xr1, 64) LOADX(xh13, xl13, xr1, 96)
    #undef LOADX
    int r0 = rw + q * 4;
    int r1 = r0 + 16;
    #define CT_MAIN(CT) { \
        bf16x8 bh0 = Bhi[((CT) * 4 + 0) * 64 + l]; \
        bf16x8 bh1 = Bhi[((CT) * 4 + 1) * 64 + l]; \
        bf16x8 bh2 = Bhi[((CT) * 4 + 2) * 64 + l]; \
        bf16x8 bh3 = Bhi[((CT) * 4 + 3) * 64 + l]; \
        bf16x8 bl0 = Blo[((CT) * 4 + 0) * 64 + l]; \
        bf16x8 bl1 = Blo[((CT) * 4 + 1) * 64 + l]; \
        bf16x8 bl2 = Blo[((CT) * 4 + 2) * 64 + l]; \
        bf16x8 bl3 = Blo[((CT) * 4 + 3) * 64 + l]; \
        f32x4 aA = {0,0,0,0}, aB = {0,0,0,0}, aC = {0,0,0,0}, aD = {0,0,0,0}; \
        aA = MFMA(xh00, bh0, aA); aB = MFMA(xh01, bh1, aB); \
        aC = MFMA(xh10, bh0, aC); aD = MFMA(xh11, bh1, aD); \
        aA = MFMA(xl00, bh0, aA); aB = MFMA(xl01, bh1, aB); \
        aC = MFMA(xl10, bh0, aC); aD = MFMA(xl11, bh1, aD); \
        aA = MFMA(xh00, bl0, aA); aB = MFMA(xh01, bl1, aB); \
        aC = MFMA(xh10, bl0, aC); aD = MFMA(xh11, bl1, aD); \
        aA = MFMA(xh02, bh2, aA); aB = MFMA(xh03, bh3, aB); \
        aC = MFMA(xh12, bh2, aC); aD = MFMA(xh13, bh3, aD); \
        aA = MFMA(xl02, bh2, aA); aB = MFMA(xl03, bh3, aB); \
        aC = MFMA(xl12, bh2, aC); aD = MFMA(xl13, bh3, aD); \
        aA = MFMA(xh02, bl2, aA); aB = MFMA(xh03, bl3, aB); \
        aC = MFMA(xh12, bl2, aC); aD = MFMA(xh13, bl3, aD); \
        f32x4 d0 = aA + aB, d1 = aC + aD; \
        float bv = bias[(CT) * 16 + c16]; \
        int col = (CT) * 16 + c16; \
        if (r0 + 0 < N) xbf[(size_t)(r0 + 0) * 128 + col] = f16_bits(d0[0] + bv); \
        if (r0 + 1 < N) xbf[(size_t)(r0 + 1) * 128 + col] = f16_bits(d0[1] + bv); \
        if (r0 + 2 < N) xbf[(size_t)(r0 + 2) * 128 + col] = f16_bits(d0[2] + bv); \
        if (r0 + 3 < N) xbf[(size_t)(r0 + 3) * 128 + col] = f16_bits(d0[3] + bv); \
        if (r1 + 0 < N) xbf[(size_t)(r1 + 0) * 128 + col] = f16_bits(d1[0] + bv); \
        if (r1 + 1 < N) xbf[(size_t)(r1 + 1) * 128 + col] = f16_bits(d1[1] + bv); \
        if (r1 + 2 < N) xbf[(size_t)(r1 + 2) * 128 + col] = f16_bits(d1[2] + bv); \
        if (r1 + 3 < N) xbf[(size_t)(r1 + 3) * 128 + col] = f16_bits(d1[3] + bv); }
    CT_MAIN(0) CT_MAIN(1) CT_MAIN(2) CT_MAIN(3)
    CT_MAIN(4) CT_MAIN(5) CT_MAIN(6) CT_MAIN(7)
    #undef CT_MAIN
    #define CT_ATT(TE) { \
        bf16x8 bh0 = Bhi[((8 + (TE)) * 4 + 0) * 64 + l]; \
        bf16x8 bh1 = Bhi[((8 + (TE)) * 4 + 1) * 64 + l]; \
        bf16x8 bh2 = Bhi[((8 + (TE)) * 4 + 2) * 64 + l]; \
        bf16x8 bh3 = Bhi[((8 + (TE)) * 4 + 3) * 64 + l]; \
        f32x4 aA = {0,0,0,0}, aB = {0,0,0,0}, aC = {0,0,0,0}, aD = {0,0,0,0}; \
        aA = MFMA(xh00, bh0, aA); aB = MFMA(xh01, bh1, aB); \
        aC = MFMA(xh10, bh0, aC); aD = MFMA(xh11, bh1, aD); \
        aA = MFMA(xh02, bh2, aA); aB = MFMA(xh03, bh3, aB); \
        aC = MFMA(xh12, bh2, aC); aD = MFMA(xh13, bh3, aD); \
        f32x4 d0 = aA + aB, d1 = aC + aD; \
        int cc = (TE) * 16 + c16; \
        if (cc < ccmax) { \
            float bt = btilS[cc]; \
            int vv = cc >> 3, h = cc & 7; \
            float* op = (vv == 0) ? o0 : ((vv == 1) ? o1 : o2); \
            if (r0 + 0 < N) op[(r0 + 0) * 8 + h] = d0[0] + bt; \
            if (r0 + 1 < N) op[(r0 + 1) * 8 + h] = d0[1] + bt; \
            if (r0 + 2 < N) op[(r0 + 2) * 8 + h] = d0[2] + bt; \
            if (r0 + 3 < N) op[(r0 + 3) * 8 + h] = d0[3] + bt; \
            if (r1 + 0 < N) op[(r1 + 0) * 8 + h] = d1[0] + bt; \
            if (r1 + 1 < N) op[(r1 + 1) * 8 + h] = d1[1] + bt; \
            if (r1 + 2 < N) op[(r1 + 2) * 8 + h] = d1[2] + bt; \
            if (r1 + 3 < N) op[(r1 + 3) * 8 + h] = d1[3] + bt; } }
    CT_ATT(0)
    if (ccmax > 16) { CT_ATT(1) }
    #undef CT_ATT
}

// ---------------- K1: fused bucket scatter ----------------
__launch_bounds__(256)
__global__ void fused_scatter(const int* __restrict__ gg_src, const int* __restrict__ gg_dst,
                              const int* __restrict__ dg_src, const int* __restrict__ dg_dst,
                              int* __restrict__ bcnt, unsigned int* __restrict__ colPacked) {
    __shared__ int cnt[256], scanE[256], gbase[256], cursor[256];
    __shared__ int ss[256];
    __shared__ unsigned int sorted[S1_CH];
    __shared__ unsigned char bof[S1_CH];
    int t = threadIdx.x;
    cnt[t] = 0;
    __syncthreads();
    int base = blockIdx.x * S1_CH;
    for (int k = 0; k < S1_CH; k += 256) {
        int e = base + k + t;
        if (e < EALL) {
            int dn = (e < EGG) ? gg_dst[e] : (NG + dg_dst[e - EGG]);
            atomicAdd(&cnt[dn >> SHIFT], 1);
        }
    }
    __syncthreads();
    int v = cnt[t];
    ss[t] = v;
    __syncthreads();
    for (int off = 1; off < 256; off <<= 1) {
        int y = (t >= off) ? ss[t - off] : 0;
        __syncthreads();
        ss[t] += y;
        __syncthreads();
    }
    scanE[t] = ss[t] - v;
    cursor[t] = ss[t] - v;
    if (t < NBUK && v > 0) gbase[t] = atomicAdd(&bcnt[t], v);
    __syncthreads();
    for (int k = 0; k < S1_CH; k += 256) {
        int e = base + k + t;
        if (e < EALL) {
            int s, dn;
            if (e < EGG) { s = gg_src[e]; dn = gg_dst[e]; }
            else         { s = dg_src[e - EGG]; dn = NG + dg_dst[e - EGG]; }
            int b = dn >> SHIFT;
            int slot = atomicAdd(&cursor[b], 1);
            sorted[slot] = ((unsigned int)s << SHIFT) | (unsigned int)(dn & (BDSTS - 1));
            bof[slot] = (unsigned char)b;
        }
    }
    __syncthreads();
    int total = ss[255];
    for (int f = t; f < total; f += 256) {
        int b = bof[f];
        colPacked[(size_t)b * BUKCAP + gbase[b] + (f - scanE[b])] = sorted[f];
    }
}

// ---------------- K2: per-bucket build ----------------
__launch_bounds__(256)
__global__ void bucket_build(const unsigned int* __restrict__ colPacked,
                             const int* __restrict__ bcnt,
                             int* __restrict__ rp, int* __restrict__ col) {
    __shared__ int lcur[BDSTS];
    __shared__ int tsum[256];
    __shared__ int bscan[256];
    int b = blockIdx.x;
    int t = threadIdx.x;
    bscan[t] = (t < NBUK) ? bcnt[t] : 0;
    __syncthreads();
    for (int off = 1; off < 256; off <<= 1) {
        int y = (t >= off) ? bscan[t - off] : 0;
        __syncthreads();
        bscan[t] += y;
        __syncthreads();
    }
    int gb = (b > 0) ? bscan[b - 1] : 0;
    int d0 = b << SHIFT;
    int nd = min(BDSTS, NALL - d0);
    int cnt = bcnt[b];
    const unsigned int* pk = colPacked + (size_t)b * BUKCAP;
    for (int i = t; i < BDSTS; i += 256) lcur[i] = 0;
    __syncthreads();
    for (int i = t; i < cnt; i += 256)
        atomicAdd(&lcur[pk[i] & (BDSTS - 1)], 1);
    __syncthreads();
    int h0 = lcur[t * 4 + 0], h1 = lcur[t * 4 + 1], h2 = lcur[t * 4 + 2], h3 = lcur[t * 4 + 3];
    int tot = h0 + h1 + h2 + h3;
    tsum[t] = tot;
    __syncthreads();
    for (int off = 1; off < 256; off <<= 1) {
        int y = (t >= off) ? tsum[t - off] : 0;
        __syncthreads();
        tsum[t] += y;
        __syncthreads();
    }
    int pp = tsum[t] - tot + gb;
    __syncthreads();
    #define EMIT(J, HJ) { int idx = t * 4 + (J); \
        if (idx < nd) rp[d0 + idx] = pp; \
        lcur[idx] = pp; pp += (HJ); }
    EMIT(0, h0) EMIT(1, h1) EMIT(2, h2) EMIT(3, h3)
    #undef EMIT
    if (b == NBUK - 1 && t == 0) rp[NALL] = EALL;
    __syncthreads();
    for (int i = t; i < cnt; i += 256) {
        unsigned int p = pk[i];
        int pos = atomicAdd(&lcur[p & (BDSTS - 1)], 1);
        col[pos] = (int)(p >> SHIFT);
    }
}

// ---------------- gather v8 (R16, no epilogue): single-pass softmax+accumulate ----------------
__launch_bounds__(256)
__global__ void gat_gather_all(const int* __restrict__ rp, const int* __restrict__ col,
                               const float* __restrict__ as_gg, const float* __restrict__ ad_gg,
                               const unsigned short* __restrict__ xg_h,
                               const float* __restrict__ as_dg, const float* __restrict__ ad_dg,
                               const unsigned short* __restrict__ xd_h,
                               unsigned short* __restrict__ out_gg,
                               unsigned short* __restrict__ out_dg) {
    int wid = (blockIdx.x * 256 + threadIdx.x) >> 6;
    int l = threadIdx.x & 63;
    if (wid >= NALL) return;
    int isdg = wid >= NG;
    int d = isdg ? wid - NG : wid;
    const float* a_s = isdg ? as_dg : as_gg;
    const float* a_d = isdg ? ad_dg : ad_gg;
    const unsigned short* xbf = isdg ? xd_h : xg_h;
    unsigned short* outh = (isdg ? out_dg : out_gg);

    int base = rp[wid];
    int deg = rp[wid + 1] - base;

    int hl = l & 7;
    int g  = l >> 3;
    float adl = a_d[d * 8 + hl];
    int q = l >> 4;
    int cq = l & 15;
    int hq = cq >> 1;
    uint32_t colbyte = (uint32_t)cq << 4;
    float a0 = 0.f, a1 = 0.f, a2 = 0.f, a3 = 0.f, a4 = 0.f, a5 = 0.f, a6 = 0.f, a7 = 0.f;
    float sacc = 0.f;
    for (int c0 = 0; c0 < deg; c0 += 64) {
        int myi = c0 + l;
        int colreg = (myi < deg) ? col[base + myi] : 0;
        int lim = min(deg - c0, 64);
        for (int j8 = 0; j8 < lim; j8 += 8) {
            float ex;
            {
                int s = __shfl(colreg, j8 + g);
                float a = a_s[s * 8 + hl] + adl;
                a = a > 0.f ? a : 0.2f * a;
                ex = __expf(a);
            }
            int jlim = min(lim - j8, 8);
            #pragma unroll
            for (int sub = 0; sub < 8; sub += 4) {
                int jrel = sub + q;
                int s = __shfl(colreg, j8 + jrel);
                float al = __shfl(ex, (jrel << 3) + hq);
                al = (jrel < jlim) ? al : 0.f;
                sacc += al;
                const uint4 rv = *(const uint4*)((const char*)xbf +
                                    (((size_t)(uint32_t)s << 8) + colbyte));
                FMAMIX_LO(a0, rv.x, al); FMAMIX_HI(a1, rv.x, al);
                FMAMIX_LO(a2, rv.y, al); FMAMIX_HI(a3, rv.y, al);
                FMAMIX_LO(a4, rv.z, al); FMAMIX_HI(a5, rv.z, al);
                FMAMIX_LO(a6, rv.w, al); FMAMIX_HI(a7, rv.w, al);
            }
        }
    }
    sacc += __shfl_xor(sacc, 16); sacc += __shfl_xor(sacc, 32);
    a0 += __shfl_xor(a0, 16); a0 += __shfl_xor(a0, 32);
    a1 += __shfl_xor(a1, 16); a1 += __shfl_xor(a1, 32);
    a2 += __shfl_xor(a2, 16); a2 += __shfl_xor(a2, 32);
    a3 += __shfl_xor(a3, 16); a3 += __shfl_xor(a3, 32);
    a4 += __shfl_xor(a4, 16); a4 += __shfl_xor(a4, 32);
    a5 += __shfl_xor(a5, 16); a5 += __shfl_xor(a5, 32);
    a6 += __shfl_xor(a6, 16); a6 += __shfl_xor(a6, 32);
    a7 += __shfl_xor(a7, 16); a7 += __shfl_xor(a7, 32);
    if (q == 0) {
        float rsc = 1.f / (sacc + 1e-16f);
        a0 *= rsc; a1 *= rsc; a2 *= rsc; a3 *= rsc;
        a4 *= rsc; a5 *= rsc; a6 *= rsc; a7 *= rsc;
        __half2 h01 = __floats2half2_rn(a0, a1);
        __half2 h23 = __floats2half2_rn(a2, a3);
        __half2 h45 = __floats2half2_rn(a4, a5);
        __half2 h67 = __floats2half2_rn(a6, a7);
        uint4 o;
        o.x = *(unsigned*)&h01; o.y = *(unsigned*)&h23;
        o.z = *(unsigned*)&h45; o.w = *(unsigned*)&h67;
        *(uint4*)((char*)outh + (size_t)d * 256 + cq * 16) = o;
    }
}

// ---------------- kmean via f16 MFMA + fused final-lin partials ----------------
__launch_bounds__(256)
__global__ void kmean_mfma(const unsigned short* __restrict__ srcA,
                           const unsigned short* __restrict__ srcB,
                           const float* __restrict__ W, const float* __restrict__ bias,
                           float* __restrict__ kp,
                           const float* __restrict__ lin_w,
                           float* __restrict__ pgg, float* __restrict__ pdg) {
    __shared__ f16x8 Bs[8 * 4 * 64];
    __shared__ float LW[256];
    for (int idx = threadIdx.x; idx < 128 * 32; idx += 256) {
        int row = idx >> 5, kq = idx & 31;
        f32x4 v = *(const f32x4*)&W[row * 128 + kq * 4];
        int ct = row >> 4, c = row & 15;
        int k0 = kq * 4;
        int kc = k0 >> 5, q16 = (k0 & 31) >> 3, j2 = (k0 & 7) >> 1;
        unsigned* dst = (unsigned*)&Bs[(ct * 4 + kc) * 64 + q16 * 16 + c];
        dst[j2]     = ((unsigned)f16_bits(v.y) << 16) | f16_bits(v.x);
        dst[j2 + 1] = ((unsigned)f16_bits(v.w) << 16) | f16_bits(v.z);
    }
    LW[threadIdx.x] = lin_w[threadIdx.x];
    __syncthreads();
    int half = blockIdx.x >= KM_HALF;
    const unsigned short* src = half ? srcB : srcA;
    float* kpp = half ? (kp + 128) : kp;
    int rb = (half ? blockIdx.x - KM_HALF : blockIdx.x) * 128;
    int wv = threadIdx.x >> 6, l = threadIdx.x & 63;
    int q = l >> 4, c16 = l & 15;
    int rw = rb + wv * 32;
    const char* xr0 = (const char*)src + (size_t)(rw + c16) * 256 + q * 16;
    const char* xr1 = xr0 + 16 * 256;
    #define LOADA(F, U, PTR, OFF) f16x8 F; uint4 U; { \
        U = *(const uint4*)((PTR) + (OFF)); \
        U.x = relu_pk(U.x); U.y = relu_pk(U.y); \
        U.z = relu_pk(U.z); U.w = relu_pk(U.w); \
        U4F16 u_; u_.u = U; F = u_.f; }
    LOADA(f00, u00, xr0, 0) LOADA(f01, u01, xr0, 64) LOADA(f02, u02, xr0, 128) LOADA(f03, u03, xr0, 192)
    LOADA(f10, u10, xr1, 0) LOADA(f11, u11, xr1, 64) LOADA(f12, u12, xr1, 128) LOADA(f13, u13, xr1, 192)
    #undef LOADA
    float bv0 = bias[c16],      bv1 = bias[16 + c16], bv2 = bias[32 + c16], bv3 = bias[48 + c16];
    float bv4 = bias[64 + c16], bv5 = bias[80 + c16], bv6 = bias[96 + c16], bv7 = bias[112 + c16];
    int row0 = rw + q * 4;
    int row1 = row0 + 16;
    float cs0 = 0.f, cs1 = 0.f, cs2 = 0.f, cs3 = 0.f, cs4 = 0.f, cs5 = 0.f, cs6 = 0.f, cs7 = 0.f;
    #define CT_STEP(CT, CS, BV) { \
        f16x8 b0 = Bs[((CT) * 4 + 0) * 64 + l]; \
        f16x8 b1 = Bs[((CT) * 4 + 1) * 64 + l]; \
        f16x8 b2 = Bs[((CT) * 4 + 2) * 64 + l]; \
        f16x8 b3 = Bs[((CT) * 4 + 3) * 64 + l]; \
        f32x4 aA = {0,0,0,0}, aB = {0,0,0,0}, aC = {0,0,0,0}, aD = {0,0,0,0}; \
        aA = MFMAH(f00, b0, aA); aB = MFMAH(f01, b1, aB); \
        aA = MFMAH(f02, b2, aA); aB = MFMAH(f03, b3, aB); \
        aC = MFMAH(f10, b0, aC); aD = MFMAH(f11, b1, aD); \
        aC = MFMAH(f12, b2, aC); aD = MFMAH(f13, b3, aD); \
        f32x4 d0 = aA + aB, d1 = aC + aD; \
        float s = 0.f; \
        if (row0 + 0 < NG) s += fast_tanh(d0[0] + (BV)); \
        if (row0 + 1 < NG) s += fast_tanh(d0[1] + (BV)); \
        if (row0 + 2 < NG) s += fast_tanh(d0[2] + (BV)); \
        if (row0 + 3 < NG) s += fast_tanh(d0[3] + (BV)); \
        if (row1 + 0 < NG) s += fast_tanh(d1[0] + (BV)); \
        if (row1 + 1 < NG) s += fast_tanh(d1[1] + (BV)); \
        if (row1 + 2 < NG) s += fast_tanh(d1[2] + (BV)); \
        if (row1 + 3 < NG) s += fast_tanh(d1[3] + (BV)); \
        CS += s; }
    CT_STEP(0, cs0, bv0) CT_STEP(1, cs1, bv1) CT_STEP(2, cs2, bv2) CT_STEP(3, cs3, bv3)
    CT_STEP(4, cs4, bv4) CT_STEP(5, cs5, bv5) CT_STEP(6, cs6, bv6) CT_STEP(7, cs7, bv7)
    #undef CT_STEP
    // fused final-lin partials: pX = relu(row) . lin_w[0/1] via FMAMIX on relu'd fragments
    float pA0 = 0.f, pA1 = 0.f, pB0 = 0.f, pB1 = 0.f;
    #define PART(U, KC, P0, P1) { \
        f32x4 wa = *(const f32x4*)&LW[(KC) * 32 + q * 8]; \
        f32x4 wb = *(const f32x4*)&LW[(KC) * 32 + q * 8 + 4]; \
        f32x4 va = *(const f32x4*)&LW[128 + (KC) * 32 + q * 8]; \
        f32x4 vb = *(const f32x4*)&LW[128 + (KC) * 32 + q * 8 + 4]; \
        FMAMIX_LO(P0, U.x, wa.x); FMAMIX_HI(P0, U.x, wa.y); \
        FMAMIX_LO(P0, U.y, wa.z); FMAMIX_HI(P0, U.y, wa.w); \
        FMAMIX_LO(P0, U.z, wb.x); FMAMIX_HI(P0, U.z, wb.y); \
        FMAMIX_LO(P0, U.w, wb.z); FMAMIX_HI(P0, U.w, wb.w); \
        FMAMIX_LO(P1, U.x, va.x); FMAMIX_HI(P1, U.x, va.y); \
        FMAMIX_LO(P1, U.y, va.z); FMAMIX_HI(P1, U.y, va.w); \
        FMAMIX_LO(P1, U.z, vb.x); FMAMIX_HI(P1, U.z, vb.y); \
        FMAMIX_LO(P1, U.w, vb.z); FMAMIX_HI(P1, U.w, vb.w); }
    PART(u00, 0, pA0, pA1) PART(u01, 1, pA0, pA1) PART(u02, 2, pA0, pA1) PART(u03, 3, pA0, pA1)
    PART(u10, 0, pB0, pB1) PART(u11, 1, pB0, pB1) PART(u12, 2, pB0, pB1) PART(u13, 3, pB0, pB1)
    #undef PART
    pA0 += __shfl_xor(pA0, 16); pA0 += __shfl_xor(pA0, 32);
    pA1 += __shfl_xor(pA1, 16); pA1 += __shfl_xor(pA1, 32);
    pB0 += __shfl_xor(pB0, 16); pB0 += __shfl_xor(pB0, 32);
    pB1 += __shfl_xor(pB1, 16); pB1 += __shfl_xor(pB1, 32);
    if (l < 16) {
        float* pp = half ? pdg : pgg;
        int ra = rw + l, rbw = rw + 16 + l;
        if (ra < NG)  { float2 v; v.x = pA0; v.y = pA1; *(float2*)&pp[ra * 2] = v; }
        if (rbw < NG) { float2 v; v.x = pB0; v.y = pB1; *(float2*)&pp[rbw * 2] = v; }
    }
    __syncthreads();
    float* red = (float*)Bs;
    #define REDUCE_CT(CT, CS) { \
        float v = (CS); \
        v += __shfl_xor(v, 16); v += __shfl_xor(v, 32); \
        if (l < 16) red[wv * 128 + (CT) * 16 + l] = v; }
    REDUCE_CT(0, cs0) REDUCE_CT(1, cs1) REDUCE_CT(2, cs2) REDUCE_CT(3, cs3)
    REDUCE_CT(4, cs4) REDUCE_CT(5, cs5) REDUCE_CT(6, cs6) REDUCE_CT(7, cs7)
    #undef REDUCE_CT
    __syncthreads();
    if (threadIdx.x < 128) {
        float s = red[threadIdx.x] + red[128 + threadIdx.x]
                + red[256 + threadIdx.x] + red[384 + threadIdx.x];
        atomicAdd(&kpp[threadIdx.x], s);
    }
}

// ---------------- semantic softmax (2 scores) ----------------
__global__ void score_attn(const float* __restrict__ kpart, const float* __restrict__ q,
                           float* __restrict__ attn) {
    __shared__ float r0[128], r1[128];
    int t = threadIdx.x;
    r0[t] = q[t] * kpart[t];
    r1[t] = q[t] * kpart[128 + t];
    __syncthreads();
    for (int s = 64; s > 0; s >>= 1) {
        if (t < s) { r0[t] += r0[t + s]; r1[t] += r1[t + s]; }
        __syncthreads();
    }
    if (t == 0) {
        float s0 = r0[0] / (float)NG, s1 = r1[0] / (float)NG;
        float mx = fmaxf(s0, s1);
        float e0 = expf(s0 - mx), e1 = expf(s1 - mx);
        attn[0] = e0 / (e0 + e1);
        attn[1] = e1 / (e0 + e1);
    }
}

// ---------------- final combine: out = attn0*pgg + attn1*pdg + lin_b ----------------
__global__ void final_combine(const float* __restrict__ pgg, const float* __restrict__ pdg,
                              const float* __restrict__ attn, const float* __restrict__ lin_b,
                              float* __restrict__ outp) {
    int n = blockIdx.x * 256 + threadIdx.x;
    if (n >= NG) return;
    float a0 = attn[0], a1 = attn[1];
    float2 g = *(const float2*)&pgg[n * 2];
    float2 dd = *(const float2*)&pdg[n * 2];
    float2 o;
    o.x = a0 * g.x + a1 * dd.x + lin_b[0];
    o.y = a0 * g.y + a1 * dd.y + lin_b[1];
    *(float2*)&outp[n * 2] = o;
}

extern "C" void kernel_launch(void* const* d_in, const int* in_sizes, int n_in,
                              void* d_out, int out_size, void* d_ws, size_t ws_size,
                              hipStream_t stream) {
    const float* x_gene    = (const float*)d_in[0];
    const float* x_disease = (const float*)d_in[1];
    const int*   edge_gg   = (const int*)d_in[2];
    const int*   edge_dg   = (const int*)d_in[3];
    const float* pg_w      = (const float*)d_in[4];
    const float* pg_b      = (const float*)d_in[5];
    const float* pd_w      = (const float*)d_in[6];
    const float* pd_b      = (const float*)d_in[7];
    const float* att_src_gg= (const float*)d_in[8];
    const float* att_dst_gg= (const float*)d_in[9];
    const float* att_src_dg= (const float*)d_in[10];
    const float* att_dst_dg= (const float*)d_in[11];
    const float* k_lin_w   = (const float*)d_in[12];
    const float* k_lin_b   = (const float*)d_in[13];
    const float* q         = (const float*)d_in[14];
    const float* lin_w     = (const float*)d_in[15];
    const float* lin_b     = (const float*)d_in[16];
    float* out = (float*)d_out;
    float* ws  = (float*)d_ws;

    unsigned short* out_gg = (unsigned short*)(ws + OFF_OUT_GG);
    unsigned short* out_dg = (unsigned short*)(ws + OFF_OUT_DG);
    unsigned int* colPacked = (unsigned int*)(ws + OFF_OUT_GG);  // overlay (dead before gather)
    unsigned short* xg_h = (unsigned short*)(ws + OFF_XG);
    unsigned short* xd_h = (unsigned short*)(ws + OFF_XD);
    float* a_src_gg = ws + OFF_ASG;
    float* a_dst_gg = ws + OFF_ADG;
    float* a_dst_dg = ws + OFF_ADD;
    float* a_src_dg = ws + OFF_ASD;
    float* kpart  = ws + OFF_KPART;
    float* attn   = ws + OFF_ATTN;
    float* pgg    = ws + OFF_PGG;
    float* pdg    = ws + OFF_PDG;
    int* bcnt  = (int*)(ws + OFF_BCNT);
    int* rp    = (int*)(ws + OFF_RP);
    int* col   = (int*)(ws + OFF_COL);

    const int* gg_src = edge_gg;
    const int* gg_dst = edge_gg + EGG;
    const int* dg_src = edge_dg;
    const int* dg_dst = edge_dg + EDG;

    // 1. zero kpart + bucket counters
    hipLaunchKernelGGL(init_zero_k, dim3(2), dim3(256), 0, stream, ws + ZERO_BASE, ZERO_CNT);
    // 2. merged projection
    hipLaunchKernelGGL(proj_both, dim3(GBLK + DBLK), dim3(256), 0, stream,
                       x_gene, pg_w, pg_b, att_src_gg, att_dst_gg, att_dst_dg,
                       xg_h, a_src_gg, a_dst_gg, a_dst_dg,
                       x_disease, pd_w, pd_b, att_src_dg, xd_h, a_src_dg);
    // 3. CSR build
    hipLaunchKernelGGL(fused_scatter, dim3((EALL + S1_CH - 1) / S1_CH), dim3(256), 0, stream,
                       gg_src, gg_dst, dg_src, dg_dst, bcnt, colPacked);
    hipLaunchKernelGGL(bucket_build, dim3(NBUK), dim3(256), 0, stream,
                       colPacked, bcnt, rp, col);
    // 4. merged single-pass gather (R16 form, no epilogue)
    hipLaunchKernelGGL(gat_gather_all, dim3((NALL + 3) / 4), dim3(256), 0, stream,
                       rp, col, a_src_gg, a_dst_gg, xg_h, a_src_dg, a_dst_dg, xd_h,
                       out_gg, out_dg);
    // 5. semantic attention + fused final-lin partials
    hipLaunchKernelGGL(kmean_mfma, dim3(KM_HALF * 2), dim3(256), 0, stream,
                       out_gg, out_dg, k_lin_w, k_lin_b, kpart, lin_w, pgg, pdg);
    hipLaunchKernelGGL(score_attn, dim3(1), dim3(128), 0, stream, kpart, q, attn);
    // 6. trivial final combine
    hipLaunchKernelGGL(final_combine, dim3((NG + 255) / 256), dim3(256), 0, stream,
                       pgg, pdg, attn, lin_b, out);
}